// Round 2
// baseline (10591.664 us; speedup 1.0000x reference)
//
#include <hip/hip_runtime.h>
#include <hip/hip_bf16.h>

#define NUM_E   20000
#define H_DIM   200
#define TD_DIM  48
#define HD_DIM  24
#define L_HIST  32
#define N_HIST  3
#define E_EDGES 200000
#define BATCH   512

// ---------------------------------------------------------------- utilities

__device__ inline float wave_sum64(float x) {
    #pragma unroll
    for (int m = 1; m < 64; m <<= 1) x += __shfl_xor(x, m);
    return x;
}

__global__ void fill_f32(float* __restrict__ p, long n, float v) {
    long i = (long)blockIdx.x * blockDim.x + threadIdx.x;
    if (i < n) p[i] = v;
}

// C[m, j] = b1[j] (+ b2[j]) broadcast over rows; dense ldc == N
__global__ void fill_bias2(float* __restrict__ C, long n, int N,
                           const float* __restrict__ b1, const float* __restrict__ b2) {
    long i = (long)blockIdx.x * blockDim.x + threadIdx.x;
    if (i >= n) return;
    int j = (int)(i % N);
    float v = b1 ? b1[j] : 0.f;
    if (b2) v += b2[j];
    C[i] = v;
}

__global__ void relu_copy(float* __restrict__ dst, const float* __restrict__ src, long n) {
    long i = (long)blockIdx.x * blockDim.x + threadIdx.x;
    if (i < n) dst[i] = fmaxf(src[i], 0.f);
}

__global__ void sigmoid_inplace(float* __restrict__ p, long n) {
    long i = (long)blockIdx.x * blockDim.x + threadIdx.x;
    if (i < n) p[i] = 1.f / (1.f + expf(-p[i]));
}

// ---------------------------------------------------------------- GEMM
// C += A @ op(B).  BT=1: B is (N,K) row-major (i.e. compute A @ B^T).
//                  BT=0: B is (K,N) row-major.
template<int BT>
__global__ __launch_bounds__(256) void gemm_acc_k(
    float* __restrict__ C, const float* __restrict__ A, const float* __restrict__ B,
    int M, int N, int K, int lda, int ldb, int ldc)
{
    __shared__ float As[32][33];
    __shared__ float Bs[32][33];
    const int bm = blockIdx.x * 32;
    const int bn = blockIdx.y * 32;
    const int tid = threadIdx.x;
    const int tx = tid & 15;
    const int ty = tid >> 4;
    const int r0 = ty * 2, c0 = tx * 2;
    float acc00 = 0.f, acc01 = 0.f, acc10 = 0.f, acc11 = 0.f;

    for (int k0 = 0; k0 < K; k0 += 32) {
        for (int i = tid; i < 1024; i += 256) {
            int r = i >> 5, c = i & 31;
            int gm = bm + r, gk = k0 + c;
            As[r][c] = (gm < M && gk < K) ? A[(long)gm * lda + gk] : 0.f;
        }
        if (BT) {
            for (int i = tid; i < 1024; i += 256) {
                int nn = i >> 5, kk = i & 31;
                int gn = bn + nn, gk = k0 + kk;
                Bs[kk][nn] = (gn < N && gk < K) ? B[(long)gn * ldb + gk] : 0.f;
            }
        } else {
            for (int i = tid; i < 1024; i += 256) {
                int kk = i >> 5, nn = i & 31;
                int gk = k0 + kk, gn = bn + nn;
                Bs[kk][nn] = (gk < K && gn < N) ? B[(long)gk * ldb + gn] : 0.f;
            }
        }
        __syncthreads();
        #pragma unroll
        for (int kk = 0; kk < 32; kk++) {
            float a0 = As[r0][kk], a1 = As[r0 + 1][kk];
            float b0 = Bs[kk][c0], b1 = Bs[kk][c0 + 1];
            acc00 += a0 * b0; acc01 += a0 * b1;
            acc10 += a1 * b0; acc11 += a1 * b1;
        }
        __syncthreads();
    }
    int gm0 = bm + r0, gn0 = bn + c0;
    if (gm0 < M) {
        if (gn0     < N) C[(long)gm0 * ldc + gn0]     += acc00;
        if (gn0 + 1 < N) C[(long)gm0 * ldc + gn0 + 1] += acc01;
    }
    if (gm0 + 1 < M) {
        if (gn0     < N) C[(long)(gm0 + 1) * ldc + gn0]     += acc10;
        if (gn0 + 1 < N) C[(long)(gm0 + 1) * ldc + gn0 + 1] += acc11;
    }
}

// ---------------------------------------------------------------- graph ops

__global__ void deg_count(const int* __restrict__ di, float* __restrict__ deg, int E) {
    int e = blockIdx.x * 256 + threadIdx.x;
    if (e < E) atomicAdd(&deg[di[e]], 1.0f);
}

__global__ void inv_deg(const float* __restrict__ deg, float* __restrict__ inv, int n) {
    int i = blockIdx.x * 256 + threadIdx.x;
    if (i < n) inv[i] = 1.f / fmaxf(deg[i], 1.f);
}

// out[didx[e], :] += src[sidx[e], :]   (one wave per edge, float4 lanes)
__global__ __launch_bounds__(256) void scatter_add_rows(
    float* __restrict__ out, const float* __restrict__ src,
    const int* __restrict__ sidx, const int* __restrict__ didx, int E)
{
    int gt = blockIdx.x * 256 + threadIdx.x;
    int e = gt >> 6;
    int lane = gt & 63;
    if (e >= E) return;
    int s = sidx[e], d = didx[e];
    if (lane < 50) {
        const float4 v = *(const float4*)(src + (long)s * H_DIM + lane * 4);
        float* o = out + (long)d * H_DIM + lane * 4;
        atomicAdd(o + 0, v.x); atomicAdd(o + 1, v.y);
        atomicAdd(o + 2, v.z); atomicAdd(o + 3, v.w);
    }
}

// h = l2norm(deg>0 ? tmp*inv : 0) per row
__global__ __launch_bounds__(64) void norm_agg(
    float* __restrict__ h, const float* __restrict__ tmp,
    const float* __restrict__ deg, const float* __restrict__ inv)
{
    int v = blockIdx.x;
    int lane = threadIdx.x;
    float dv = deg[v], iv = inv[v];
    float vals[4]; float ss = 0.f;
    #pragma unroll
    for (int t = 0; t < 4; t++) {
        int j = lane + t * 64;
        float x = 0.f;
        if (j < H_DIM && dv > 0.f) x = tmp[(long)v * H_DIM + j] * iv;
        vals[t] = x; ss += x * x;
    }
    ss = wave_sum64(ss);
    float r = 1.f / fmaxf(sqrtf(ss), 1e-12f);
    #pragma unroll
    for (int t = 0; t < 4; t++) {
        int j = lane + t * 64;
        if (j < H_DIM) h[(long)v * H_DIM + j] = vals[t] * r;
    }
}

__global__ __launch_bounds__(64) void l2norm_rows(
    float* __restrict__ out, const float* __restrict__ in)
{
    int v = blockIdx.x;
    int lane = threadIdx.x;
    float vals[4]; float ss = 0.f;
    #pragma unroll
    for (int t = 0; t < 4; t++) {
        int j = lane + t * 64;
        float x = (j < H_DIM) ? in[(long)v * H_DIM + j] : 0.f;
        vals[t] = x; ss += x * x;
    }
    ss = wave_sum64(ss);
    float r = 1.f / fmaxf(sqrtf(ss), 1e-12f);
    #pragma unroll
    for (int t = 0; t < 4; t++) {
        int j = lane + t * 64;
        if (j < H_DIM) out[(long)v * H_DIM + j] = vals[t] * r;
    }
}

__global__ void tenc_ent(float* __restrict__ te, const float* __restrict__ deg,
                         const float* __restrict__ af, const float* __restrict__ ap,
                         const float* __restrict__ cf, const float* __restrict__ cp,
                         float tcnt, int M)
{
    int idx = blockIdx.x * 256 + threadIdx.x;
    if (idx >= M * TD_DIM) return;
    int v = idx / TD_DIM, j = idx % TD_DIM;
    float t = (deg[v] > 0.f) ? tcnt : 100.0f;
    float val;
    if (j < HD_DIM) val = tanhf((t + 1.f) * af[j] + ap[j]);
    else            val = cosf(t * cf[j - HD_DIM] + cp[j - HD_DIM]);
    te[idx] = val;
}

// tmp = (tmp + relsum) * inv[row]
__global__ void hpre_scale(float* __restrict__ tmp, const float* __restrict__ relsum,
                           const float* __restrict__ inv, long n) {
    long i = (long)blockIdx.x * 256 + threadIdx.x;
    if (i >= n) return;
    int v = (int)(i / H_DIM);
    tmp[i] = (tmp[i] + relsum[i]) * inv[v];
}

// g3 = rg * g3 + b_ih[400 + j]
__global__ void ew_nhat(float* __restrict__ g3, const float* __restrict__ rg,
                        const float* __restrict__ b_ih, long n) {
    long i = (long)blockIdx.x * 256 + threadIdx.x;
    if (i >= n) return;
    int j = (int)(i % H_DIM);
    g3[i] = rg[i] * g3[i] + b_ih[400 + j];
}

// prev = l2norm((1-zg)*tanh(g3) + zg*prev) per row
__global__ __launch_bounds__(64) void gru_final(
    float* __restrict__ prev, const float* __restrict__ g3, const float* __restrict__ zg)
{
    int v = blockIdx.x;
    int lane = threadIdx.x;
    float vals[4]; float ss = 0.f;
    #pragma unroll
    for (int t = 0; t < 4; t++) {
        int j = lane + t * 64;
        float p = 0.f;
        if (j < H_DIM) {
            long idx = (long)v * H_DIM + j;
            float z = zg[idx];
            float cand = tanhf(g3[idx]);
            p = (1.f - z) * cand + z * prev[idx];
        }
        vals[t] = p; ss += p * p;
    }
    ss = wave_sum64(ss);
    float r = 1.f / fmaxf(sqrtf(ss), 1e-12f);
    #pragma unroll
    for (int t = 0; t < 4; t++) {
        int j = lane + t * 64;
        if (j < H_DIM) prev[(long)v * H_DIM + j] = vals[t] * r;
    }
}

// ---------------------------------------------------------------- batch head

__global__ void gather_qs_qr(float* __restrict__ qs, float* __restrict__ qr,
                             const float* __restrict__ out, const float* __restrict__ reln,
                             const int* __restrict__ data)
{
    long i = (long)blockIdx.x * 256 + threadIdx.x;
    if (i >= (long)BATCH * H_DIM) return;
    int b = (int)(i / H_DIM), j = (int)(i % H_DIM);
    qs[i] = out[(long)data[b * 4 + 0] * H_DIM + j];
    qr[i] = reln[(long)data[b * 4 + 1] * H_DIM + j];
}

// semb[(k*BATCH+b), :] = l2norm( sum_{l<ln} out[his_idx[b,k,l],:] / max(ln,1) )
__global__ __launch_bounds__(64) void semb_kernel(
    float* __restrict__ semb, const float* __restrict__ out,
    const int* __restrict__ his_idx, const int* __restrict__ his_len)
{
    int b = blockIdx.x, k = blockIdx.y;
    int lane = threadIdx.x;
    int ln = his_len[b * 3 + k];
    if (ln > L_HIST) ln = L_HIST;
    float vals[4] = {0.f, 0.f, 0.f, 0.f};
    for (int l = 0; l < ln; l++) {
        int idx = his_idx[((long)b * 3 + k) * L_HIST + l];
        #pragma unroll
        for (int t = 0; t < 4; t++) {
            int j = lane + t * 64;
            if (j < H_DIM) vals[t] += out[(long)idx * H_DIM + j];
        }
    }
    float scale = 1.f / fmaxf((float)ln, 1.f);
    float ss = 0.f;
    #pragma unroll
    for (int t = 0; t < 4; t++) { vals[t] *= scale; ss += vals[t] * vals[t]; }
    ss = wave_sum64(ss);
    float r = 1.f / fmaxf(sqrtf(ss), 1e-12f);
    #pragma unroll
    for (int t = 0; t < 4; t++) {
        int j = lane + t * 64;
        if (j < H_DIM) semb[((long)k * BATCH + b) * H_DIM + j] = vals[t] * r;
    }
}

__global__ void tenc_batch(float* __restrict__ teb, const int* __restrict__ his_len,
                           const float* __restrict__ af, const float* __restrict__ ap,
                           const float* __restrict__ cf, const float* __restrict__ cp)
{
    int idx = blockIdx.x * 256 + threadIdx.x;
    if (idx >= 3 * BATCH * TD_DIM) return;
    int k = idx / (BATCH * TD_DIM);
    int rem = idx - k * (BATCH * TD_DIM);
    int b = rem / TD_DIM, j = rem % TD_DIM;
    int ln = his_len[b * 3 + k];
    float t = (ln > 0) ? (float)(2 - k) : 100.0f;
    float val;
    if (j < HD_DIM) val = tanhf((t + 1.f) * af[j] + ap[j]);
    else            val = cosf(t * cf[j - HD_DIM] + cp[j - HD_DIM]);
    teb[idx] = val;
}

__global__ __launch_bounds__(64) void att_logits(
    float* __restrict__ atts, const float* __restrict__ a,
    const float* __restrict__ Wc_w, const float* __restrict__ Wc_b, int k)
{
    int b = blockIdx.x;
    int lane = threadIdx.x;
    float s = 0.f;
    for (int j = lane; j < H_DIM; j += 64) s += a[(long)b * H_DIM + j] * Wc_w[j];
    s = wave_sum64(s);
    if (lane == 0) atts[b * 3 + k] = s + Wc_b[0];
}

__global__ void softmax_out2(float* __restrict__ out2, const float* __restrict__ atts,
                             const float* __restrict__ semb)
{
    long i = (long)blockIdx.x * 256 + threadIdx.x;
    if (i >= (long)BATCH * H_DIM) return;
    int b = (int)(i / H_DIM), j = (int)(i % H_DIM);
    float l0 = atts[b * 3 + 0], l1 = atts[b * 3 + 1], l2 = atts[b * 3 + 2];
    float m = fmaxf(l0, fmaxf(l1, l2));
    float e0 = expf(l0 - m), e1 = expf(l1 - m), e2 = expf(l2 - m);
    float s = e0 + e1 + e2;
    float v = (e0 * semb[((long)0 * BATCH + b) * H_DIM + j] +
               e1 * semb[((long)1 * BATCH + b) * H_DIM + j] +
               e2 * semb[((long)2 * BATCH + b) * H_DIM + j]) / s;
    out2[i] = v;
}

// ---------------------------------------------------------------- launch

extern "C" void kernel_launch(void* const* d_in, const int* in_sizes, int n_in,
                              void* d_out, int out_size, void* d_ws, size_t ws_size,
                              hipStream_t stream)
{
    (void)in_sizes; (void)n_in; (void)out_size; (void)ws_size;

    const int*   src     = (const int*)d_in[0];
    const int*   dst     = (const int*)d_in[1];
    const int*   etype   = (const int*)d_in[2];
    const int*   data    = (const int*)d_in[3];
    const int*   his_idx = (const int*)d_in[4];
    const int*   his_len = (const int*)d_in[5];
    const float* ent     = (const float*)d_in[6];
    const float* loop_w  = (const float*)d_in[7];
    const float* rel     = (const float*)d_in[8];
    const float* af      = (const float*)d_in[9];
    const float* ap      = (const float*)d_in[10];
    const float* cf      = (const float*)d_in[11];
    const float* cp      = (const float*)d_in[12];
    const float* Wn      = (const float*)d_in[13];
    const float* Ws      = (const float*)d_in[14];
    const float* W_ih    = (const float*)d_in[15];
    const float* W_hh    = (const float*)d_in[16];
    const float* b_ih    = (const float*)d_in[17];
    const float* b_hh    = (const float*)d_in[18];
    const float* Wb_w    = (const float*)d_in[19];
    const float* Wb_b    = (const float*)d_in[20];
    const float* Wc_w    = (const float*)d_in[21];
    const float* Wc_b    = (const float*)d_in[22];
    const float* Wd_w    = (const float*)d_in[23];
    const float* Wd_b    = (const float*)d_in[24];
    float* out_p = (float*)d_out;

    float* wp = (float*)d_ws;
    size_t off = 0;
    auto alloc = [&](size_t n) { float* p = wp + off; off += n; return p; };
    const long nE200 = (long)NUM_E * H_DIM;            // 4,000,000
    float* prev   = alloc(nE200);
    float* h      = alloc(nE200);
    float* tmp    = alloc(nE200);  // also GRU rg
    float* relsum = alloc(nE200);  // also GRU zg
    float* g3     = alloc(nE200);  // also GRU nhat
    float* te     = alloc((size_t)NUM_E * TD_DIM);
    float* deg    = alloc(NUM_E);
    float* invd   = alloc(NUM_E);
    float* reln   = alloc(400 * H_DIM);
    float* qs     = alloc(BATCH * H_DIM);
    float* qr     = alloc(BATCH * H_DIM);
    float* semb   = alloc(3 * BATCH * H_DIM);
    float* teb    = alloc(3 * BATCH * TD_DIM);
    float* abuf   = alloc(BATCH * H_DIM);
    float* atts   = alloc(2048);
    float* out2   = alloc(BATCH * H_DIM);
    float* qbuf   = alloc(BATCH * H_DIM);

    auto nblk = [](long n) { return (unsigned)((n + 255) / 256); };
    auto fill = [&](float* p, long n, float v) {
        fill_f32<<<nblk(n), 256, 0, stream>>>(p, n, v);
    };
    auto bias2 = [&](float* C, long rows, const float* b1, const float* b2) {
        long n = rows * H_DIM;
        fill_bias2<<<nblk(n), 256, 0, stream>>>(C, n, H_DIM, b1, b2);
    };
    auto gemm_bt = [&](float* C, const float* A, const float* B,
                       int M, int N, int K, int lda, int ldb, int ldc) {
        dim3 grid((M + 31) / 32, (N + 31) / 32);
        gemm_acc_k<1><<<grid, 256, 0, stream>>>(C, A, B, M, N, K, lda, ldb, ldc);
    };
    auto gemm_bn = [&](float* C, const float* A, const float* B,
                       int M, int N, int K, int lda, int ldb, int ldc) {
        dim3 grid((M + 31) / 32, (N + 31) / 32);
        gemm_acc_k<0><<<grid, 256, 0, stream>>>(C, A, B, M, N, K, lda, ldb, ldc);
    };

    // rel_n = l2norm(rel)
    l2norm_rows<<<400, 64, 0, stream>>>(reln, rel);

    // prev = l2norm(ent @ loop_weight)
    fill(g3, nE200, 0.f);
    gemm_bn(g3, ent, loop_w, NUM_E, H_DIM, H_DIM, H_DIM, H_DIM, H_DIM);
    l2norm_rows<<<NUM_E, 64, 0, stream>>>(prev, g3);

    const unsigned scat_blocks = (unsigned)(((long)E_EDGES * 64 + 255) / 256);

    for (int i = 0; i < N_HIST; i++) {
        const int* si = src   + (long)i * E_EDGES;
        const int* di = dst   + (long)i * E_EDGES;
        const int* ei = etype + (long)i * E_EDGES;
        float tcnt = (float)(N_HIST - 1 - i);

        fill(deg, NUM_E, 0.f);
        deg_count<<<nblk(E_EDGES), 256, 0, stream>>>(di, deg, E_EDGES);
        inv_deg<<<nblk(NUM_E), 256, 0, stream>>>(deg, invd, NUM_E);

        // agg -> h
        fill(tmp, nE200, 0.f);
        scatter_add_rows<<<scat_blocks, 256, 0, stream>>>(tmp, prev, si, di, E_EDGES);
        norm_agg<<<NUM_E, 64, 0, stream>>>(h, tmp, deg, invd);

        tenc_ent<<<nblk((long)NUM_E * TD_DIM), 256, 0, stream>>>(te, deg, af, ap, cf, cp, tcnt, NUM_E);

        // relsum = segment_sum(rel_n[ei], di)   (layer-independent)
        fill(relsum, nE200, 0.f);
        scatter_add_rows<<<scat_blocks, 256, 0, stream>>>(relsum, reln, ei, di, E_EDGES);

        // 2 RGCN layers:  h = relu( ((segsum(h[si]) + relsum)*inv) @ Wn[l] + h @ Ws[l] )
        for (int l = 0; l < 2; l++) {
            fill(tmp, nE200, 0.f);
            scatter_add_rows<<<scat_blocks, 256, 0, stream>>>(tmp, h, si, di, E_EDGES);
            hpre_scale<<<nblk(nE200), 256, 0, stream>>>(tmp, relsum, invd, nE200);
            fill(g3, nE200, 0.f);
            gemm_bn(g3, tmp, Wn + (long)l * H_DIM * H_DIM, NUM_E, H_DIM, H_DIM, H_DIM, H_DIM, H_DIM);
            gemm_bn(g3, h,   Ws + (long)l * H_DIM * H_DIM, NUM_E, H_DIM, H_DIM, H_DIM, H_DIM, H_DIM);
            relu_copy<<<nblk(nE200), 256, 0, stream>>>(h, g3, nE200);
        }

        // h = l2norm(h) after the RGCN layers (reference: h = _l2n(h))
        l2norm_rows<<<NUM_E, 64, 0, stream>>>(h, h);

        // GRU:  rg in tmp, zg in relsum, nhat in g3
        float* rg = tmp; float* zg = relsum; float* gn = g3;

        bias2(rg, NUM_E, b_ih + 0, b_hh + 0);
        gemm_bt(rg, h,    W_ih,                 NUM_E, H_DIM, H_DIM, H_DIM, 248, H_DIM);
        gemm_bt(rg, te,   W_ih + 200,           NUM_E, H_DIM, TD_DIM, TD_DIM, 248, H_DIM);
        gemm_bt(rg, prev, W_hh,                 NUM_E, H_DIM, H_DIM, H_DIM, H_DIM, H_DIM);
        sigmoid_inplace<<<nblk(nE200), 256, 0, stream>>>(rg, nE200);

        bias2(gn, NUM_E, b_hh + 400, nullptr);
        gemm_bt(gn, prev, W_hh + 400 * 200,     NUM_E, H_DIM, H_DIM, H_DIM, H_DIM, H_DIM);
        ew_nhat<<<nblk(nE200), 256, 0, stream>>>(gn, rg, b_ih, nE200);   // gn = rg*hN + b_ih[400:]
        gemm_bt(gn, h,    W_ih + 400 * 248,       NUM_E, H_DIM, H_DIM, H_DIM, 248, H_DIM);
        gemm_bt(gn, te,   W_ih + 400 * 248 + 200, NUM_E, H_DIM, TD_DIM, TD_DIM, 248, H_DIM);

        bias2(zg, NUM_E, b_ih + 200, b_hh + 200);
        gemm_bt(zg, h,    W_ih + 200 * 248,       NUM_E, H_DIM, H_DIM, H_DIM, 248, H_DIM);
        gemm_bt(zg, te,   W_ih + 200 * 248 + 200, NUM_E, H_DIM, TD_DIM, TD_DIM, 248, H_DIM);
        gemm_bt(zg, prev, W_hh + 200 * 200,       NUM_E, H_DIM, H_DIM, H_DIM, H_DIM, H_DIM);
        sigmoid_inplace<<<nblk(nE200), 256, 0, stream>>>(zg, nE200);

        gru_final<<<NUM_E, 64, 0, stream>>>(prev, gn, zg);
    }

    // ---- batch head ----
    gather_qs_qr<<<nblk((long)BATCH * H_DIM), 256, 0, stream>>>(qs, qr, prev, reln, data);
    semb_kernel<<<dim3(BATCH, 3), 64, 0, stream>>>(semb, prev, his_idx, his_len);
    tenc_batch<<<nblk(3L * BATCH * TD_DIM), 256, 0, stream>>>(teb, his_len, af, ap, cf, cp);

    for (int k = 0; k < 3; k++) {
        const float* sk = semb + (long)k * BATCH * H_DIM;
        const float* tk = teb  + (long)k * BATCH * TD_DIM;
        bias2(abuf, BATCH, Wb_b, nullptr);
        gemm_bt(abuf, qs, Wb_w + 0,   BATCH, H_DIM, H_DIM, H_DIM, 648, H_DIM);
        gemm_bt(abuf, qr, Wb_w + 200, BATCH, H_DIM, H_DIM, H_DIM, 648, H_DIM);
        gemm_bt(abuf, sk, Wb_w + 400, BATCH, H_DIM, H_DIM, H_DIM, 648, H_DIM);
        gemm_bt(abuf, tk, Wb_w + 600, BATCH, H_DIM, TD_DIM, TD_DIM, 648, H_DIM);
        relu_copy<<<nblk((long)BATCH * H_DIM), 256, 0, stream>>>(abuf, abuf, (long)BATCH * H_DIM);
        att_logits<<<BATCH, 64, 0, stream>>>(atts, abuf, Wc_w, Wc_b, k);
    }
    softmax_out2<<<nblk((long)BATCH * H_DIM), 256, 0, stream>>>(out2, atts, semb);

    bias2(qbuf, BATCH, Wd_b, nullptr);
    gemm_bt(qbuf, qs,   Wd_w + 0,   BATCH, H_DIM, H_DIM, H_DIM, 600, H_DIM);
    gemm_bt(qbuf, qr,   Wd_w + 200, BATCH, H_DIM, H_DIM, H_DIM, 600, H_DIM);
    gemm_bt(qbuf, out2, Wd_w + 400, BATCH, H_DIM, H_DIM, H_DIM, 600, H_DIM);
    relu_copy<<<nblk((long)BATCH * H_DIM), 256, 0, stream>>>(qbuf, qbuf, (long)BATCH * H_DIM);

    // result = q @ out^T  -> (512, 20000)
    fill(out_p, (long)BATCH * NUM_E, 0.f);
    gemm_bt(out_p, qbuf, prev, BATCH, NUM_E, H_DIM, H_DIM, H_DIM, NUM_E);
}

// Round 3
// 4143.289 us; speedup vs baseline: 2.5563x; 2.5563x over previous
//
#include <hip/hip_runtime.h>
#include <hip/hip_bf16.h>

#define NUM_E   20000
#define H_DIM   200
#define TD_DIM  48
#define HD_DIM  24
#define L_HIST  32
#define N_HIST  3
#define E_EDGES 200000
#define BATCH   512

// ---------------------------------------------------------------- utilities

__device__ inline float wave_sum64(float x) {
    #pragma unroll
    for (int m = 1; m < 64; m <<= 1) x += __shfl_xor(x, m);
    return x;
}

__global__ void fill_i32(int* __restrict__ p, long n, int v) {
    long i = (long)blockIdx.x * blockDim.x + threadIdx.x;
    if (i < n) p[i] = v;
}

// C[m, j] = b1[j] (+ b2[j]) broadcast over rows; dense ldc == N
__global__ void fill_bias2(float* __restrict__ C, long n, int N,
                           const float* __restrict__ b1, const float* __restrict__ b2) {
    long i = (long)blockIdx.x * blockDim.x + threadIdx.x;
    if (i >= n) return;
    int j = (int)(i % N);
    float v = b1 ? b1[j] : 0.f;
    if (b2) v += b2[j];
    C[i] = v;
}

__global__ void relu_copy(float* __restrict__ dst, const float* __restrict__ src, long n) {
    long i = (long)blockIdx.x * blockDim.x + threadIdx.x;
    if (i < n) dst[i] = fmaxf(src[i], 0.f);
}

__global__ void sigmoid_inplace(float* __restrict__ p, long n) {
    long i = (long)blockIdx.x * blockDim.x + threadIdx.x;
    if (i < n) p[i] = 1.f / (1.f + expf(-p[i]));
}

// ---------------------------------------------------------------- GEMM
// ACC=1: C += A @ op(B); ACC=0: C = A @ op(B).
// BT=1: B is (N,K) row-major (A @ B^T). BT=0: B is (K,N) row-major.
template<int BT, int ACC>
__global__ __launch_bounds__(256) void gemm_acc_k(
    float* __restrict__ C, const float* __restrict__ A, const float* __restrict__ B,
    int M, int N, int K, int lda, int ldb, int ldc)
{
    __shared__ float As[32][33];
    __shared__ float Bs[32][33];
    const int bm = blockIdx.x * 32;
    const int bn = blockIdx.y * 32;
    const int tid = threadIdx.x;
    const int tx = tid & 15;
    const int ty = tid >> 4;
    const int r0 = ty * 2, c0 = tx * 2;
    float acc00 = 0.f, acc01 = 0.f, acc10 = 0.f, acc11 = 0.f;

    for (int k0 = 0; k0 < K; k0 += 32) {
        for (int i = tid; i < 1024; i += 256) {
            int r = i >> 5, c = i & 31;
            int gm = bm + r, gk = k0 + c;
            As[r][c] = (gm < M && gk < K) ? A[(long)gm * lda + gk] : 0.f;
        }
        if (BT) {
            for (int i = tid; i < 1024; i += 256) {
                int nn = i >> 5, kk = i & 31;
                int gn = bn + nn, gk = k0 + kk;
                Bs[kk][nn] = (gn < N && gk < K) ? B[(long)gn * ldb + gk] : 0.f;
            }
        } else {
            for (int i = tid; i < 1024; i += 256) {
                int kk = i >> 5, nn = i & 31;
                int gk = k0 + kk, gn = bn + nn;
                Bs[kk][nn] = (gk < K && gn < N) ? B[(long)gk * ldb + gn] : 0.f;
            }
        }
        __syncthreads();
        #pragma unroll
        for (int kk = 0; kk < 32; kk++) {
            float a0 = As[r0][kk], a1 = As[r0 + 1][kk];
            float b0 = Bs[kk][c0], b1 = Bs[kk][c0 + 1];
            acc00 += a0 * b0; acc01 += a0 * b1;
            acc10 += a1 * b0; acc11 += a1 * b1;
        }
        __syncthreads();
    }
    int gm0 = bm + r0, gn0 = bn + c0;
    if (gm0 < M) {
        if (gn0 < N)     { float* p = &C[(long)gm0 * ldc + gn0];     *p = ACC ? *p + acc00 : acc00; }
        if (gn0 + 1 < N) { float* p = &C[(long)gm0 * ldc + gn0 + 1]; *p = ACC ? *p + acc01 : acc01; }
    }
    if (gm0 + 1 < M) {
        if (gn0 < N)     { float* p = &C[(long)(gm0 + 1) * ldc + gn0];     *p = ACC ? *p + acc10 : acc10; }
        if (gn0 + 1 < N) { float* p = &C[(long)(gm0 + 1) * ldc + gn0 + 1]; *p = ACC ? *p + acc11 : acc11; }
    }
}

// ---------------------------------------------------------------- CSR build

__global__ void count_dst(const int* __restrict__ di, int* __restrict__ cnt, int E) {
    int e = blockIdx.x * 256 + threadIdx.x;
    if (e < E) atomicAdd(&cnt[di[e]], 1);
}

// single-workgroup scan over NUM_E counts -> row_start, cursor, degf, invd
__global__ __launch_bounds__(1024) void scan_rows(
    const int* __restrict__ cnt, int* __restrict__ row_start, int* __restrict__ cursor,
    float* __restrict__ degf, float* __restrict__ invd)
{
    __shared__ int part[1024];
    const int CH = (NUM_E + 1023) / 1024;   // 20
    int t = threadIdx.x;
    int base = t * CH;
    int local[32];
    int s = 0;
    for (int j = 0; j < CH; j++) {
        int idx = base + j;
        int c = (idx < NUM_E) ? cnt[idx] : 0;
        local[j] = s; s += c;
    }
    part[t] = s;
    __syncthreads();
    for (int off = 1; off < 1024; off <<= 1) {
        int v = (t >= off) ? part[t - off] : 0;
        __syncthreads();
        part[t] += v;
        __syncthreads();
    }
    int pre = (t == 0) ? 0 : part[t - 1];
    for (int j = 0; j < CH; j++) {
        int idx = base + j;
        if (idx < NUM_E) {
            int rs = pre + local[j];
            row_start[idx] = rs;
            cursor[idx] = rs;
            int c = cnt[idx];
            degf[idx] = (float)c;
            invd[idx] = 1.f / fmaxf((float)c, 1.f);
        }
    }
    if (t == 1023) row_start[NUM_E] = part[1023];
}

__global__ void build_perm(const int* __restrict__ si, const int* __restrict__ di,
                           const int* __restrict__ ei, int* __restrict__ cursor,
                           int* __restrict__ ssrc, int* __restrict__ setype, int E)
{
    int e = blockIdx.x * 256 + threadIdx.x;
    if (e >= E) return;
    int pos = atomicAdd(&cursor[di[e]], 1);
    ssrc[pos]   = si[e];
    setype[pos] = ei[e];
}

// ---------------------------------------------------------------- gathers

// h[v,:] = l2norm( (sum_{e in seg(v)} prev[ssrc[e],:]) * inv_v )   (0 if empty)
__global__ __launch_bounds__(256) void seg_gather_norm(
    float* __restrict__ h, const float* __restrict__ prev,
    const int* __restrict__ ssrc, const int* __restrict__ row_start,
    const float* __restrict__ invd)
{
    int v = blockIdx.x * 4 + (threadIdx.x >> 6);
    int lane = threadIdx.x & 63;
    if (v >= NUM_E) return;
    int s0 = row_start[v], s1 = row_start[v + 1];
    bool act = lane < 50;
    float4 acc = {0.f, 0.f, 0.f, 0.f};
    for (int j = s0; j < s1; j++) {
        int s = ssrc[j];
        if (act) {
            float4 x = *(const float4*)(prev + (long)s * H_DIM + lane * 4);
            acc.x += x.x; acc.y += x.y; acc.z += x.z; acc.w += x.w;
        }
    }
    float iv = invd[v];
    acc.x *= iv; acc.y *= iv; acc.z *= iv; acc.w *= iv;
    float ss = act ? (acc.x*acc.x + acc.y*acc.y + acc.z*acc.z + acc.w*acc.w) : 0.f;
    ss = wave_sum64(ss);
    float r = 1.f / fmaxf(sqrtf(ss), 1e-12f);
    if (act) {
        float4 o = {acc.x * r, acc.y * r, acc.z * r, acc.w * r};
        *(float4*)(h + (long)v * H_DIM + lane * 4) = o;
    }
}

// tmp[v,:] = (sum_{e in seg(v)} (h[ssrc[e],:] + reln[setype[e],:])) * inv_v
__global__ __launch_bounds__(256) void seg_gather_layer(
    float* __restrict__ tmp, const float* __restrict__ h, const float* __restrict__ reln,
    const int* __restrict__ ssrc, const int* __restrict__ setype,
    const int* __restrict__ row_start, const float* __restrict__ invd)
{
    int v = blockIdx.x * 4 + (threadIdx.x >> 6);
    int lane = threadIdx.x & 63;
    if (v >= NUM_E) return;
    int s0 = row_start[v], s1 = row_start[v + 1];
    bool act = lane < 50;
    float4 acc = {0.f, 0.f, 0.f, 0.f};
    for (int j = s0; j < s1; j++) {
        int s = ssrc[j];
        int t = setype[j];
        if (act) {
            float4 x = *(const float4*)(h    + (long)s * H_DIM + lane * 4);
            float4 y = *(const float4*)(reln + (long)t * H_DIM + lane * 4);
            acc.x += x.x + y.x; acc.y += x.y + y.y;
            acc.z += x.z + y.z; acc.w += x.w + y.w;
        }
    }
    float iv = invd[v];
    if (act) {
        float4 o = {acc.x * iv, acc.y * iv, acc.z * iv, acc.w * iv};
        *(float4*)(tmp + (long)v * H_DIM + lane * 4) = o;
    }
}

// ---------------------------------------------------------------- row kernels

__global__ __launch_bounds__(64) void l2norm_rows(
    float* __restrict__ out, const float* __restrict__ in)
{
    int v = blockIdx.x;
    int lane = threadIdx.x;
    float vals[4]; float ss = 0.f;
    #pragma unroll
    for (int t = 0; t < 4; t++) {
        int j = lane + t * 64;
        float x = (j < H_DIM) ? in[(long)v * H_DIM + j] : 0.f;
        vals[t] = x; ss += x * x;
    }
    ss = wave_sum64(ss);
    float r = 1.f / fmaxf(sqrtf(ss), 1e-12f);
    #pragma unroll
    for (int t = 0; t < 4; t++) {
        int j = lane + t * 64;
        if (j < H_DIM) out[(long)v * H_DIM + j] = vals[t] * r;
    }
}

__global__ void tenc_ent(float* __restrict__ te, const float* __restrict__ deg,
                         const float* __restrict__ af, const float* __restrict__ ap,
                         const float* __restrict__ cf, const float* __restrict__ cp,
                         float tcnt, int M)
{
    int idx = blockIdx.x * 256 + threadIdx.x;
    if (idx >= M * TD_DIM) return;
    int v = idx / TD_DIM, j = idx % TD_DIM;
    float t = (deg[v] > 0.f) ? tcnt : 100.0f;
    float val;
    if (j < HD_DIM) val = tanhf((t + 1.f) * af[j] + ap[j]);
    else            val = cosf(t * cf[j - HD_DIM] + cp[j - HD_DIM]);
    te[idx] = val;
}

// g3 = rg * g3 + b_ih[400 + j]
__global__ void ew_nhat(float* __restrict__ g3, const float* __restrict__ rg,
                        const float* __restrict__ b_ih, long n) {
    long i = (long)blockIdx.x * 256 + threadIdx.x;
    if (i >= n) return;
    int j = (int)(i % H_DIM);
    g3[i] = rg[i] * g3[i] + b_ih[400 + j];
}

// prev = l2norm((1-zg)*tanh(g3) + zg*prev) per row
__global__ __launch_bounds__(64) void gru_final(
    float* __restrict__ prev, const float* __restrict__ g3, const float* __restrict__ zg)
{
    int v = blockIdx.x;
    int lane = threadIdx.x;
    float vals[4]; float ss = 0.f;
    #pragma unroll
    for (int t = 0; t < 4; t++) {
        int j = lane + t * 64;
        float p = 0.f;
        if (j < H_DIM) {
            long idx = (long)v * H_DIM + j;
            float z = zg[idx];
            float cand = tanhf(g3[idx]);
            p = (1.f - z) * cand + z * prev[idx];
        }
        vals[t] = p; ss += p * p;
    }
    ss = wave_sum64(ss);
    float r = 1.f / fmaxf(sqrtf(ss), 1e-12f);
    #pragma unroll
    for (int t = 0; t < 4; t++) {
        int j = lane + t * 64;
        if (j < H_DIM) prev[(long)v * H_DIM + j] = vals[t] * r;
    }
}

// ---------------------------------------------------------------- batch head

__global__ void gather_qs_qr(float* __restrict__ qs, float* __restrict__ qr,
                             const float* __restrict__ out, const float* __restrict__ reln,
                             const int* __restrict__ data)
{
    long i = (long)blockIdx.x * 256 + threadIdx.x;
    if (i >= (long)BATCH * H_DIM) return;
    int b = (int)(i / H_DIM), j = (int)(i % H_DIM);
    qs[i] = out[(long)data[b * 4 + 0] * H_DIM + j];
    qr[i] = reln[(long)data[b * 4 + 1] * H_DIM + j];
}

__global__ __launch_bounds__(64) void semb_kernel(
    float* __restrict__ semb, const float* __restrict__ out,
    const int* __restrict__ his_idx, const int* __restrict__ his_len)
{
    int b = blockIdx.x, k = blockIdx.y;
    int lane = threadIdx.x;
    int ln = his_len[b * 3 + k];
    if (ln > L_HIST) ln = L_HIST;
    float vals[4] = {0.f, 0.f, 0.f, 0.f};
    for (int l = 0; l < ln; l++) {
        int idx = his_idx[((long)b * 3 + k) * L_HIST + l];
        #pragma unroll
        for (int t = 0; t < 4; t++) {
            int j = lane + t * 64;
            if (j < H_DIM) vals[t] += out[(long)idx * H_DIM + j];
        }
    }
    float scale = 1.f / fmaxf((float)ln, 1.f);
    float ss = 0.f;
    #pragma unroll
    for (int t = 0; t < 4; t++) { vals[t] *= scale; ss += vals[t] * vals[t]; }
    ss = wave_sum64(ss);
    float r = 1.f / fmaxf(sqrtf(ss), 1e-12f);
    #pragma unroll
    for (int t = 0; t < 4; t++) {
        int j = lane + t * 64;
        if (j < H_DIM) semb[((long)k * BATCH + b) * H_DIM + j] = vals[t] * r;
    }
}

__global__ void tenc_batch(float* __restrict__ teb, const int* __restrict__ his_len,
                           const float* __restrict__ af, const float* __restrict__ ap,
                           const float* __restrict__ cf, const float* __restrict__ cp)
{
    int idx = blockIdx.x * 256 + threadIdx.x;
    if (idx >= 3 * BATCH * TD_DIM) return;
    int k = idx / (BATCH * TD_DIM);
    int rem = idx - k * (BATCH * TD_DIM);
    int b = rem / TD_DIM, j = rem % TD_DIM;
    int ln = his_len[b * 3 + k];
    float t = (ln > 0) ? (float)(2 - k) : 100.0f;
    float val;
    if (j < HD_DIM) val = tanhf((t + 1.f) * af[j] + ap[j]);
    else            val = cosf(t * cf[j - HD_DIM] + cp[j - HD_DIM]);
    teb[idx] = val;
}

__global__ __launch_bounds__(64) void att_logits(
    float* __restrict__ atts, const float* __restrict__ a,
    const float* __restrict__ Wc_w, const float* __restrict__ Wc_b, int k)
{
    int b = blockIdx.x;
    int lane = threadIdx.x;
    float s = 0.f;
    for (int j = lane; j < H_DIM; j += 64) s += a[(long)b * H_DIM + j] * Wc_w[j];
    s = wave_sum64(s);
    if (lane == 0) atts[b * 3 + k] = s + Wc_b[0];
}

__global__ void softmax_out2(float* __restrict__ out2, const float* __restrict__ atts,
                             const float* __restrict__ semb)
{
    long i = (long)blockIdx.x * 256 + threadIdx.x;
    if (i >= (long)BATCH * H_DIM) return;
    int b = (int)(i / H_DIM), j = (int)(i % H_DIM);
    float l0 = atts[b * 3 + 0], l1 = atts[b * 3 + 1], l2 = atts[b * 3 + 2];
    float m = fmaxf(l0, fmaxf(l1, l2));
    float e0 = expf(l0 - m), e1 = expf(l1 - m), e2 = expf(l2 - m);
    float s = e0 + e1 + e2;
    float v = (e0 * semb[((long)0 * BATCH + b) * H_DIM + j] +
               e1 * semb[((long)1 * BATCH + b) * H_DIM + j] +
               e2 * semb[((long)2 * BATCH + b) * H_DIM + j]) / s;
    out2[i] = v;
}

// ---------------------------------------------------------------- launch

extern "C" void kernel_launch(void* const* d_in, const int* in_sizes, int n_in,
                              void* d_out, int out_size, void* d_ws, size_t ws_size,
                              hipStream_t stream)
{
    (void)in_sizes; (void)n_in; (void)out_size; (void)ws_size;

    const int*   src     = (const int*)d_in[0];
    const int*   dst     = (const int*)d_in[1];
    const int*   etype   = (const int*)d_in[2];
    const int*   data    = (const int*)d_in[3];
    const int*   his_idx = (const int*)d_in[4];
    const int*   his_len = (const int*)d_in[5];
    const float* ent     = (const float*)d_in[6];
    const float* loop_w  = (const float*)d_in[7];
    const float* rel     = (const float*)d_in[8];
    const float* af      = (const float*)d_in[9];
    const float* ap      = (const float*)d_in[10];
    const float* cf      = (const float*)d_in[11];
    const float* cp      = (const float*)d_in[12];
    const float* Wn      = (const float*)d_in[13];
    const float* Ws      = (const float*)d_in[14];
    const float* W_ih    = (const float*)d_in[15];
    const float* W_hh    = (const float*)d_in[16];
    const float* b_ih    = (const float*)d_in[17];
    const float* b_hh    = (const float*)d_in[18];
    const float* Wb_w    = (const float*)d_in[19];
    const float* Wb_b    = (const float*)d_in[20];
    const float* Wc_w    = (const float*)d_in[21];
    const float* Wc_b    = (const float*)d_in[22];
    const float* Wd_w    = (const float*)d_in[23];
    const float* Wd_b    = (const float*)d_in[24];
    float* out_p = (float*)d_out;

    float* wp = (float*)d_ws;
    size_t off = 0;
    auto alloc = [&](size_t n) { float* p = wp + off; off += n; return p; };
    const long nE200 = (long)NUM_E * H_DIM;            // 4,000,000
    float* prev   = alloc(nE200);
    float* h      = alloc(nE200);
    float* tmp    = alloc(nE200);  // gather target / GRU rg
    float* zgbuf  = alloc(nE200);  // GRU zg
    float* g3     = alloc(nE200);  // layer GEMM out / GRU nhat
    float* te     = alloc((size_t)NUM_E * TD_DIM);
    float* degf   = alloc(NUM_E);
    float* invd   = alloc(NUM_E);
    float* reln   = alloc(400 * H_DIM);
    float* qs     = alloc(BATCH * H_DIM);
    float* qr     = alloc(BATCH * H_DIM);
    float* semb   = alloc(3 * BATCH * H_DIM);
    float* teb    = alloc(3 * BATCH * TD_DIM);
    float* abuf   = alloc(BATCH * H_DIM);
    float* atts   = alloc(2048);
    float* out2   = alloc(BATCH * H_DIM);
    float* qbuf   = alloc(BATCH * H_DIM);
    // int scratch (CSR)
    int* cnt       = (int*)alloc(NUM_E);
    int* row_start = (int*)alloc(NUM_E + 4);
    int* cursor    = (int*)alloc(NUM_E);
    int* ssrc      = (int*)alloc(E_EDGES);
    int* setype    = (int*)alloc(E_EDGES);

    auto nblk = [](long n) { return (unsigned)((n + 255) / 256); };
    auto bias2 = [&](float* C, long rows, const float* b1, const float* b2) {
        long n = rows * H_DIM;
        fill_bias2<<<nblk(n), 256, 0, stream>>>(C, n, H_DIM, b1, b2);
    };
    auto gemm_bt = [&](float* C, const float* A, const float* B,
                       int M, int N, int K, int lda, int ldb, int ldc) {
        dim3 grid((M + 31) / 32, (N + 31) / 32);
        gemm_acc_k<1, 1><<<grid, 256, 0, stream>>>(C, A, B, M, N, K, lda, ldb, ldc);
    };
    auto gemm_bt_w = [&](float* C, const float* A, const float* B,
                         int M, int N, int K, int lda, int ldb, int ldc) {
        dim3 grid((M + 31) / 32, (N + 31) / 32);
        gemm_acc_k<1, 0><<<grid, 256, 0, stream>>>(C, A, B, M, N, K, lda, ldb, ldc);
    };
    auto gemm_bn = [&](float* C, const float* A, const float* B,
                       int M, int N, int K, int lda, int ldb, int ldc) {
        dim3 grid((M + 31) / 32, (N + 31) / 32);
        gemm_acc_k<0, 1><<<grid, 256, 0, stream>>>(C, A, B, M, N, K, lda, ldb, ldc);
    };
    auto gemm_bn_w = [&](float* C, const float* A, const float* B,
                         int M, int N, int K, int lda, int ldb, int ldc) {
        dim3 grid((M + 31) / 32, (N + 31) / 32);
        gemm_acc_k<0, 0><<<grid, 256, 0, stream>>>(C, A, B, M, N, K, lda, ldb, ldc);
    };

    // rel_n = l2norm(rel)
    l2norm_rows<<<400, 64, 0, stream>>>(reln, rel);

    // prev = l2norm(ent @ loop_weight)
    gemm_bn_w(g3, ent, loop_w, NUM_E, H_DIM, H_DIM, H_DIM, H_DIM, H_DIM);
    l2norm_rows<<<NUM_E, 64, 0, stream>>>(prev, g3);

    const unsigned gat_blocks = (NUM_E + 3) / 4;   // 4 waves (rows) per 256-block

    for (int i = 0; i < N_HIST; i++) {
        const int* si = src   + (long)i * E_EDGES;
        const int* di = dst   + (long)i * E_EDGES;
        const int* ei = etype + (long)i * E_EDGES;
        float tcnt = (float)(N_HIST - 1 - i);

        // ---- CSR build (counting sort by dst) ----
        fill_i32<<<nblk(NUM_E), 256, 0, stream>>>(cnt, NUM_E, 0);
        count_dst<<<nblk(E_EDGES), 256, 0, stream>>>(di, cnt, E_EDGES);
        scan_rows<<<1, 1024, 0, stream>>>(cnt, row_start, cursor, degf, invd);
        build_perm<<<nblk(E_EDGES), 256, 0, stream>>>(si, di, ei, cursor, ssrc, setype, E_EDGES);

        // ---- agg: h = l2norm(segsum(prev)*inv) ----
        seg_gather_norm<<<gat_blocks, 256, 0, stream>>>(h, prev, ssrc, row_start, invd);

        tenc_ent<<<nblk((long)NUM_E * TD_DIM), 256, 0, stream>>>(te, degf, af, ap, cf, cp, tcnt, NUM_E);

        // ---- 2 RGCN layers: h = relu(((segsum(h)+segsum(reln))*inv) @ Wn + h @ Ws) ----
        for (int l = 0; l < 2; l++) {
            seg_gather_layer<<<gat_blocks, 256, 0, stream>>>(tmp, h, reln, ssrc, setype, row_start, invd);
            gemm_bn_w(g3, tmp, Wn + (long)l * H_DIM * H_DIM, NUM_E, H_DIM, H_DIM, H_DIM, H_DIM, H_DIM);
            gemm_bn  (g3, h,   Ws + (long)l * H_DIM * H_DIM, NUM_E, H_DIM, H_DIM, H_DIM, H_DIM, H_DIM);
            relu_copy<<<nblk(nE200), 256, 0, stream>>>(h, g3, nE200);
        }

        // h = l2norm(h)
        l2norm_rows<<<NUM_E, 64, 0, stream>>>(h, h);

        // ---- GRU: rg in tmp, zg in zgbuf, nhat in g3 ----
        float* rg = tmp; float* zg = zgbuf; float* gn = g3;

        bias2(rg, NUM_E, b_ih + 0, b_hh + 0);
        gemm_bt(rg, h,    W_ih,                 NUM_E, H_DIM, H_DIM, H_DIM, 248, H_DIM);
        gemm_bt(rg, te,   W_ih + 200,           NUM_E, H_DIM, TD_DIM, TD_DIM, 248, H_DIM);
        gemm_bt(rg, prev, W_hh,                 NUM_E, H_DIM, H_DIM, H_DIM, H_DIM, H_DIM);
        sigmoid_inplace<<<nblk(nE200), 256, 0, stream>>>(rg, nE200);

        bias2(gn, NUM_E, b_hh + 400, nullptr);
        gemm_bt(gn, prev, W_hh + 400 * 200,     NUM_E, H_DIM, H_DIM, H_DIM, H_DIM, H_DIM);
        ew_nhat<<<nblk(nE200), 256, 0, stream>>>(gn, rg, b_ih, nE200);   // gn = rg*hN + b_ih[400:]
        gemm_bt(gn, h,    W_ih + 400 * 248,       NUM_E, H_DIM, H_DIM, H_DIM, 248, H_DIM);
        gemm_bt(gn, te,   W_ih + 400 * 248 + 200, NUM_E, H_DIM, TD_DIM, TD_DIM, 248, H_DIM);

        bias2(zg, NUM_E, b_ih + 200, b_hh + 200);
        gemm_bt(zg, h,    W_ih + 200 * 248,       NUM_E, H_DIM, H_DIM, H_DIM, 248, H_DIM);
        gemm_bt(zg, te,   W_ih + 200 * 248 + 200, NUM_E, H_DIM, TD_DIM, TD_DIM, 248, H_DIM);
        gemm_bt(zg, prev, W_hh + 200 * 200,       NUM_E, H_DIM, H_DIM, H_DIM, H_DIM, H_DIM);
        sigmoid_inplace<<<nblk(nE200), 256, 0, stream>>>(zg, nE200);

        gru_final<<<NUM_E, 64, 0, stream>>>(prev, gn, zg);
    }

    // ---- batch head ----
    gather_qs_qr<<<nblk((long)BATCH * H_DIM), 256, 0, stream>>>(qs, qr, prev, reln, data);
    semb_kernel<<<dim3(BATCH, 3), 64, 0, stream>>>(semb, prev, his_idx, his_len);
    tenc_batch<<<nblk(3L * BATCH * TD_DIM), 256, 0, stream>>>(teb, his_len, af, ap, cf, cp);

    for (int k = 0; k < 3; k++) {
        const float* sk = semb + (long)k * BATCH * H_DIM;
        const float* tk = teb  + (long)k * BATCH * TD_DIM;
        bias2(abuf, BATCH, Wb_b, nullptr);
        gemm_bt(abuf, qs, Wb_w + 0,   BATCH, H_DIM, H_DIM, H_DIM, 648, H_DIM);
        gemm_bt(abuf, qr, Wb_w + 200, BATCH, H_DIM, H_DIM, H_DIM, 648, H_DIM);
        gemm_bt(abuf, sk, Wb_w + 400, BATCH, H_DIM, H_DIM, H_DIM, 648, H_DIM);
        gemm_bt(abuf, tk, Wb_w + 600, BATCH, H_DIM, TD_DIM, TD_DIM, 648, H_DIM);
        relu_copy<<<nblk((long)BATCH * H_DIM), 256, 0, stream>>>(abuf, abuf, (long)BATCH * H_DIM);
        att_logits<<<BATCH, 64, 0, stream>>>(atts, abuf, Wc_w, Wc_b, k);
    }
    softmax_out2<<<nblk((long)BATCH * H_DIM), 256, 0, stream>>>(out2, atts, semb);

    bias2(qbuf, BATCH, Wd_b, nullptr);
    gemm_bt(qbuf, qs,   Wd_w + 0,   BATCH, H_DIM, H_DIM, H_DIM, 600, H_DIM);
    gemm_bt(qbuf, qr,   Wd_w + 200, BATCH, H_DIM, H_DIM, H_DIM, 600, H_DIM);
    gemm_bt(qbuf, out2, Wd_w + 400, BATCH, H_DIM, H_DIM, H_DIM, 600, H_DIM);
    relu_copy<<<nblk((long)BATCH * H_DIM), 256, 0, stream>>>(qbuf, qbuf, (long)BATCH * H_DIM);

    // result = q @ out^T  -> (512, 20000)
    gemm_bt_w(out_p, qbuf, prev, BATCH, NUM_E, H_DIM, H_DIM, H_DIM, NUM_E);
}

// Round 4
// 2494.764 us; speedup vs baseline: 4.2456x; 1.6608x over previous
//
#include <hip/hip_runtime.h>
#include <hip/hip_bf16.h>

#define NUM_E   20000
#define H_DIM   200
#define TD_DIM  48
#define HD_DIM  24
#define L_HIST  32
#define N_HIST  3
#define E_EDGES 200000
#define BATCH   512

// ---------------------------------------------------------------- utilities

__device__ inline float wave_sum64(float x) {
    #pragma unroll
    for (int m = 1; m < 64; m <<= 1) x += __shfl_xor(x, m);
    return x;
}

__global__ void fill_i32(int* __restrict__ p, long n, int v) {
    long i = (long)blockIdx.x * blockDim.x + threadIdx.x;
    if (i < n) p[i] = v;
}

// bsum[j] = b_ih[j] + b_hh[j]  (j < 600)
__global__ void bias_sum(float* __restrict__ bsum, const float* __restrict__ b_ih,
                         const float* __restrict__ b_hh) {
    int j = blockIdx.x * 256 + threadIdx.x;
    if (j < 600) bsum[j] = b_ih[j] + b_hh[j];
}

// ---------------------------------------------------------------- multi-segment GEMM
// C = act( sum_seg A_s @ op(B_s) + bias )
// BT=1: B_s is (N, Ks) row-major (A @ B^T). BT=0: B_s is (Ks, N) row-major.
// Tiles: BM=128, BN=64, BK=32; 256 threads; 8x4 micro-tile.
// All segment K sizes and N are multiples of 4.

struct Segs {
    const float* A[4];
    const float* B[4];
    int lda[4], ldb[4], Ks[4];
    int nseg, Ktot;
};

__device__ inline void seg_find(const Segs& sg, int gk, int& s, int& loc) {
    s = 0; loc = gk;
    #pragma unroll
    for (int t = 0; t < 3; t++) {
        if (s + 1 < sg.nseg && loc >= sg.Ks[s]) { loc -= sg.Ks[s]; s++; }
    }
}

// ACT: 0 = none, 1 = relu, 2 = sigmoid
template<int BT, int ACT>
__global__ __launch_bounds__(256) void sgemm_seg(
    float* __restrict__ C, const Segs sg, const float* __restrict__ bias,
    int M, int N, int ldc)
{
    __shared__ float As[32][132];   // [k][m]
    __shared__ float Bs[32][68];    // [k][n]
    const int bm = blockIdx.x * 128;
    const int bn = blockIdx.y * 64;
    const int tid = threadIdx.x;
    const int tm = tid >> 4;        // 0..15 -> m0 = tm*8
    const int tn = tid & 15;        // 0..15 -> n0 = tn*4
    const int m0 = tm * 8, n0 = tn * 4;

    float acc[8][4];
    #pragma unroll
    for (int i = 0; i < 8; i++)
        #pragma unroll
        for (int j = 0; j < 4; j++) acc[i][j] = 0.f;

    const int Ktot = sg.Ktot;
    const int ntile = (Ktot + 31) / 32;

    // staging indices
    const int a_kv = tid & 7;          // k4 = a_kv*4
    const int a_rb = (tid >> 3) * 4;   // rows a_rb .. a_rb+3
    const int b_nv = tid & 15;         // BT=0: n4 = b_nv*4
    const int b_kb = tid >> 4;         // BT=0: k rows b_kb, b_kb+16
    const int b_kv = tid & 7;          // BT=1: k4 = b_kv*4
    const int b_nb = tid >> 3;         // BT=1: n rows b_nb*2, +1

    for (int t = 0; t < ntile; t++) {
        const int k0 = t * 32;

        // ---- stage A (transposed into As[k][m]) ----
        {
            int gk = k0 + a_kv * 4;
            bool kin = gk < Ktot;
            int s = 0, loc = 0;
            if (kin) seg_find(sg, gk, s, loc);
            const float* Ab = sg.A[s];
            const int lda = sg.lda[s];
            #pragma unroll
            for (int r = 0; r < 4; r++) {
                int row = bm + a_rb + r;
                float4 v = {0.f, 0.f, 0.f, 0.f};
                if (kin && row < M) v = *(const float4*)(Ab + (size_t)row * lda + loc);
                As[a_kv*4 + 0][a_rb + r] = v.x;
                As[a_kv*4 + 1][a_rb + r] = v.y;
                As[a_kv*4 + 2][a_rb + r] = v.z;
                As[a_kv*4 + 3][a_rb + r] = v.w;
            }
        }

        // ---- stage B into Bs[k][n] ----
        if (BT) {
            int gk = k0 + b_kv * 4;
            bool kin = gk < Ktot;
            int s = 0, loc = 0;
            if (kin) seg_find(sg, gk, s, loc);
            const float* Bb = sg.B[s];
            const int ldb = sg.ldb[s];
            #pragma unroll
            for (int r = 0; r < 2; r++) {
                int n = b_nb * 2 + r;
                int gn = bn + n;
                float4 v = {0.f, 0.f, 0.f, 0.f};
                if (kin && gn < N) v = *(const float4*)(Bb + (size_t)gn * ldb + loc);
                Bs[b_kv*4 + 0][n] = v.x;
                Bs[b_kv*4 + 1][n] = v.y;
                Bs[b_kv*4 + 2][n] = v.z;
                Bs[b_kv*4 + 3][n] = v.w;
            }
        } else {
            #pragma unroll
            for (int r = 0; r < 2; r++) {
                int kk = b_kb + r * 16;
                int gk = k0 + kk;
                float4 v = {0.f, 0.f, 0.f, 0.f};
                if (gk < Ktot) {
                    int s, loc; seg_find(sg, gk, s, loc);
                    const float* Bb = sg.B[s];
                    const int ldb = sg.ldb[s];
                    int gn = bn + b_nv * 4;
                    if (gn + 3 < N) v = *(const float4*)(Bb + (size_t)loc * ldb + gn);
                    else if (gn < N) {
                        const float* p = Bb + (size_t)loc * ldb;
                        v.x = p[gn];
                        if (gn + 1 < N) v.y = p[gn + 1];
                        if (gn + 2 < N) v.z = p[gn + 2];
                    }
                }
                *(float4*)&Bs[kk][b_nv * 4] = v;
            }
        }

        __syncthreads();

        #pragma unroll 8
        for (int kk = 0; kk < 32; kk++) {
            float4 b = *(float4*)&Bs[kk][n0];
            float4 a0 = *(float4*)&As[kk][m0];
            float4 a1 = *(float4*)&As[kk][m0 + 4];
            float a[8] = {a0.x, a0.y, a0.z, a0.w, a1.x, a1.y, a1.z, a1.w};
            #pragma unroll
            for (int i = 0; i < 8; i++) {
                acc[i][0] += a[i] * b.x;
                acc[i][1] += a[i] * b.y;
                acc[i][2] += a[i] * b.z;
                acc[i][3] += a[i] * b.w;
            }
        }

        __syncthreads();
    }

    // ---- epilogue ----
    int col = bn + n0;
    if (col < N) {   // N % 4 == 0 -> full float4 in-bounds
        float4 bv = {0.f, 0.f, 0.f, 0.f};
        if (bias) bv = *(const float4*)(bias + col);
        #pragma unroll
        for (int i = 0; i < 8; i++) {
            int row = bm + m0 + i;
            if (row < M) {
                float4 o;
                o.x = acc[i][0] + bv.x;
                o.y = acc[i][1] + bv.y;
                o.z = acc[i][2] + bv.z;
                o.w = acc[i][3] + bv.w;
                if (ACT == 1) {
                    o.x = fmaxf(o.x, 0.f); o.y = fmaxf(o.y, 0.f);
                    o.z = fmaxf(o.z, 0.f); o.w = fmaxf(o.w, 0.f);
                } else if (ACT == 2) {
                    o.x = 1.f / (1.f + expf(-o.x)); o.y = 1.f / (1.f + expf(-o.y));
                    o.z = 1.f / (1.f + expf(-o.z)); o.w = 1.f / (1.f + expf(-o.w));
                }
                *(float4*)(C + (size_t)row * ldc + col) = o;
            }
        }
    }
}

// ---------------------------------------------------------------- CSR build

__global__ void count_dst(const int* __restrict__ di, int* __restrict__ cnt, int E) {
    int e = blockIdx.x * 256 + threadIdx.x;
    if (e < E) atomicAdd(&cnt[di[e]], 1);
}

__global__ __launch_bounds__(1024) void scan_rows(
    const int* __restrict__ cnt, int* __restrict__ row_start, int* __restrict__ cursor,
    float* __restrict__ degf, float* __restrict__ invd)
{
    __shared__ int part[1024];
    const int CH = (NUM_E + 1023) / 1024;   // 20
    int t = threadIdx.x;
    int base = t * CH;
    int local[32];
    int s = 0;
    for (int j = 0; j < CH; j++) {
        int idx = base + j;
        int c = (idx < NUM_E) ? cnt[idx] : 0;
        local[j] = s; s += c;
    }
    part[t] = s;
    __syncthreads();
    for (int off = 1; off < 1024; off <<= 1) {
        int v = (t >= off) ? part[t - off] : 0;
        __syncthreads();
        part[t] += v;
        __syncthreads();
    }
    int pre = (t == 0) ? 0 : part[t - 1];
    for (int j = 0; j < CH; j++) {
        int idx = base + j;
        if (idx < NUM_E) {
            int rs = pre + local[j];
            row_start[idx] = rs;
            cursor[idx] = rs;
            int c = cnt[idx];
            degf[idx] = (float)c;
            invd[idx] = 1.f / fmaxf((float)c, 1.f);
        }
    }
    if (t == 1023) row_start[NUM_E] = part[1023];
}

__global__ void build_perm(const int* __restrict__ si, const int* __restrict__ di,
                           const int* __restrict__ ei, int* __restrict__ cursor,
                           int* __restrict__ ssrc, int* __restrict__ setype, int E)
{
    int e = blockIdx.x * 256 + threadIdx.x;
    if (e >= E) return;
    int pos = atomicAdd(&cursor[di[e]], 1);
    ssrc[pos]   = si[e];
    setype[pos] = ei[e];
}

// ---------------------------------------------------------------- gathers

__global__ __launch_bounds__(256) void seg_gather_norm(
    float* __restrict__ h, const float* __restrict__ prev,
    const int* __restrict__ ssrc, const int* __restrict__ row_start,
    const float* __restrict__ invd)
{
    int v = blockIdx.x * 4 + (threadIdx.x >> 6);
    int lane = threadIdx.x & 63;
    if (v >= NUM_E) return;
    int s0 = row_start[v], s1 = row_start[v + 1];
    bool act = lane < 50;
    float4 acc = {0.f, 0.f, 0.f, 0.f};
    for (int j = s0; j < s1; j++) {
        int s = ssrc[j];
        if (act) {
            float4 x = *(const float4*)(prev + (long)s * H_DIM + lane * 4);
            acc.x += x.x; acc.y += x.y; acc.z += x.z; acc.w += x.w;
        }
    }
    float iv = invd[v];
    acc.x *= iv; acc.y *= iv; acc.z *= iv; acc.w *= iv;
    float ss = act ? (acc.x*acc.x + acc.y*acc.y + acc.z*acc.z + acc.w*acc.w) : 0.f;
    ss = wave_sum64(ss);
    float r = 1.f / fmaxf(sqrtf(ss), 1e-12f);
    if (act) {
        float4 o = {acc.x * r, acc.y * r, acc.z * r, acc.w * r};
        *(float4*)(h + (long)v * H_DIM + lane * 4) = o;
    }
}

__global__ __launch_bounds__(256) void seg_gather_layer(
    float* __restrict__ tmp, const float* __restrict__ h, const float* __restrict__ reln,
    const int* __restrict__ ssrc, const int* __restrict__ setype,
    const int* __restrict__ row_start, const float* __restrict__ invd)
{
    int v = blockIdx.x * 4 + (threadIdx.x >> 6);
    int lane = threadIdx.x & 63;
    if (v >= NUM_E) return;
    int s0 = row_start[v], s1 = row_start[v + 1];
    bool act = lane < 50;
    float4 acc = {0.f, 0.f, 0.f, 0.f};
    for (int j = s0; j < s1; j++) {
        int s = ssrc[j];
        int t = setype[j];
        if (act) {
            float4 x = *(const float4*)(h    + (long)s * H_DIM + lane * 4);
            float4 y = *(const float4*)(reln + (long)t * H_DIM + lane * 4);
            acc.x += x.x + y.x; acc.y += x.y + y.y;
            acc.z += x.z + y.z; acc.w += x.w + y.w;
        }
    }
    float iv = invd[v];
    if (act) {
        float4 o = {acc.x * iv, acc.y * iv, acc.z * iv, acc.w * iv};
        *(float4*)(tmp + (long)v * H_DIM + lane * 4) = o;
    }
}

// ---------------------------------------------------------------- row kernels

// 4 rows per block
__global__ __launch_bounds__(256) void l2norm_rows4(
    float* __restrict__ out, const float* __restrict__ in, int nrows)
{
    int v = blockIdx.x * 4 + (threadIdx.x >> 6);
    int lane = threadIdx.x & 63;
    if (v >= nrows) return;
    bool act = lane < 50;
    float4 x = {0.f, 0.f, 0.f, 0.f};
    if (act) x = *(const float4*)(in + (long)v * H_DIM + lane * 4);
    float ss = x.x*x.x + x.y*x.y + x.z*x.z + x.w*x.w;
    ss = wave_sum64(ss);
    float r = 1.f / fmaxf(sqrtf(ss), 1e-12f);
    if (act) {
        float4 o = {x.x * r, x.y * r, x.z * r, x.w * r};
        *(float4*)(out + (long)v * H_DIM + lane * 4) = o;
    }
}

__global__ void tenc_ent(float* __restrict__ te, const float* __restrict__ deg,
                         const float* __restrict__ af, const float* __restrict__ ap,
                         const float* __restrict__ cf, const float* __restrict__ cp,
                         float tcnt, int M)
{
    int idx = blockIdx.x * 256 + threadIdx.x;
    if (idx >= M * TD_DIM) return;
    int v = idx / TD_DIM, j = idx % TD_DIM;
    float t = (deg[v] > 0.f) ? tcnt : 100.0f;
    float val;
    if (j < HD_DIM) val = tanhf((t + 1.f) * af[j] + ap[j]);
    else            val = cosf(t * cf[j - HD_DIM] + cp[j - HD_DIM]);
    te[idx] = val;
}

// prev = l2norm((1-zg)*tanh(iN + rg*hN) + zg*prev), 4 rows/block
__global__ __launch_bounds__(256) void gru_fused(
    float* __restrict__ prev, const float* __restrict__ rg, const float* __restrict__ zg,
    const float* __restrict__ iN, const float* __restrict__ hN)
{
    int v = blockIdx.x * 4 + (threadIdx.x >> 6);
    int lane = threadIdx.x & 63;
    if (v >= NUM_E) return;
    bool act = lane < 50;
    long base = (long)v * H_DIM + lane * 4;
    float4 o = {0.f, 0.f, 0.f, 0.f};
    if (act) {
        float4 r4 = *(const float4*)(rg + base);
        float4 z4 = *(const float4*)(zg + base);
        float4 n4 = *(const float4*)(iN + base);
        float4 g4 = *(const float4*)(hN + base);
        float4 p4 = *(const float4*)(prev + base);
        float ngx = tanhf(n4.x + r4.x * g4.x);
        float ngy = tanhf(n4.y + r4.y * g4.y);
        float ngz = tanhf(n4.z + r4.z * g4.z);
        float ngw = tanhf(n4.w + r4.w * g4.w);
        o.x = (1.f - z4.x) * ngx + z4.x * p4.x;
        o.y = (1.f - z4.y) * ngy + z4.y * p4.y;
        o.z = (1.f - z4.z) * ngz + z4.z * p4.z;
        o.w = (1.f - z4.w) * ngw + z4.w * p4.w;
    }
    float ss = o.x*o.x + o.y*o.y + o.z*o.z + o.w*o.w;
    ss = wave_sum64(ss);
    float r = 1.f / fmaxf(sqrtf(ss), 1e-12f);
    if (act) {
        float4 w = {o.x * r, o.y * r, o.z * r, o.w * r};
        *(float4*)(prev + base) = w;
    }
}

// ---------------------------------------------------------------- batch head

// writes qs/qr replicated 3x (rows k*512+b)
__global__ void gather_qs_qr3(float* __restrict__ qs3, float* __restrict__ qr3,
                              const float* __restrict__ out, const float* __restrict__ reln,
                              const int* __restrict__ data)
{
    long i = (long)blockIdx.x * 256 + threadIdx.x;
    if (i >= (long)BATCH * H_DIM) return;
    int b = (int)(i / H_DIM), j = (int)(i % H_DIM);
    float vs = out[(long)data[b * 4 + 0] * H_DIM + j];
    float vr = reln[(long)data[b * 4 + 1] * H_DIM + j];
    const long S = (long)BATCH * H_DIM;
    qs3[i] = vs; qs3[i + S] = vs; qs3[i + 2*S] = vs;
    qr3[i] = vr; qr3[i + S] = vr; qr3[i + 2*S] = vr;
}

__global__ __launch_bounds__(64) void semb_kernel(
    float* __restrict__ semb, const float* __restrict__ out,
    const int* __restrict__ his_idx, const int* __restrict__ his_len)
{
    int b = blockIdx.x, k = blockIdx.y;
    int lane = threadIdx.x;
    int ln = his_len[b * 3 + k];
    if (ln > L_HIST) ln = L_HIST;
    float vals[4] = {0.f, 0.f, 0.f, 0.f};
    for (int l = 0; l < ln; l++) {
        int idx = his_idx[((long)b * 3 + k) * L_HIST + l];
        #pragma unroll
        for (int t = 0; t < 4; t++) {
            int j = lane + t * 64;
            if (j < H_DIM) vals[t] += out[(long)idx * H_DIM + j];
        }
    }
    float scale = 1.f / fmaxf((float)ln, 1.f);
    float ss = 0.f;
    #pragma unroll
    for (int t = 0; t < 4; t++) { vals[t] *= scale; ss += vals[t] * vals[t]; }
    ss = wave_sum64(ss);
    float r = 1.f / fmaxf(sqrtf(ss), 1e-12f);
    #pragma unroll
    for (int t = 0; t < 4; t++) {
        int j = lane + t * 64;
        if (j < H_DIM) semb[((long)k * BATCH + b) * H_DIM + j] = vals[t] * r;
    }
}

__global__ void tenc_batch(float* __restrict__ teb, const int* __restrict__ his_len,
                           const float* __restrict__ af, const float* __restrict__ ap,
                           const float* __restrict__ cf, const float* __restrict__ cp)
{
    int idx = blockIdx.x * 256 + threadIdx.x;
    if (idx >= 3 * BATCH * TD_DIM) return;
    int k = idx / (BATCH * TD_DIM);
    int rem = idx - k * (BATCH * TD_DIM);
    int b = rem / TD_DIM, j = rem % TD_DIM;
    int ln = his_len[b * 3 + k];
    float t = (ln > 0) ? (float)(2 - k) : 100.0f;
    float val;
    if (j < HD_DIM) val = tanhf((t + 1.f) * af[j] + ap[j]);
    else            val = cosf(t * cf[j - HD_DIM] + cp[j - HD_DIM]);
    teb[idx] = val;
}

// 1536 rows (k*512+b), 4 rows/block
__global__ __launch_bounds__(256) void att_logits_rows(
    float* __restrict__ atts, const float* __restrict__ a,
    const float* __restrict__ Wc_w, const float* __restrict__ Wc_b)
{
    int row = blockIdx.x * 4 + (threadIdx.x >> 6);
    int lane = threadIdx.x & 63;
    if (row >= 3 * BATCH) return;
    int k = row >> 9;
    int b = row & 511;
    float s = 0.f;
    for (int j = lane; j < H_DIM; j += 64) s += a[(long)row * H_DIM + j] * Wc_w[j];
    s = wave_sum64(s);
    if (lane == 0) atts[b * 3 + k] = s + Wc_b[0];
}

__global__ void softmax_out2(float* __restrict__ out2, const float* __restrict__ atts,
                             const float* __restrict__ semb)
{
    long i = (long)blockIdx.x * 256 + threadIdx.x;
    if (i >= (long)BATCH * H_DIM) return;
    int b = (int)(i / H_DIM), j = (int)(i % H_DIM);
    float l0 = atts[b * 3 + 0], l1 = atts[b * 3 + 1], l2 = atts[b * 3 + 2];
    float m = fmaxf(l0, fmaxf(l1, l2));
    float e0 = expf(l0 - m), e1 = expf(l1 - m), e2 = expf(l2 - m);
    float s = e0 + e1 + e2;
    float v = (e0 * semb[((long)0 * BATCH + b) * H_DIM + j] +
               e1 * semb[((long)1 * BATCH + b) * H_DIM + j] +
               e2 * semb[((long)2 * BATCH + b) * H_DIM + j]) / s;
    out2[i] = v;
}

// ---------------------------------------------------------------- launch

extern "C" void kernel_launch(void* const* d_in, const int* in_sizes, int n_in,
                              void* d_out, int out_size, void* d_ws, size_t ws_size,
                              hipStream_t stream)
{
    (void)in_sizes; (void)n_in; (void)out_size; (void)ws_size;

    const int*   src     = (const int*)d_in[0];
    const int*   dst     = (const int*)d_in[1];
    const int*   etype   = (const int*)d_in[2];
    const int*   data    = (const int*)d_in[3];
    const int*   his_idx = (const int*)d_in[4];
    const int*   his_len = (const int*)d_in[5];
    const float* ent     = (const float*)d_in[6];
    const float* loop_w  = (const float*)d_in[7];
    const float* rel     = (const float*)d_in[8];
    const float* af      = (const float*)d_in[9];
    const float* ap      = (const float*)d_in[10];
    const float* cf      = (const float*)d_in[11];
    const float* cp      = (const float*)d_in[12];
    const float* Wn      = (const float*)d_in[13];
    const float* Ws      = (const float*)d_in[14];
    const float* W_ih    = (const float*)d_in[15];
    const float* W_hh    = (const float*)d_in[16];
    const float* b_ih    = (const float*)d_in[17];
    const float* b_hh    = (const float*)d_in[18];
    const float* Wb_w    = (const float*)d_in[19];
    const float* Wb_b    = (const float*)d_in[20];
    const float* Wc_w    = (const float*)d_in[21];
    const float* Wc_b    = (const float*)d_in[22];
    const float* Wd_w    = (const float*)d_in[23];
    const float* Wd_b    = (const float*)d_in[24];
    float* out_p = (float*)d_out;

    float* wp = (float*)d_ws;
    size_t off = 0;
    auto alloc = [&](size_t n) { float* p = wp + off; off += n; return p; };
    const long nE200 = (long)NUM_E * H_DIM;            // 4,000,000
    float* prev   = alloc(nE200);
    float* h0     = alloc(nE200);
    float* h1     = alloc(nE200);   // layer ping-pong; GRU: iN
    float* tmp    = alloc(nE200);   // gather target; GRU: rg
    float* zgb    = alloc(nE200);   // GRU: zg
    float* te     = alloc((size_t)NUM_E * TD_DIM);
    float* degf   = alloc(NUM_E);
    float* invd   = alloc(NUM_E);
    float* reln   = alloc(400 * H_DIM);
    float* bsum   = alloc(1024);
    float* qs3    = alloc(3 * BATCH * H_DIM);
    float* qr3    = alloc(3 * BATCH * H_DIM);
    float* semb   = alloc(3 * BATCH * H_DIM);
    float* teb    = alloc(3 * BATCH * TD_DIM);
    float* abuf   = alloc(3 * BATCH * H_DIM);
    float* atts   = alloc(2048);
    float* out2   = alloc(BATCH * H_DIM);
    float* qbuf   = alloc(BATCH * H_DIM);
    int* cnt       = (int*)alloc(NUM_E);
    int* row_start = (int*)alloc(NUM_E + 4);
    int* cursor    = (int*)alloc(NUM_E);
    int* ssrc      = (int*)alloc(E_EDGES);
    int* setype    = (int*)alloc(E_EDGES);

    auto nblk = [](long n) { return (unsigned)((n + 255) / 256); };

    auto seg1 = [](const float* A, int lda, const float* B, int ldb, int K) {
        Segs s{}; s.A[0]=A; s.lda[0]=lda; s.B[0]=B; s.ldb[0]=ldb; s.Ks[0]=K;
        s.nseg=1; s.Ktot=K; return s;
    };
    auto seg2 = [](const float* A0, int la0, const float* B0, int lb0, int K0,
                   const float* A1, int la1, const float* B1, int lb1, int K1) {
        Segs s{}; s.A[0]=A0; s.lda[0]=la0; s.B[0]=B0; s.ldb[0]=lb0; s.Ks[0]=K0;
        s.A[1]=A1; s.lda[1]=la1; s.B[1]=B1; s.ldb[1]=lb1; s.Ks[1]=K1;
        s.nseg=2; s.Ktot=K0+K1; return s;
    };
    auto seg3 = [](const float* A0, int la0, const float* B0, int lb0, int K0,
                   const float* A1, int la1, const float* B1, int lb1, int K1,
                   const float* A2, int la2, const float* B2, int lb2, int K2) {
        Segs s{}; s.A[0]=A0; s.lda[0]=la0; s.B[0]=B0; s.ldb[0]=lb0; s.Ks[0]=K0;
        s.A[1]=A1; s.lda[1]=la1; s.B[1]=B1; s.ldb[1]=lb1; s.Ks[1]=K1;
        s.A[2]=A2; s.lda[2]=la2; s.B[2]=B2; s.ldb[2]=lb2; s.Ks[2]=K2;
        s.nseg=3; s.Ktot=K0+K1+K2; return s;
    };
    auto seg4 = [](const float* A0, int la0, const float* B0, int lb0, int K0,
                   const float* A1, int la1, const float* B1, int lb1, int K1,
                   const float* A2, int la2, const float* B2, int lb2, int K2,
                   const float* A3, int la3, const float* B3, int lb3, int K3) {
        Segs s{}; s.A[0]=A0; s.lda[0]=la0; s.B[0]=B0; s.ldb[0]=lb0; s.Ks[0]=K0;
        s.A[1]=A1; s.lda[1]=la1; s.B[1]=B1; s.ldb[1]=lb1; s.Ks[1]=K1;
        s.A[2]=A2; s.lda[2]=la2; s.B[2]=B2; s.ldb[2]=lb2; s.Ks[2]=K2;
        s.A[3]=A3; s.lda[3]=la3; s.B[3]=B3; s.ldb[3]=lb3; s.Ks[3]=K3;
        s.nseg=4; s.Ktot=K0+K1+K2+K3; return s;
    };

    auto gemm = [&](int BT, int ACT, float* C, const Segs& sg, const float* bias,
                    int M, int N, int ldc) {
        dim3 g((M + 127) / 128, (N + 63) / 64);
        if (BT) {
            if      (ACT == 0) sgemm_seg<1,0><<<g, 256, 0, stream>>>(C, sg, bias, M, N, ldc);
            else if (ACT == 1) sgemm_seg<1,1><<<g, 256, 0, stream>>>(C, sg, bias, M, N, ldc);
            else               sgemm_seg<1,2><<<g, 256, 0, stream>>>(C, sg, bias, M, N, ldc);
        } else {
            if      (ACT == 0) sgemm_seg<0,0><<<g, 256, 0, stream>>>(C, sg, bias, M, N, ldc);
            else               sgemm_seg<0,1><<<g, 256, 0, stream>>>(C, sg, bias, M, N, ldc);
        }
    };

    const unsigned r4 = (NUM_E + 3) / 4;

    // rel_n, bias sums
    l2norm_rows4<<<100, 256, 0, stream>>>(reln, rel, 400);
    bias_sum<<<3, 256, 0, stream>>>(bsum, b_ih, b_hh);

    // prev = l2norm(ent @ loop_weight)
    gemm(0, 0, tmp, seg1(ent, H_DIM, loop_w, H_DIM, H_DIM), nullptr, NUM_E, H_DIM, H_DIM);
    l2norm_rows4<<<r4, 256, 0, stream>>>(prev, tmp, NUM_E);

    for (int i = 0; i < N_HIST; i++) {
        const int* si = src   + (long)i * E_EDGES;
        const int* di = dst   + (long)i * E_EDGES;
        const int* ei = etype + (long)i * E_EDGES;
        float tcnt = (float)(N_HIST - 1 - i);

        // CSR build
        fill_i32<<<nblk(NUM_E), 256, 0, stream>>>(cnt, NUM_E, 0);
        count_dst<<<nblk(E_EDGES), 256, 0, stream>>>(di, cnt, E_EDGES);
        scan_rows<<<1, 1024, 0, stream>>>(cnt, row_start, cursor, degf, invd);
        build_perm<<<nblk(E_EDGES), 256, 0, stream>>>(si, di, ei, cursor, ssrc, setype, E_EDGES);

        // h0 = l2norm(segsum(prev)*inv)
        seg_gather_norm<<<r4, 256, 0, stream>>>(h0, prev, ssrc, row_start, invd);
        tenc_ent<<<nblk((long)NUM_E * TD_DIM), 256, 0, stream>>>(te, degf, af, ap, cf, cp, tcnt, NUM_E);

        // 2 RGCN layers, ping-pong h0 -> h1 -> h0, relu fused
        float* hcur = h0; float* hnext = h1;
        for (int l = 0; l < 2; l++) {
            seg_gather_layer<<<r4, 256, 0, stream>>>(tmp, hcur, reln, ssrc, setype, row_start, invd);
            const float* Wn_l = Wn + (long)l * H_DIM * H_DIM;
            const float* Ws_l = Ws + (long)l * H_DIM * H_DIM;
            gemm(0, 1, hnext,
                 seg2(tmp, H_DIM, Wn_l, H_DIM, H_DIM,
                      hcur, H_DIM, Ws_l, H_DIM, H_DIM),
                 nullptr, NUM_E, H_DIM, H_DIM);
            float* t2 = hcur; hcur = hnext; hnext = t2;
        }
        // hcur == h0 now; h = l2norm(h) in place
        l2norm_rows4<<<r4, 256, 0, stream>>>(h0, h0, NUM_E);

        // GRU: rg->tmp (sigmoid fused), zg->zgb (sigmoid fused), iN->h1, hN->h0
        gemm(1, 2, tmp,
             seg3(h0, H_DIM,   W_ih,        248, H_DIM,
                  te, TD_DIM,  W_ih + 200,  248, TD_DIM,
                  prev, H_DIM, W_hh,        200, H_DIM),
             bsum, NUM_E, H_DIM, H_DIM);
        gemm(1, 2, zgb,
             seg3(h0, H_DIM,   W_ih + 200*248,       248, H_DIM,
                  te, TD_DIM,  W_ih + 200*248 + 200, 248, TD_DIM,
                  prev, H_DIM, W_hh + 200*200,       200, H_DIM),
             bsum + 200, NUM_E, H_DIM, H_DIM);
        gemm(1, 0, h1,
             seg2(h0, H_DIM,  W_ih + 400*248,       248, H_DIM,
                  te, TD_DIM, W_ih + 400*248 + 200, 248, TD_DIM),
             b_ih + 400, NUM_E, H_DIM, H_DIM);
        gemm(1, 0, h0,
             seg1(prev, H_DIM, W_hh + 400*200, 200, H_DIM),
             b_hh + 400, NUM_E, H_DIM, H_DIM);

        gru_fused<<<r4, 256, 0, stream>>>(prev, tmp, zgb, h1, h0);
    }

    // ---- batch head ----
    gather_qs_qr3<<<nblk((long)BATCH * H_DIM), 256, 0, stream>>>(qs3, qr3, prev, reln, data);
    semb_kernel<<<dim3(BATCH, 3), 64, 0, stream>>>(semb, prev, his_idx, his_len);
    tenc_batch<<<nblk(3L * BATCH * TD_DIM), 256, 0, stream>>>(teb, his_len, af, ap, cf, cp);

    // abuf (1536 x 200) = relu([qs|qr|semb|teb] @ Wb_w^T + Wb_b)
    gemm(1, 1, abuf,
         seg4(qs3, H_DIM,  Wb_w,       648, H_DIM,
              qr3, H_DIM,  Wb_w + 200, 648, H_DIM,
              semb, H_DIM, Wb_w + 400, 648, H_DIM,
              teb, TD_DIM, Wb_w + 600, 648, TD_DIM),
         Wb_b, 3 * BATCH, H_DIM, H_DIM);
    att_logits_rows<<<(3 * BATCH + 3) / 4, 256, 0, stream>>>(atts, abuf, Wc_w, Wc_b);
    softmax_out2<<<nblk((long)BATCH * H_DIM), 256, 0, stream>>>(out2, atts, semb);

    // qbuf = relu([qs|qr|out2] @ Wd_w^T + Wd_b)
    gemm(1, 1, qbuf,
         seg3(qs3, H_DIM,  Wd_w,       600, H_DIM,
              qr3, H_DIM,  Wd_w + 200, 600, H_DIM,
              out2, H_DIM, Wd_w + 400, 600, H_DIM),
         Wd_b, BATCH, H_DIM, H_DIM);

    // result = q @ prev^T  -> (512, 20000)
    gemm(1, 0, out_p, seg1(qbuf, H_DIM, prev, H_DIM, H_DIM), nullptr,
         BATCH, NUM_E, NUM_E);
}

// Round 5
// 2126.497 us; speedup vs baseline: 4.9808x; 1.1732x over previous
//
#include <hip/hip_runtime.h>
#include <hip/hip_bf16.h>

#define NUM_E   20000
#define H_DIM   200
#define TD_DIM  48
#define HD_DIM  24
#define L_HIST  32
#define N_HIST  3
#define E_EDGES 200000
#define BATCH   512

// ---------------------------------------------------------------- utilities

__device__ inline float wave_sum64(float x) {
    #pragma unroll
    for (int m = 1; m < 64; m <<= 1) x += __shfl_xor(x, m);
    return x;
}

__global__ void fill_i32(int* __restrict__ p, long n, int v) {
    long i = (long)blockIdx.x * blockDim.x + threadIdx.x;
    if (i < n) p[i] = v;
}

// bsum[j] = b_ih[j] + b_hh[j]  (j < 600)
__global__ void bias_sum(float* __restrict__ bsum, const float* __restrict__ b_ih,
                         const float* __restrict__ b_hh) {
    int j = blockIdx.x * 256 + threadIdx.x;
    if (j < 600) bsum[j] = b_ih[j] + b_hh[j];
}

// ---------------------------------------------------------------- multi-segment GEMM
// C = act( sum_seg A_s @ op(B_s) + bias )
// BT=1: B_s is (N, Ks) row-major (A @ B^T). BT=0: B_s is (Ks, N) row-major.
// Tiles: BM x 64, BK=32; 256 threads; (BM/16) x 4 micro-tile.
// Grid: x = N tiles (fast -> A-tile L2 reuse), y = M tiles.
// Segment Ks and N are multiples of 4.

struct Segs {
    const float* A[4];
    const float* B[4];
    int lda[4], ldb[4], Ks[4];
    int nseg, Ktot;
};

__device__ inline void seg_find(const Segs& sg, int gk, int& s, int& loc) {
    s = 0; loc = gk;
    #pragma unroll
    for (int t = 0; t < 3; t++) {
        if (s + 1 < sg.nseg && loc >= sg.Ks[s]) { loc -= sg.Ks[s]; s++; }
    }
}

// ACT: 0 = none, 1 = relu, 2 = sigmoid
template<int BT, int ACT, int BM>
__global__ __launch_bounds__(256) void sgemm_seg(
    float* __restrict__ C, const Segs sg, const float* __restrict__ bias,
    int M, int N, int ldc)
{
    constexpr int MR = BM / 16;                  // 8 (BM=128) or 4 (BM=64)
    __shared__ float As[32][BM + 4];             // [k][m], stride BM+4 (mult of 4)
    __shared__ float Bs[32][68];                 // [k][n]
    const int bn = blockIdx.x * 64;
    const int bm = blockIdx.y * BM;
    const int tid = threadIdx.x;
    const int m0 = (tid >> 4) * MR;
    const int n0 = (tid & 15) * 4;

    float acc[MR][4];
    #pragma unroll
    for (int i = 0; i < MR; i++)
        #pragma unroll
        for (int j = 0; j < 4; j++) acc[i][j] = 0.f;

    const int Ktot = sg.Ktot;
    const int ntile = (Ktot + 31) / 32;

    // A staging: lanes write consecutive m for fixed k -> conflict-free
    const int a_m  = tid & 31;                   // m base (consecutive across lanes)
    const int a_k4 = (tid >> 5) * 4;             // k group
    // B staging BT=1: lanes write consecutive n for fixed k
    const int b1_n = tid & 63;
    const int b1_k = (tid >> 6) * 4;
    // B staging BT=0: float4 along n
    const int b0_k  = tid >> 4;
    const int b0_n4 = (tid & 15) * 4;

    for (int t = 0; t < ntile; t++) {
        const int k0 = t * 32;

        // ---- stage A (transposed into As[k][m]) ----
        {
            int gk = k0 + a_k4;
            bool kin = gk < Ktot;
            int s = 0, loc = 0;
            if (kin) seg_find(sg, gk, s, loc);
            const float* Ab = sg.A[s];
            const int lda = sg.lda[s];
            #pragma unroll
            for (int r = 0; r < BM / 32; r++) {
                int m = a_m + 32 * r;
                int row = bm + m;
                float4 v = {0.f, 0.f, 0.f, 0.f};
                if (kin && row < M) v = *(const float4*)(Ab + (size_t)row * lda + loc);
                As[a_k4 + 0][m] = v.x;
                As[a_k4 + 1][m] = v.y;
                As[a_k4 + 2][m] = v.z;
                As[a_k4 + 3][m] = v.w;
            }
        }

        // ---- stage B into Bs[k][n] ----
        if (BT) {
            #pragma unroll
            for (int r = 0; r < 2; r++) {
                int k4 = b1_k + 16 * r;
                int gk = k0 + k4;
                bool kin = gk < Ktot;
                int s = 0, loc = 0;
                if (kin) seg_find(sg, gk, s, loc);
                const float* Bb = sg.B[s];
                const int ldb = sg.ldb[s];
                int gn = bn + b1_n;
                float4 v = {0.f, 0.f, 0.f, 0.f};
                if (kin && gn < N) v = *(const float4*)(Bb + (size_t)gn * ldb + loc);
                Bs[k4 + 0][b1_n] = v.x;
                Bs[k4 + 1][b1_n] = v.y;
                Bs[k4 + 2][b1_n] = v.z;
                Bs[k4 + 3][b1_n] = v.w;
            }
        } else {
            #pragma unroll
            for (int r = 0; r < 2; r++) {
                int kk = b0_k + r * 16;
                int gk = k0 + kk;
                float4 v = {0.f, 0.f, 0.f, 0.f};
                if (gk < Ktot) {
                    int s, loc; seg_find(sg, gk, s, loc);
                    const float* Bb = sg.B[s];
                    const int ldb = sg.ldb[s];
                    int gn = bn + b0_n4;
                    if (gn < N) v = *(const float4*)(Bb + (size_t)loc * ldb + gn);
                }
                *(float4*)&Bs[kk][b0_n4] = v;
            }
        }

        __syncthreads();

        #pragma unroll 8
        for (int kk = 0; kk < 32; kk++) {
            float4 b = *(float4*)&Bs[kk][n0];
            float a[MR];
            #pragma unroll
            for (int q = 0; q < MR / 4; q++) {
                float4 av = *(float4*)&As[kk][m0 + q * 4];
                a[q*4 + 0] = av.x; a[q*4 + 1] = av.y;
                a[q*4 + 2] = av.z; a[q*4 + 3] = av.w;
            }
            #pragma unroll
            for (int i = 0; i < MR; i++) {
                acc[i][0] += a[i] * b.x;
                acc[i][1] += a[i] * b.y;
                acc[i][2] += a[i] * b.z;
                acc[i][3] += a[i] * b.w;
            }
        }

        __syncthreads();
    }

    // ---- epilogue ----
    int col = bn + n0;
    if (col < N) {   // N % 4 == 0 -> full float4 in-bounds
        float4 bv = {0.f, 0.f, 0.f, 0.f};
        if (bias) bv = *(const float4*)(bias + col);
        #pragma unroll
        for (int i = 0; i < MR; i++) {
            int row = bm + m0 + i;
            if (row < M) {
                float4 o;
                o.x = acc[i][0] + bv.x;
                o.y = acc[i][1] + bv.y;
                o.z = acc[i][2] + bv.z;
                o.w = acc[i][3] + bv.w;
                if (ACT == 1) {
                    o.x = fmaxf(o.x, 0.f); o.y = fmaxf(o.y, 0.f);
                    o.z = fmaxf(o.z, 0.f); o.w = fmaxf(o.w, 0.f);
                } else if (ACT == 2) {
                    o.x = 1.f / (1.f + expf(-o.x)); o.y = 1.f / (1.f + expf(-o.y));
                    o.z = 1.f / (1.f + expf(-o.z)); o.w = 1.f / (1.f + expf(-o.w));
                }
                *(float4*)(C + (size_t)row * ldc + col) = o;
            }
        }
    }
}

// ---------------------------------------------------------------- CSR build

__global__ void count_dst(const int* __restrict__ di, int* __restrict__ cnt, int E) {
    int e = blockIdx.x * 256 + threadIdx.x;
    if (e < E) atomicAdd(&cnt[di[e]], 1);
}

__global__ __launch_bounds__(1024) void scan_rows(
    const int* __restrict__ cnt, int* __restrict__ row_start, int* __restrict__ cursor,
    float* __restrict__ degf, float* __restrict__ invd)
{
    __shared__ int part[1024];
    const int CH = (NUM_E + 1023) / 1024;   // 20
    int t = threadIdx.x;
    int base = t * CH;
    int local[32];
    int s = 0;
    for (int j = 0; j < CH; j++) {
        int idx = base + j;
        int c = (idx < NUM_E) ? cnt[idx] : 0;
        local[j] = s; s += c;
    }
    part[t] = s;
    __syncthreads();
    for (int off = 1; off < 1024; off <<= 1) {
        int v = (t >= off) ? part[t - off] : 0;
        __syncthreads();
        part[t] += v;
        __syncthreads();
    }
    int pre = (t == 0) ? 0 : part[t - 1];
    for (int j = 0; j < CH; j++) {
        int idx = base + j;
        if (idx < NUM_E) {
            int rs = pre + local[j];
            row_start[idx] = rs;
            cursor[idx] = rs;
            int c = cnt[idx];
            degf[idx] = (float)c;
            invd[idx] = 1.f / fmaxf((float)c, 1.f);
        }
    }
    if (t == 1023) row_start[NUM_E] = part[1023];
}

__global__ void build_perm(const int* __restrict__ si, const int* __restrict__ di,
                           const int* __restrict__ ei, int* __restrict__ cursor,
                           int* __restrict__ ssrc, int* __restrict__ setype, int E)
{
    int e = blockIdx.x * 256 + threadIdx.x;
    if (e >= E) return;
    int pos = atomicAdd(&cursor[di[e]], 1);
    ssrc[pos]   = si[e];
    setype[pos] = ei[e];
}

// ---------------------------------------------------------------- gathers

__global__ __launch_bounds__(256) void seg_gather_norm(
    float* __restrict__ h, const float* __restrict__ prev,
    const int* __restrict__ ssrc, const int* __restrict__ row_start,
    const float* __restrict__ invd)
{
    int v = blockIdx.x * 4 + (threadIdx.x >> 6);
    int lane = threadIdx.x & 63;
    if (v >= NUM_E) return;
    int s0 = row_start[v], s1 = row_start[v + 1];
    bool act = lane < 50;
    float4 acc = {0.f, 0.f, 0.f, 0.f};
    for (int j = s0; j < s1; j++) {
        int s = ssrc[j];
        if (act) {
            float4 x = *(const float4*)(prev + (long)s * H_DIM + lane * 4);
            acc.x += x.x; acc.y += x.y; acc.z += x.z; acc.w += x.w;
        }
    }
    float iv = invd[v];
    acc.x *= iv; acc.y *= iv; acc.z *= iv; acc.w *= iv;
    float ss = act ? (acc.x*acc.x + acc.y*acc.y + acc.z*acc.z + acc.w*acc.w) : 0.f;
    ss = wave_sum64(ss);
    float r = 1.f / fmaxf(sqrtf(ss), 1e-12f);
    if (act) {
        float4 o = {acc.x * r, acc.y * r, acc.z * r, acc.w * r};
        *(float4*)(h + (long)v * H_DIM + lane * 4) = o;
    }
}

__global__ __launch_bounds__(256) void seg_gather_layer(
    float* __restrict__ tmp, const float* __restrict__ h, const float* __restrict__ reln,
    const int* __restrict__ ssrc, const int* __restrict__ setype,
    const int* __restrict__ row_start, const float* __restrict__ invd)
{
    int v = blockIdx.x * 4 + (threadIdx.x >> 6);
    int lane = threadIdx.x & 63;
    if (v >= NUM_E) return;
    int s0 = row_start[v], s1 = row_start[v + 1];
    bool act = lane < 50;
    float4 acc = {0.f, 0.f, 0.f, 0.f};
    for (int j = s0; j < s1; j++) {
        int s = ssrc[j];
        int t = setype[j];
        if (act) {
            float4 x = *(const float4*)(h    + (long)s * H_DIM + lane * 4);
            float4 y = *(const float4*)(reln + (long)t * H_DIM + lane * 4);
            acc.x += x.x + y.x; acc.y += x.y + y.y;
            acc.z += x.z + y.z; acc.w += x.w + y.w;
        }
    }
    float iv = invd[v];
    if (act) {
        float4 o = {acc.x * iv, acc.y * iv, acc.z * iv, acc.w * iv};
        *(float4*)(tmp + (long)v * H_DIM + lane * 4) = o;
    }
}

// ---------------------------------------------------------------- row kernels

__global__ __launch_bounds__(256) void l2norm_rows4(
    float* __restrict__ out, const float* __restrict__ in, int nrows)
{
    int v = blockIdx.x * 4 + (threadIdx.x >> 6);
    int lane = threadIdx.x & 63;
    if (v >= nrows) return;
    bool act = lane < 50;
    float4 x = {0.f, 0.f, 0.f, 0.f};
    if (act) x = *(const float4*)(in + (long)v * H_DIM + lane * 4);
    float ss = x.x*x.x + x.y*x.y + x.z*x.z + x.w*x.w;
    ss = wave_sum64(ss);
    float r = 1.f / fmaxf(sqrtf(ss), 1e-12f);
    if (act) {
        float4 o = {x.x * r, x.y * r, x.z * r, x.w * r};
        *(float4*)(out + (long)v * H_DIM + lane * 4) = o;
    }
}

__global__ void tenc_ent(float* __restrict__ te, const float* __restrict__ deg,
                         const float* __restrict__ af, const float* __restrict__ ap,
                         const float* __restrict__ cf, const float* __restrict__ cp,
                         float tcnt, int M)
{
    int idx = blockIdx.x * 256 + threadIdx.x;
    if (idx >= M * TD_DIM) return;
    int v = idx / TD_DIM, j = idx % TD_DIM;
    float t = (deg[v] > 0.f) ? tcnt : 100.0f;
    float val;
    if (j < HD_DIM) val = tanhf((t + 1.f) * af[j] + ap[j]);
    else            val = cosf(t * cf[j - HD_DIM] + cp[j - HD_DIM]);
    te[idx] = val;
}

// prev = l2norm((1-z)*tanh(iN + r*hN) + z*prev); rz holds sigmoid(r|z) (ld 400)
__global__ __launch_bounds__(256) void gru_fused(
    float* __restrict__ prev, const float* __restrict__ rz,
    const float* __restrict__ iN, const float* __restrict__ hN)
{
    int v = blockIdx.x * 4 + (threadIdx.x >> 6);
    int lane = threadIdx.x & 63;
    if (v >= NUM_E) return;
    bool act = lane < 50;
    long b200 = (long)v * H_DIM + lane * 4;
    long b400 = (long)v * 400 + lane * 4;
    float4 o = {0.f, 0.f, 0.f, 0.f};
    if (act) {
        float4 r4 = *(const float4*)(rz + b400);
        float4 z4 = *(const float4*)(rz + b400 + 200);
        float4 n4 = *(const float4*)(iN + b200);
        float4 g4 = *(const float4*)(hN + b200);
        float4 p4 = *(const float4*)(prev + b200);
        float ngx = tanhf(n4.x + r4.x * g4.x);
        float ngy = tanhf(n4.y + r4.y * g4.y);
        float ngz = tanhf(n4.z + r4.z * g4.z);
        float ngw = tanhf(n4.w + r4.w * g4.w);
        o.x = (1.f - z4.x) * ngx + z4.x * p4.x;
        o.y = (1.f - z4.y) * ngy + z4.y * p4.y;
        o.z = (1.f - z4.z) * ngz + z4.z * p4.z;
        o.w = (1.f - z4.w) * ngw + z4.w * p4.w;
    }
    float ss = o.x*o.x + o.y*o.y + o.z*o.z + o.w*o.w;
    ss = wave_sum64(ss);
    float r = 1.f / fmaxf(sqrtf(ss), 1e-12f);
    if (act) {
        float4 w = {o.x * r, o.y * r, o.z * r, o.w * r};
        *(float4*)(prev + b200) = w;
    }
}

// ---------------------------------------------------------------- batch head

__global__ void gather_qs_qr3(float* __restrict__ qs3, float* __restrict__ qr3,
                              const float* __restrict__ out, const float* __restrict__ reln,
                              const int* __restrict__ data)
{
    long i = (long)blockIdx.x * 256 + threadIdx.x;
    if (i >= (long)BATCH * H_DIM) return;
    int b = (int)(i / H_DIM), j = (int)(i % H_DIM);
    float vs = out[(long)data[b * 4 + 0] * H_DIM + j];
    float vr = reln[(long)data[b * 4 + 1] * H_DIM + j];
    const long S = (long)BATCH * H_DIM;
    qs3[i] = vs; qs3[i + S] = vs; qs3[i + 2*S] = vs;
    qr3[i] = vr; qr3[i + S] = vr; qr3[i + 2*S] = vr;
}

__global__ __launch_bounds__(64) void semb_kernel(
    float* __restrict__ semb, const float* __restrict__ out,
    const int* __restrict__ his_idx, const int* __restrict__ his_len)
{
    int b = blockIdx.x, k = blockIdx.y;
    int lane = threadIdx.x;
    int ln = his_len[b * 3 + k];
    if (ln > L_HIST) ln = L_HIST;
    float vals[4] = {0.f, 0.f, 0.f, 0.f};
    for (int l = 0; l < ln; l++) {
        int idx = his_idx[((long)b * 3 + k) * L_HIST + l];
        #pragma unroll
        for (int t = 0; t < 4; t++) {
            int j = lane + t * 64;
            if (j < H_DIM) vals[t] += out[(long)idx * H_DIM + j];
        }
    }
    float scale = 1.f / fmaxf((float)ln, 1.f);
    float ss = 0.f;
    #pragma unroll
    for (int t = 0; t < 4; t++) { vals[t] *= scale; ss += vals[t] * vals[t]; }
    ss = wave_sum64(ss);
    float r = 1.f / fmaxf(sqrtf(ss), 1e-12f);
    #pragma unroll
    for (int t = 0; t < 4; t++) {
        int j = lane + t * 64;
        if (j < H_DIM) semb[((long)k * BATCH + b) * H_DIM + j] = vals[t] * r;
    }
}

__global__ void tenc_batch(float* __restrict__ teb, const int* __restrict__ his_len,
                           const float* __restrict__ af, const float* __restrict__ ap,
                           const float* __restrict__ cf, const float* __restrict__ cp)
{
    int idx = blockIdx.x * 256 + threadIdx.x;
    if (idx >= 3 * BATCH * TD_DIM) return;
    int k = idx / (BATCH * TD_DIM);
    int rem = idx - k * (BATCH * TD_DIM);
    int b = rem / TD_DIM, j = rem % TD_DIM;
    int ln = his_len[b * 3 + k];
    float t = (ln > 0) ? (float)(2 - k) : 100.0f;
    float val;
    if (j < HD_DIM) val = tanhf((t + 1.f) * af[j] + ap[j]);
    else            val = cosf(t * cf[j - HD_DIM] + cp[j - HD_DIM]);
    teb[idx] = val;
}

__global__ __launch_bounds__(256) void att_logits_rows(
    float* __restrict__ atts, const float* __restrict__ a,
    const float* __restrict__ Wc_w, const float* __restrict__ Wc_b)
{
    int row = blockIdx.x * 4 + (threadIdx.x >> 6);
    int lane = threadIdx.x & 63;
    if (row >= 3 * BATCH) return;
    int k = row >> 9;
    int b = row & 511;
    float s = 0.f;
    for (int j = lane; j < H_DIM; j += 64) s += a[(long)row * H_DIM + j] * Wc_w[j];
    s = wave_sum64(s);
    if (lane == 0) atts[b * 3 + k] = s + Wc_b[0];
}

__global__ void softmax_out2(float* __restrict__ out2, const float* __restrict__ atts,
                             const float* __restrict__ semb)
{
    long i = (long)blockIdx.x * 256 + threadIdx.x;
    if (i >= (long)BATCH * H_DIM) return;
    int b = (int)(i / H_DIM), j = (int)(i % H_DIM);
    float l0 = atts[b * 3 + 0], l1 = atts[b * 3 + 1], l2 = atts[b * 3 + 2];
    float m = fmaxf(l0, fmaxf(l1, l2));
    float e0 = expf(l0 - m), e1 = expf(l1 - m), e2 = expf(l2 - m);
    float s = e0 + e1 + e2;
    float v = (e0 * semb[((long)0 * BATCH + b) * H_DIM + j] +
               e1 * semb[((long)1 * BATCH + b) * H_DIM + j] +
               e2 * semb[((long)2 * BATCH + b) * H_DIM + j]) / s;
    out2[i] = v;
}

// ---------------------------------------------------------------- launch

extern "C" void kernel_launch(void* const* d_in, const int* in_sizes, int n_in,
                              void* d_out, int out_size, void* d_ws, size_t ws_size,
                              hipStream_t stream)
{
    (void)in_sizes; (void)n_in; (void)out_size; (void)ws_size;

    const int*   src     = (const int*)d_in[0];
    const int*   dst     = (const int*)d_in[1];
    const int*   etype   = (const int*)d_in[2];
    const int*   data    = (const int*)d_in[3];
    const int*   his_idx = (const int*)d_in[4];
    const int*   his_len = (const int*)d_in[5];
    const float* ent     = (const float*)d_in[6];
    const float* loop_w  = (const float*)d_in[7];
    const float* rel     = (const float*)d_in[8];
    const float* af      = (const float*)d_in[9];
    const float* ap      = (const float*)d_in[10];
    const float* cf      = (const float*)d_in[11];
    const float* cp      = (const float*)d_in[12];
    const float* Wn      = (const float*)d_in[13];
    const float* Ws      = (const float*)d_in[14];
    const float* W_ih    = (const float*)d_in[15];
    const float* W_hh    = (const float*)d_in[16];
    const float* b_ih    = (const float*)d_in[17];
    const float* b_hh    = (const float*)d_in[18];
    const float* Wb_w    = (const float*)d_in[19];
    const float* Wb_b    = (const float*)d_in[20];
    const float* Wc_w    = (const float*)d_in[21];
    const float* Wc_b    = (const float*)d_in[22];
    const float* Wd_w    = (const float*)d_in[23];
    const float* Wd_b    = (const float*)d_in[24];
    float* out_p = (float*)d_out;

    float* wp = (float*)d_ws;
    size_t off = 0;
    auto alloc = [&](size_t n) { float* p = wp + off; off += n; return p; };
    const long nE200 = (long)NUM_E * H_DIM;            // 4,000,000
    float* prev   = alloc(nE200);
    float* h0     = alloc(nE200);
    float* h1     = alloc(nE200);                       // layer ping-pong; GRU iN
    float* tmp    = alloc(nE200);                       // layer gather; GRU hN
    float* rz     = alloc((size_t)NUM_E * 400);         // GRU r|z (sigmoid applied)
    float* te     = alloc((size_t)NUM_E * TD_DIM);
    float* degf   = alloc(NUM_E);
    float* invd   = alloc(NUM_E);
    float* reln   = alloc(400 * H_DIM);
    float* bsum   = alloc(1024);
    float* qs3    = alloc(3 * BATCH * H_DIM);
    float* qr3    = alloc(3 * BATCH * H_DIM);
    float* semb   = alloc(3 * BATCH * H_DIM);
    float* teb    = alloc(3 * BATCH * TD_DIM);
    float* abuf   = alloc(3 * BATCH * H_DIM);
    float* atts   = alloc(2048);
    float* out2   = alloc(BATCH * H_DIM);
    float* qbuf   = alloc(BATCH * H_DIM);
    int* cnt       = (int*)alloc(NUM_E);
    int* row_start = (int*)alloc(NUM_E + 4);
    int* cursor    = (int*)alloc(NUM_E);
    int* ssrc      = (int*)alloc(E_EDGES);
    int* setype    = (int*)alloc(E_EDGES);

    auto nblk = [](long n) { return (unsigned)((n + 255) / 256); };

    auto seg1 = [](const float* A, int lda, const float* B, int ldb, int K) {
        Segs s{}; s.A[0]=A; s.lda[0]=lda; s.B[0]=B; s.ldb[0]=ldb; s.Ks[0]=K;
        s.nseg=1; s.Ktot=K; return s;
    };
    auto seg2 = [](const float* A0, int la0, const float* B0, int lb0, int K0,
                   const float* A1, int la1, const float* B1, int lb1, int K1) {
        Segs s{}; s.A[0]=A0; s.lda[0]=la0; s.B[0]=B0; s.ldb[0]=lb0; s.Ks[0]=K0;
        s.A[1]=A1; s.lda[1]=la1; s.B[1]=B1; s.ldb[1]=lb1; s.Ks[1]=K1;
        s.nseg=2; s.Ktot=K0+K1; return s;
    };
    auto seg3 = [](const float* A0, int la0, const float* B0, int lb0, int K0,
                   const float* A1, int la1, const float* B1, int lb1, int K1,
                   const float* A2, int la2, const float* B2, int lb2, int K2) {
        Segs s{}; s.A[0]=A0; s.lda[0]=la0; s.B[0]=B0; s.ldb[0]=lb0; s.Ks[0]=K0;
        s.A[1]=A1; s.lda[1]=la1; s.B[1]=B1; s.ldb[1]=lb1; s.Ks[1]=K1;
        s.A[2]=A2; s.lda[2]=la2; s.B[2]=B2; s.ldb[2]=lb2; s.Ks[2]=K2;
        s.nseg=3; s.Ktot=K0+K1+K2; return s;
    };
    auto seg4 = [](const float* A0, int la0, const float* B0, int lb0, int K0,
                   const float* A1, int la1, const float* B1, int lb1, int K1,
                   const float* A2, int la2, const float* B2, int lb2, int K2,
                   const float* A3, int la3, const float* B3, int lb3, int K3) {
        Segs s{}; s.A[0]=A0; s.lda[0]=la0; s.B[0]=B0; s.ldb[0]=lb0; s.Ks[0]=K0;
        s.A[1]=A1; s.lda[1]=la1; s.B[1]=B1; s.ldb[1]=lb1; s.Ks[1]=K1;
        s.A[2]=A2; s.lda[2]=la2; s.B[2]=B2; s.ldb[2]=lb2; s.Ks[2]=K2;
        s.A[3]=A3; s.lda[3]=la3; s.B[3]=B3; s.ldb[3]=lb3; s.Ks[3]=K3;
        s.nseg=4; s.Ktot=K0+K1+K2+K3; return s;
    };

    // BT, ACT, BM runtime dispatch
    auto gemm = [&](int BT, int ACT, int BM, float* C, const Segs& sg, const float* bias,
                    int M, int N, int ldc) {
        dim3 g((N + 63) / 64, (M + BM - 1) / BM);
        if (BM == 128) {
            if (BT) {
                if      (ACT == 0) sgemm_seg<1,0,128><<<g, 256, 0, stream>>>(C, sg, bias, M, N, ldc);
                else if (ACT == 1) sgemm_seg<1,1,128><<<g, 256, 0, stream>>>(C, sg, bias, M, N, ldc);
                else               sgemm_seg<1,2,128><<<g, 256, 0, stream>>>(C, sg, bias, M, N, ldc);
            } else {
                if      (ACT == 0) sgemm_seg<0,0,128><<<g, 256, 0, stream>>>(C, sg, bias, M, N, ldc);
                else               sgemm_seg<0,1,128><<<g, 256, 0, stream>>>(C, sg, bias, M, N, ldc);
            }
        } else {
            if (BT) {
                if      (ACT == 0) sgemm_seg<1,0,64><<<g, 256, 0, stream>>>(C, sg, bias, M, N, ldc);
                else if (ACT == 1) sgemm_seg<1,1,64><<<g, 256, 0, stream>>>(C, sg, bias, M, N, ldc);
                else               sgemm_seg<1,2,64><<<g, 256, 0, stream>>>(C, sg, bias, M, N, ldc);
            } else {
                if      (ACT == 0) sgemm_seg<0,0,64><<<g, 256, 0, stream>>>(C, sg, bias, M, N, ldc);
                else               sgemm_seg<0,1,64><<<g, 256, 0, stream>>>(C, sg, bias, M, N, ldc);
            }
        }
    };

    const unsigned r4 = (NUM_E + 3) / 4;

    // rel_n, bias sums
    l2norm_rows4<<<100, 256, 0, stream>>>(reln, rel, 400);
    bias_sum<<<3, 256, 0, stream>>>(bsum, b_ih, b_hh);

    // prev = l2norm(ent @ loop_weight)
    gemm(0, 0, 64, tmp, seg1(ent, H_DIM, loop_w, H_DIM, H_DIM), nullptr, NUM_E, H_DIM, H_DIM);
    l2norm_rows4<<<r4, 256, 0, stream>>>(prev, tmp, NUM_E);

    for (int i = 0; i < N_HIST; i++) {
        const int* si = src   + (long)i * E_EDGES;
        const int* di = dst   + (long)i * E_EDGES;
        const int* ei = etype + (long)i * E_EDGES;
        float tcnt = (float)(N_HIST - 1 - i);

        // CSR build
        fill_i32<<<nblk(NUM_E), 256, 0, stream>>>(cnt, NUM_E, 0);
        count_dst<<<nblk(E_EDGES), 256, 0, stream>>>(di, cnt, E_EDGES);
        scan_rows<<<1, 1024, 0, stream>>>(cnt, row_start, cursor, degf, invd);
        build_perm<<<nblk(E_EDGES), 256, 0, stream>>>(si, di, ei, cursor, ssrc, setype, E_EDGES);

        // h0 = l2norm(segsum(prev)*inv)
        seg_gather_norm<<<r4, 256, 0, stream>>>(h0, prev, ssrc, row_start, invd);
        tenc_ent<<<nblk((long)NUM_E * TD_DIM), 256, 0, stream>>>(te, degf, af, ap, cf, cp, tcnt, NUM_E);

        // 2 RGCN layers, ping-pong h0 -> h1 -> h0, relu fused
        float* hcur = h0; float* hnext = h1;
        for (int l = 0; l < 2; l++) {
            seg_gather_layer<<<r4, 256, 0, stream>>>(tmp, hcur, reln, ssrc, setype, row_start, invd);
            const float* Wn_l = Wn + (long)l * H_DIM * H_DIM;
            const float* Ws_l = Ws + (long)l * H_DIM * H_DIM;
            gemm(0, 1, 64, hnext,
                 seg2(tmp, H_DIM, Wn_l, H_DIM, H_DIM,
                      hcur, H_DIM, Ws_l, H_DIM, H_DIM),
                 nullptr, NUM_E, H_DIM, H_DIM);
            float* t2 = hcur; hcur = hnext; hnext = t2;
        }
        // h = l2norm(h) in place (hcur == h0)
        l2norm_rows4<<<r4, 256, 0, stream>>>(h0, h0, NUM_E);

        // GRU: rz (N=400, sigmoid fused), iN -> h1, hN -> tmp
        gemm(1, 2, 128, rz,
             seg3(h0, H_DIM,   W_ih,        248, H_DIM,
                  te, TD_DIM,  W_ih + 200,  248, TD_DIM,
                  prev, H_DIM, W_hh,        200, H_DIM),
             bsum, NUM_E, 400, 400);
        gemm(1, 0, 64, h1,
             seg2(h0, H_DIM,  W_ih + 400*248,       248, H_DIM,
                  te, TD_DIM, W_ih + 400*248 + 200, 248, TD_DIM),
             b_ih + 400, NUM_E, H_DIM, H_DIM);
        gemm(1, 0, 64, tmp,
             seg1(prev, H_DIM, W_hh + 400*200, 200, H_DIM),
             b_hh + 400, NUM_E, H_DIM, H_DIM);

        gru_fused<<<r4, 256, 0, stream>>>(prev, rz, h1, tmp);
    }

    // ---- batch head ----
    gather_qs_qr3<<<nblk((long)BATCH * H_DIM), 256, 0, stream>>>(qs3, qr3, prev, reln, data);
    semb_kernel<<<dim3(BATCH, 3), 64, 0, stream>>>(semb, prev, his_idx, his_len);
    tenc_batch<<<nblk(3L * BATCH * TD_DIM), 256, 0, stream>>>(teb, his_len, af, ap, cf, cp);

    // abuf (1536 x 200) = relu([qs|qr|semb|teb] @ Wb_w^T + Wb_b)
    gemm(1, 1, 64, abuf,
         seg4(qs3, H_DIM,  Wb_w,       648, H_DIM,
              qr3, H_DIM,  Wb_w + 200, 648, H_DIM,
              semb, H_DIM, Wb_w + 400, 648, H_DIM,
              teb, TD_DIM, Wb_w + 600, 648, TD_DIM),
         Wb_b, 3 * BATCH, H_DIM, H_DIM);
    att_logits_rows<<<(3 * BATCH + 3) / 4, 256, 0, stream>>>(atts, abuf, Wc_w, Wc_b);
    softmax_out2<<<nblk((long)BATCH * H_DIM), 256, 0, stream>>>(out2, atts, semb);

    // qbuf = relu([qs|qr|out2] @ Wd_w^T + Wd_b)
    gemm(1, 1, 64, qbuf,
         seg3(qs3, H_DIM,  Wd_w,       600, H_DIM,
              qr3, H_DIM,  Wd_w + 200, 600, H_DIM,
              out2, H_DIM, Wd_w + 400, 600, H_DIM),
         Wd_b, BATCH, H_DIM, H_DIM);

    // result = q @ prev^T  -> (512, 20000)
    gemm(1, 0, 128, out_p, seg1(qbuf, H_DIM, prev, H_DIM, H_DIM), nullptr,
         BATCH, NUM_E, NUM_E);
}

// Round 6
// 1544.199 us; speedup vs baseline: 6.8590x; 1.3771x over previous
//
#include <hip/hip_runtime.h>
#include <hip/hip_bf16.h>

#define NUM_E   20000
#define H_DIM   200
#define TD_DIM  48
#define HD_DIM  24
#define L_HIST  32
#define N_HIST  3
#define E_EDGES 200000
#define BATCH   512

// ---------------------------------------------------------------- utilities

__device__ inline float wave_sum64(float x) {
    #pragma unroll
    for (int m = 1; m < 64; m <<= 1) x += __shfl_xor(x, m);
    return x;
}

__device__ inline ushort f2bf(float f) {   // round-to-nearest-even f32 -> bf16
    unsigned u = __float_as_uint(f);
    u += 0x7fffu + ((u >> 16) & 1u);
    return (ushort)(u >> 16);
}

__global__ void fill_i32(int* __restrict__ p, long n, int v) {
    long i = (long)blockIdx.x * blockDim.x + threadIdx.x;
    if (i < n) p[i] = v;
}

__global__ void bias_sum(float* __restrict__ bsum, const float* __restrict__ b_ih,
                         const float* __restrict__ b_hh) {
    int j = blockIdx.x * 256 + threadIdx.x;
    if (j < 600) bsum[j] = b_ih[j] + b_hh[j];
}

__global__ void cvt_bf16_k(ushort* __restrict__ o, const float* __restrict__ in, long n) {
    long i = (long)blockIdx.x * 256 + threadIdx.x;
    if (i < n) o[i] = f2bf(in[i]);
}

// in (R,C) row-major f32 -> o (C,R) row-major bf16
__global__ void tcvt_bf16_k(ushort* __restrict__ o, const float* __restrict__ in, int R, int C) {
    int i = blockIdx.x * 256 + threadIdx.x;
    if (i >= R * C) return;
    int r = i / C, c = i - r * C;
    o[(size_t)c * R + r] = f2bf(in[i]);
}

// ---------------------------------------------------------------- f32 multi-segment GEMM
// (kept for batch head + final scoring GEMM)
struct Segs {
    const float* A[4];
    const float* B[4];
    int lda[4], ldb[4], Ks[4];
    int nseg, Ktot;
};

__device__ inline void seg_find(const Segs& sg, int gk, int& s, int& loc) {
    s = 0; loc = gk;
    #pragma unroll
    for (int t = 0; t < 3; t++) {
        if (s + 1 < sg.nseg && loc >= sg.Ks[s]) { loc -= sg.Ks[s]; s++; }
    }
}

// ACT: 0 none, 1 relu. BT=1 only used. order: 0 = A-reuse (y contig/XCD), 1 = B-reuse.
template<int ACT, int BM>
__global__ __launch_bounds__(256) void sgemm_seg(
    float* __restrict__ C, const Segs sg, const float* __restrict__ bias,
    int M, int N, int ldc, int nbx, int nby, int order)
{
    constexpr int MR = BM / 16;
    __shared__ float As[32][BM + 4];
    __shared__ float Bs[32][68];

    int tot = nbx * nby;
    int chunk = (tot + 7) >> 3;
    int v = (int)(blockIdx.x & 7) * chunk + (int)(blockIdx.x >> 3);
    if (v >= tot) return;
    int bx, by;
    if (order == 0) { by = v / nbx; bx = v - by * nbx; }
    else            { bx = v / nby; by = v - bx * nby; }
    const int bn = bx * 64;
    const int bm = by * BM;
    const int tid = threadIdx.x;
    const int m0 = (tid >> 4) * MR;
    const int n0 = (tid & 15) * 4;

    float acc[MR][4];
    #pragma unroll
    for (int i = 0; i < MR; i++)
        #pragma unroll
        for (int j = 0; j < 4; j++) acc[i][j] = 0.f;

    const int Ktot = sg.Ktot;
    const int ntile = (Ktot + 31) / 32;

    const int a_m  = tid & 31;
    const int a_k4 = (tid >> 5) * 4;
    const int b1_n = tid & 63;
    const int b1_k = (tid >> 6) * 4;

    for (int t = 0; t < ntile; t++) {
        const int k0 = t * 32;
        {
            int gk = k0 + a_k4;
            bool kin = gk < Ktot;
            int s = 0, loc = 0;
            if (kin) seg_find(sg, gk, s, loc);
            const float* Ab = sg.A[s];
            const int lda = sg.lda[s];
            #pragma unroll
            for (int r = 0; r < BM / 32; r++) {
                int m = a_m + 32 * r;
                int row = bm + m;
                float4 vv = {0.f, 0.f, 0.f, 0.f};
                if (kin && row < M) vv = *(const float4*)(Ab + (size_t)row * lda + loc);
                As[a_k4 + 0][m] = vv.x;
                As[a_k4 + 1][m] = vv.y;
                As[a_k4 + 2][m] = vv.z;
                As[a_k4 + 3][m] = vv.w;
            }
        }
        #pragma unroll
        for (int r = 0; r < 2; r++) {
            int k4 = b1_k + 16 * r;
            int gk = k0 + k4;
            bool kin = gk < Ktot;
            int s = 0, loc = 0;
            if (kin) seg_find(sg, gk, s, loc);
            const float* Bb = sg.B[s];
            const int ldb = sg.ldb[s];
            int gn = bn + b1_n;
            float4 vv = {0.f, 0.f, 0.f, 0.f};
            if (kin && gn < N) vv = *(const float4*)(Bb + (size_t)gn * ldb + loc);
            Bs[k4 + 0][b1_n] = vv.x;
            Bs[k4 + 1][b1_n] = vv.y;
            Bs[k4 + 2][b1_n] = vv.z;
            Bs[k4 + 3][b1_n] = vv.w;
        }
        __syncthreads();

        #pragma unroll 8
        for (int kk = 0; kk < 32; kk++) {
            float4 b = *(float4*)&Bs[kk][n0];
            float a[MR];
            #pragma unroll
            for (int q = 0; q < MR / 4; q++) {
                float4 av = *(float4*)&As[kk][m0 + q * 4];
                a[q*4 + 0] = av.x; a[q*4 + 1] = av.y;
                a[q*4 + 2] = av.z; a[q*4 + 3] = av.w;
            }
            #pragma unroll
            for (int i = 0; i < MR; i++) {
                acc[i][0] += a[i] * b.x;
                acc[i][1] += a[i] * b.y;
                acc[i][2] += a[i] * b.z;
                acc[i][3] += a[i] * b.w;
            }
        }
        __syncthreads();
    }

    int col = bn + n0;
    if (col < N) {
        float4 bv = {0.f, 0.f, 0.f, 0.f};
        if (bias) bv = *(const float4*)(bias + col);
        #pragma unroll
        for (int i = 0; i < MR; i++) {
            int row = bm + m0 + i;
            if (row < M) {
                float4 o;
                o.x = acc[i][0] + bv.x;
                o.y = acc[i][1] + bv.y;
                o.z = acc[i][2] + bv.z;
                o.w = acc[i][3] + bv.w;
                if (ACT == 1) {
                    o.x = fmaxf(o.x, 0.f); o.y = fmaxf(o.y, 0.f);
                    o.z = fmaxf(o.z, 0.f); o.w = fmaxf(o.w, 0.f);
                }
                *(float4*)(C + (size_t)row * ldc + col) = o;
            }
        }
    }
}

// ---------------------------------------------------------------- bf16 MFMA multi-segment GEMM
// C = act( sum_seg A_s @ B_s^T + bias ).  A_s: (M,Ks) bf16 row-major; B_s: (N,Ks) bf16 row-major.
// BM=128, BN=64, BK=64; 256 threads = 4 waves; wave tile 64x32 via 4x2 mfma_f32_16x16x32_bf16.
// All segment Ks and lda/ldb are multiples of 8 (16B alignment).

typedef __attribute__((ext_vector_type(8))) short bfrag;
typedef __attribute__((ext_vector_type(4))) float ffrag;

struct BfSegs {
    const ushort* A[3];
    const ushort* B[3];
    int lda[3], ldb[3], Ks[3];
    int nseg, Ktot;
};

__device__ inline void bseg_find(const BfSegs& sg, int gk, int& s, int& loc) {
    s = 0; loc = gk;
    #pragma unroll
    for (int t = 0; t < 2; t++) {
        if (s + 1 < sg.nseg && loc >= sg.Ks[s]) { loc -= sg.Ks[s]; s++; }
    }
}

// ACT: 0 none, 1 relu, 2 sigmoid. BFOUT: also write bf16 mirror Cb.
template<int ACT, int BFOUT>
__global__ __launch_bounds__(256) void mfma_seg(
    float* __restrict__ C, ushort* __restrict__ Cb, const BfSegs sg,
    const float* __restrict__ bias, int M, int N, int ldc, int nbx)
{
    __shared__ __align__(16) ushort Als[8192];  // [mt(8)][kt(2)][lane(64)][8]
    __shared__ __align__(16) ushort Bls[4096];  // [nt(4)][kt(2)][lane(64)][8]

    int tot = nbx * ((M + 127) >> 7);
    int chunk = (tot + 7) >> 3;
    int v = (int)(blockIdx.x & 7) * chunk + (int)(blockIdx.x >> 3);
    if (v >= tot) return;
    int by = v / nbx, bx = v - by * nbx;
    const int bm = by * 128, bn = bx * 64;

    const int tid  = threadIdx.x;
    const int lane = tid & 63;
    const int w    = tid >> 6;
    const int wm   = (w & 1) * 4;    // mtg base: 0 or 4
    const int wn   = (w >> 1) * 2;   // ntg base: 0 or 2

    ffrag acc[4][2];
    #pragma unroll
    for (int i = 0; i < 4; i++)
        #pragma unroll
        for (int j = 0; j < 2; j++) acc[i][j] = (ffrag){0.f, 0.f, 0.f, 0.f};

    const int Ktot = sg.Ktot;
    const int nkt = (Ktot + 63) >> 6;

    for (int t = 0; t < nkt; t++) {
        const int k0 = t << 6;

        // stage A: 1024 chunks of 8 bf16, 4 per thread; lane-contiguous LDS writes
        #pragma unroll
        for (int i = 0; i < 4; i++) {
            int c = i * 256 + tid;
            int m = c & 127, kq = c >> 7;        // kq 0..7 (8-element k group)
            int gk = k0 + kq * 8;
            int row = bm + m;
            uint4 vv = {0u, 0u, 0u, 0u};
            if (gk < Ktot && row < M) {
                int s, loc; bseg_find(sg, gk, s, loc);
                vv = *(const uint4*)(sg.A[s] + (size_t)row * sg.lda[s] + loc);
            }
            int wc = ((m >> 4) * 2 + (kq >> 2)) * 64 + (kq & 3) * 16 + (m & 15);
            *(uint4*)(&Als[wc * 8]) = vv;
        }
        // stage B: 512 chunks, 2 per thread
        #pragma unroll
        for (int i = 0; i < 2; i++) {
            int c = i * 256 + tid;
            int n = c & 63, kq = c >> 6;
            int gk = k0 + kq * 8;
            int gn = bn + n;
            uint4 vv = {0u, 0u, 0u, 0u};
            if (gk < Ktot && gn < N) {
                int s, loc; bseg_find(sg, gk, s, loc);
                vv = *(const uint4*)(sg.B[s] + (size_t)gn * sg.ldb[s] + loc);
            }
            int wc = ((n >> 4) * 2 + (kq >> 2)) * 64 + (kq & 3) * 16 + (n & 15);
            *(uint4*)(&Bls[wc * 8]) = vv;
        }
        __syncthreads();

        #pragma unroll
        for (int kt = 0; kt < 2; kt++) {
            bfrag af[4], bf[2];
            #pragma unroll
            for (int i = 0; i < 4; i++)
                af[i] = *(const bfrag*)(&Als[(((wm + i) * 2 + kt) * 64 + lane) * 8]);
            #pragma unroll
            for (int j = 0; j < 2; j++)
                bf[j] = *(const bfrag*)(&Bls[(((wn + j) * 2 + kt) * 64 + lane) * 8]);
            #pragma unroll
            for (int i = 0; i < 4; i++)
                #pragma unroll
                for (int j = 0; j < 2; j++)
                    acc[i][j] = __builtin_amdgcn_mfma_f32_16x16x32_bf16(af[i], bf[j], acc[i][j], 0, 0, 0);
        }
        __syncthreads();
    }

    // epilogue: C/D layout col=lane&15, row=(lane>>4)*4+reg
    const int rbase = (lane >> 4) * 4;
    const int cl = lane & 15;
    #pragma unroll
    for (int j = 0; j < 2; j++) {
        int col = bn + (wn + j) * 16 + cl;
        if (col >= N) continue;
        float bv = bias ? bias[col] : 0.f;
        #pragma unroll
        for (int i = 0; i < 4; i++) {
            int mrow = bm + (wm + i) * 16 + rbase;
            #pragma unroll
            for (int r = 0; r < 4; r++) {
                int row = mrow + r;
                if (row < M) {
                    float o = acc[i][j][r] + bv;
                    if (ACT == 1) o = fmaxf(o, 0.f);
                    else if (ACT == 2) o = 1.f / (1.f + expf(-o));
                    C[(size_t)row * ldc + col] = o;
                    if (BFOUT) Cb[(size_t)row * ldc + col] = f2bf(o);
                }
            }
        }
    }
}

// ---------------------------------------------------------------- CSR build

__global__ void count_dst(const int* __restrict__ di, int* __restrict__ cnt, int E) {
    int e = blockIdx.x * 256 + threadIdx.x;
    if (e < E) atomicAdd(&cnt[di[e]], 1);
}

__global__ __launch_bounds__(1024) void scan_rows(
    const int* __restrict__ cnt, int* __restrict__ row_start, int* __restrict__ cursor,
    float* __restrict__ degf, float* __restrict__ invd)
{
    __shared__ int part[1024];
    const int CH = (NUM_E + 1023) / 1024;
    int t = threadIdx.x;
    int base = t * CH;
    int local[32];
    int s = 0;
    for (int j = 0; j < CH; j++) {
        int idx = base + j;
        int c = (idx < NUM_E) ? cnt[idx] : 0;
        local[j] = s; s += c;
    }
    part[t] = s;
    __syncthreads();
    for (int off = 1; off < 1024; off <<= 1) {
        int vv = (t >= off) ? part[t - off] : 0;
        __syncthreads();
        part[t] += vv;
        __syncthreads();
    }
    int pre = (t == 0) ? 0 : part[t - 1];
    for (int j = 0; j < CH; j++) {
        int idx = base + j;
        if (idx < NUM_E) {
            int rs = pre + local[j];
            row_start[idx] = rs;
            cursor[idx] = rs;
            int c = cnt[idx];
            degf[idx] = (float)c;
            invd[idx] = 1.f / fmaxf((float)c, 1.f);
        }
    }
    if (t == 1023) row_start[NUM_E] = part[1023];
}

__global__ void build_perm(const int* __restrict__ si, const int* __restrict__ di,
                           const int* __restrict__ ei, int* __restrict__ cursor,
                           int* __restrict__ ssrc, int* __restrict__ setype, int E)
{
    int e = blockIdx.x * 256 + threadIdx.x;
    if (e >= E) return;
    int pos = atomicAdd(&cursor[di[e]], 1);
    ssrc[pos]   = si[e];
    setype[pos] = ei[e];
}

// ---------------------------------------------------------------- gathers (f32 + bf16 out)

__global__ __launch_bounds__(256) void seg_gather_norm(
    float* __restrict__ h, ushort* __restrict__ bh, const float* __restrict__ prev,
    const int* __restrict__ ssrc, const int* __restrict__ row_start,
    const float* __restrict__ invd)
{
    int v = blockIdx.x * 4 + (threadIdx.x >> 6);
    int lane = threadIdx.x & 63;
    if (v >= NUM_E) return;
    int s0 = row_start[v], s1 = row_start[v + 1];
    bool act = lane < 50;
    float4 acc = {0.f, 0.f, 0.f, 0.f};
    for (int j = s0; j < s1; j++) {
        int s = ssrc[j];
        if (act) {
            float4 x = *(const float4*)(prev + (long)s * H_DIM + lane * 4);
            acc.x += x.x; acc.y += x.y; acc.z += x.z; acc.w += x.w;
        }
    }
    float iv = invd[v];
    acc.x *= iv; acc.y *= iv; acc.z *= iv; acc.w *= iv;
    float ss = act ? (acc.x*acc.x + acc.y*acc.y + acc.z*acc.z + acc.w*acc.w) : 0.f;
    ss = wave_sum64(ss);
    float r = 1.f / fmaxf(sqrtf(ss), 1e-12f);
    if (act) {
        long base = (long)v * H_DIM + lane * 4;
        float4 o = {acc.x * r, acc.y * r, acc.z * r, acc.w * r};
        *(float4*)(h + base) = o;
        ushort4 ob = {f2bf(o.x), f2bf(o.y), f2bf(o.z), f2bf(o.w)};
        *(ushort4*)(bh + base) = ob;
    }
}

__global__ __launch_bounds__(256) void seg_gather_layer(
    float* __restrict__ tmp, ushort* __restrict__ btmp,
    const float* __restrict__ h, const float* __restrict__ reln,
    const int* __restrict__ ssrc, const int* __restrict__ setype,
    const int* __restrict__ row_start, const float* __restrict__ invd)
{
    int v = blockIdx.x * 4 + (threadIdx.x >> 6);
    int lane = threadIdx.x & 63;
    if (v >= NUM_E) return;
    int s0 = row_start[v], s1 = row_start[v + 1];
    bool act = lane < 50;
    float4 acc = {0.f, 0.f, 0.f, 0.f};
    for (int j = s0; j < s1; j++) {
        int s = ssrc[j];
        int t = setype[j];
        if (act) {
            float4 x = *(const float4*)(h    + (long)s * H_DIM + lane * 4);
            float4 y = *(const float4*)(reln + (long)t * H_DIM + lane * 4);
            acc.x += x.x + y.x; acc.y += x.y + y.y;
            acc.z += x.z + y.z; acc.w += x.w + y.w;
        }
    }
    float iv = invd[v];
    if (act) {
        long base = (long)v * H_DIM + lane * 4;
        float4 o = {acc.x * iv, acc.y * iv, acc.z * iv, acc.w * iv};
        *(float4*)(tmp + base) = o;
        ushort4 ob = {f2bf(o.x), f2bf(o.y), f2bf(o.z), f2bf(o.w)};
        *(ushort4*)(btmp + base) = ob;
    }
}

// ---------------------------------------------------------------- row kernels

__global__ __launch_bounds__(256) void l2norm_rows4(
    float* __restrict__ out, ushort* __restrict__ bout,
    const float* __restrict__ in, int nrows)
{
    int v = blockIdx.x * 4 + (threadIdx.x >> 6);
    int lane = threadIdx.x & 63;
    if (v >= nrows) return;
    bool act = lane < 50;
    float4 x = {0.f, 0.f, 0.f, 0.f};
    if (act) x = *(const float4*)(in + (long)v * H_DIM + lane * 4);
    float ss = x.x*x.x + x.y*x.y + x.z*x.z + x.w*x.w;
    ss = wave_sum64(ss);
    float r = 1.f / fmaxf(sqrtf(ss), 1e-12f);
    if (act) {
        long base = (long)v * H_DIM + lane * 4;
        float4 o = {x.x * r, x.y * r, x.z * r, x.w * r};
        *(float4*)(out + base) = o;
        if (bout) {
            ushort4 ob = {f2bf(o.x), f2bf(o.y), f2bf(o.z), f2bf(o.w)};
            *(ushort4*)(bout + base) = ob;
        }
    }
}

// te (bf16 only, ld 48)
__global__ void tenc_ent(ushort* __restrict__ bte, const float* __restrict__ deg,
                         const float* __restrict__ af, const float* __restrict__ ap,
                         const float* __restrict__ cf, const float* __restrict__ cp,
                         float tcnt, int M)
{
    int idx = blockIdx.x * 256 + threadIdx.x;
    if (idx >= M * TD_DIM) return;
    int v = idx / TD_DIM, j = idx % TD_DIM;
    float t = (deg[v] > 0.f) ? tcnt : 100.0f;
    float val;
    if (j < HD_DIM) val = tanhf((t + 1.f) * af[j] + ap[j]);
    else            val = cosf(t * cf[j - HD_DIM] + cp[j - HD_DIM]);
    bte[idx] = f2bf(val);
}

// prev = l2norm((1-z)*tanh(iN + r*hN) + z*prev); rz ld 400 (sigmoid already applied)
__global__ __launch_bounds__(256) void gru_fused(
    float* __restrict__ prev, ushort* __restrict__ bprev, const float* __restrict__ rz,
    const float* __restrict__ iN, const float* __restrict__ hN)
{
    int v = blockIdx.x * 4 + (threadIdx.x >> 6);
    int lane = threadIdx.x & 63;
    if (v >= NUM_E) return;
    bool act = lane < 50;
    long b200 = (long)v * H_DIM + lane * 4;
    long b400 = (long)v * 400 + lane * 4;
    float4 o = {0.f, 0.f, 0.f, 0.f};
    if (act) {
        float4 r4 = *(const float4*)(rz + b400);
        float4 z4 = *(const float4*)(rz + b400 + 200);
        float4 n4 = *(const float4*)(iN + b200);
        float4 g4 = *(const float4*)(hN + b200);
        float4 p4 = *(const float4*)(prev + b200);
        float ngx = tanhf(n4.x + r4.x * g4.x);
        float ngy = tanhf(n4.y + r4.y * g4.y);
        float ngz = tanhf(n4.z + r4.z * g4.z);
        float ngw = tanhf(n4.w + r4.w * g4.w);
        o.x = (1.f - z4.x) * ngx + z4.x * p4.x;
        o.y = (1.f - z4.y) * ngy + z4.y * p4.y;
        o.z = (1.f - z4.z) * ngz + z4.z * p4.z;
        o.w = (1.f - z4.w) * ngw + z4.w * p4.w;
    }
    float ss = o.x*o.x + o.y*o.y + o.z*o.z + o.w*o.w;
    ss = wave_sum64(ss);
    float r = 1.f / fmaxf(sqrtf(ss), 1e-12f);
    if (act) {
        float4 wv = {o.x * r, o.y * r, o.z * r, o.w * r};
        *(float4*)(prev + b200) = wv;
        ushort4 ob = {f2bf(wv.x), f2bf(wv.y), f2bf(wv.z), f2bf(wv.w)};
        *(ushort4*)(bprev + b200) = ob;
    }
}

// ---------------------------------------------------------------- batch head

__global__ void gather_qs_qr3(float* __restrict__ qs3, float* __restrict__ qr3,
                              const float* __restrict__ out, const float* __restrict__ reln,
                              const int* __restrict__ data)
{
    long i = (long)blockIdx.x * 256 + threadIdx.x;
    if (i >= (long)BATCH * H_DIM) return;
    int b = (int)(i / H_DIM), j = (int)(i % H_DIM);
    float vs = out[(long)data[b * 4 + 0] * H_DIM + j];
    float vr = reln[(long)data[b * 4 + 1] * H_DIM + j];
    const long S = (long)BATCH * H_DIM;
    qs3[i] = vs; qs3[i + S] = vs; qs3[i + 2*S] = vs;
    qr3[i] = vr; qr3[i + S] = vr; qr3[i + 2*S] = vr;
}

__global__ __launch_bounds__(64) void semb_kernel(
    float* __restrict__ semb, const float* __restrict__ out,
    const int* __restrict__ his_idx, const int* __restrict__ his_len)
{
    int b = blockIdx.x, k = blockIdx.y;
    int lane = threadIdx.x;
    int ln = his_len[b * 3 + k];
    if (ln > L_HIST) ln = L_HIST;
    float vals[4] = {0.f, 0.f, 0.f, 0.f};
    for (int l = 0; l < ln; l++) {
        int idx = his_idx[((long)b * 3 + k) * L_HIST + l];
        #pragma unroll
        for (int t = 0; t < 4; t++) {
            int j = lane + t * 64;
            if (j < H_DIM) vals[t] += out[(long)idx * H_DIM + j];
        }
    }
    float scale = 1.f / fmaxf((float)ln, 1.f);
    float ss = 0.f;
    #pragma unroll
    for (int t = 0; t < 4; t++) { vals[t] *= scale; ss += vals[t] * vals[t]; }
    ss = wave_sum64(ss);
    float r = 1.f / fmaxf(sqrtf(ss), 1e-12f);
    #pragma unroll
    for (int t = 0; t < 4; t++) {
        int j = lane + t * 64;
        if (j < H_DIM) semb[((long)k * BATCH + b) * H_DIM + j] = vals[t] * r;
    }
}

__global__ void tenc_batch(float* __restrict__ teb, const int* __restrict__ his_len,
                           const float* __restrict__ af, const float* __restrict__ ap,
                           const float* __restrict__ cf, const float* __restrict__ cp)
{
    int idx = blockIdx.x * 256 + threadIdx.x;
    if (idx >= 3 * BATCH * TD_DIM) return;
    int k = idx / (BATCH * TD_DIM);
    int rem = idx - k * (BATCH * TD_DIM);
    int b = rem / TD_DIM, j = rem % TD_DIM;
    int ln = his_len[b * 3 + k];
    float t = (ln > 0) ? (float)(2 - k) : 100.0f;
    float val;
    if (j < HD_DIM) val = tanhf((t + 1.f) * af[j] + ap[j]);
    else            val = cosf(t * cf[j - HD_DIM] + cp[j - HD_DIM]);
    teb[idx] = val;
}

__global__ __launch_bounds__(256) void att_logits_rows(
    float* __restrict__ atts, const float* __restrict__ a,
    const float* __restrict__ Wc_w, const float* __restrict__ Wc_b)
{
    int row = blockIdx.x * 4 + (threadIdx.x >> 6);
    int lane = threadIdx.x & 63;
    if (row >= 3 * BATCH) return;
    int k = row >> 9;
    int b = row & 511;
    float s = 0.f;
    for (int j = lane; j < H_DIM; j += 64) s += a[(long)row * H_DIM + j] * Wc_w[j];
    s = wave_sum64(s);
    if (lane == 0) atts[b * 3 + k] = s + Wc_b[0];
}

__global__ void softmax_out2(float* __restrict__ out2, const float* __restrict__ atts,
                             const float* __restrict__ semb)
{
    long i = (long)blockIdx.x * 256 + threadIdx.x;
    if (i >= (long)BATCH * H_DIM) return;
    int b = (int)(i / H_DIM), j = (int)(i % H_DIM);
    float l0 = atts[b * 3 + 0], l1 = atts[b * 3 + 1], l2 = atts[b * 3 + 2];
    float m = fmaxf(l0, fmaxf(l1, l2));
    float e0 = expf(l0 - m), e1 = expf(l1 - m), e2 = expf(l2 - m);
    float s = e0 + e1 + e2;
    float v = (e0 * semb[((long)0 * BATCH + b) * H_DIM + j] +
               e1 * semb[((long)1 * BATCH + b) * H_DIM + j] +
               e2 * semb[((long)2 * BATCH + b) * H_DIM + j]) / s;
    out2[i] = v;
}

// ---------------------------------------------------------------- launch

extern "C" void kernel_launch(void* const* d_in, const int* in_sizes, int n_in,
                              void* d_out, int out_size, void* d_ws, size_t ws_size,
                              hipStream_t stream)
{
    (void)in_sizes; (void)n_in; (void)out_size; (void)ws_size;

    const int*   src     = (const int*)d_in[0];
    const int*   dst     = (const int*)d_in[1];
    const int*   etype   = (const int*)d_in[2];
    const int*   data    = (const int*)d_in[3];
    const int*   his_idx = (const int*)d_in[4];
    const int*   his_len = (const int*)d_in[5];
    const float* ent     = (const float*)d_in[6];
    const float* loop_w  = (const float*)d_in[7];
    const float* rel     = (const float*)d_in[8];
    const float* af      = (const float*)d_in[9];
    const float* ap      = (const float*)d_in[10];
    const float* cf      = (const float*)d_in[11];
    const float* cp      = (const float*)d_in[12];
    const float* Wn      = (const float*)d_in[13];
    const float* Ws      = (const float*)d_in[14];
    const float* W_ih    = (const float*)d_in[15];
    const float* W_hh    = (const float*)d_in[16];
    const float* b_ih    = (const float*)d_in[17];
    const float* b_hh    = (const float*)d_in[18];
    const float* Wb_w    = (const float*)d_in[19];
    const float* Wb_b    = (const float*)d_in[20];
    const float* Wc_w    = (const float*)d_in[21];
    const float* Wc_b    = (const float*)d_in[22];
    const float* Wd_w    = (const float*)d_in[23];
    const float* Wd_b    = (const float*)d_in[24];
    float* out_p = (float*)d_out;

    float* wp = (float*)d_ws;
    size_t off = 0;
    auto alloc = [&](size_t n) {                 // 16B-aligned float allocation
        size_t n4 = (n + 3) & ~(size_t)3;
        float* p = wp + off; off += n4; return p;
    };
    const long nE200 = (long)NUM_E * H_DIM;
    float* prev   = alloc(nE200);
    float* h0     = alloc(nE200);
    float* h1     = alloc(nE200);                       // layer ping-pong; GRU iN
    float* tmp    = alloc(nE200);                       // gather target; GRU hN; init gemm out
    float* rz     = out_p;                              // (NUM_E x 400) scratch in d_out; overwritten at end
    ushort* bh0   = (ushort*)alloc(nE200 / 2);
    ushort* bh1   = (ushort*)alloc(nE200 / 2);
    ushort* btmp  = (ushort*)alloc(nE200 / 2);          // also bent for init
    ushort* bprev = (ushort*)alloc(nE200 / 2);
    ushort* bte   = (ushort*)alloc((size_t)NUM_E * TD_DIM / 2);
    ushort* bW_ih = (ushort*)alloc(600 * 248 / 2);
    ushort* bW_hh = (ushort*)alloc(600 * 200 / 2);
    ushort* bWn_t = (ushort*)alloc(2 * 200 * 200 / 2);
    ushort* bWs_t = (ushort*)alloc(2 * 200 * 200 / 2);
    ushort* bLp_t = (ushort*)alloc(200 * 200 / 2);
    float* degf   = alloc(NUM_E);
    float* invd   = alloc(NUM_E);
    float* reln   = alloc(400 * H_DIM);
    float* bsum   = alloc(1024);
    float* qs3    = alloc(3 * BATCH * H_DIM);
    float* qr3    = alloc(3 * BATCH * H_DIM);
    float* semb   = alloc(3 * BATCH * H_DIM);
    float* teb    = alloc(3 * BATCH * TD_DIM);
    float* abuf   = alloc(3 * BATCH * H_DIM);
    float* atts   = alloc(2048);
    float* out2   = alloc(BATCH * H_DIM);
    float* qbuf   = alloc(BATCH * H_DIM);
    int* cnt       = (int*)alloc(NUM_E);
    int* row_start = (int*)alloc(NUM_E + 4);
    int* cursor    = (int*)alloc(NUM_E);
    int* ssrc      = (int*)alloc(E_EDGES);
    int* setype    = (int*)alloc(E_EDGES);

    auto nblk = [](long n) { return (unsigned)((n + 255) / 256); };

    // ---- bf16 segment builders ----
    auto bseg1 = [](const ushort* A, int la, const ushort* B, int lb, int K) {
        BfSegs s{}; s.A[0]=A; s.lda[0]=la; s.B[0]=B; s.ldb[0]=lb; s.Ks[0]=K;
        s.nseg=1; s.Ktot=K; return s;
    };
    auto bseg2 = [](const ushort* A0, int la0, const ushort* B0, int lb0, int K0,
                    const ushort* A1, int la1, const ushort* B1, int lb1, int K1) {
        BfSegs s{}; s.A[0]=A0; s.lda[0]=la0; s.B[0]=B0; s.ldb[0]=lb0; s.Ks[0]=K0;
        s.A[1]=A1; s.lda[1]=la1; s.B[1]=B1; s.ldb[1]=lb1; s.Ks[1]=K1;
        s.nseg=2; s.Ktot=K0+K1; return s;
    };
    auto bseg3 = [](const ushort* A0, int la0, const ushort* B0, int lb0, int K0,
                    const ushort* A1, int la1, const ushort* B1, int lb1, int K1,
                    const ushort* A2, int la2, const ushort* B2, int lb2, int K2) {
        BfSegs s{}; s.A[0]=A0; s.lda[0]=la0; s.B[0]=B0; s.ldb[0]=lb0; s.Ks[0]=K0;
        s.A[1]=A1; s.lda[1]=la1; s.B[1]=B1; s.ldb[1]=lb1; s.Ks[1]=K1;
        s.A[2]=A2; s.lda[2]=la2; s.B[2]=B2; s.ldb[2]=lb2; s.Ks[2]=K2;
        s.nseg=3; s.Ktot=K0+K1+K2; return s;
    };

    auto mfma = [&](int ACT, int BFOUT, float* C, ushort* Cb, const BfSegs& sg,
                    const float* bias, int M, int N, int ldc) {
        int nbx = (N + 63) >> 6;
        int tot = nbx * ((M + 127) >> 7);
        unsigned grid = (unsigned)(((tot + 7) >> 3) << 3);
        if (ACT == 0)      mfma_seg<0,0><<<grid, 256, 0, stream>>>(C, Cb, sg, bias, M, N, ldc, nbx);
        else if (ACT == 1) mfma_seg<1,1><<<grid, 256, 0, stream>>>(C, Cb, sg, bias, M, N, ldc, nbx);
        else               mfma_seg<2,0><<<grid, 256, 0, stream>>>(C, Cb, sg, bias, M, N, ldc, nbx);
    };

    // ---- f32 segment builders (batch head + final) ----
    auto seg1 = [](const float* A, int la, const float* B, int lb, int K) {
        Segs s{}; s.A[0]=A; s.lda[0]=la; s.B[0]=B; s.ldb[0]=lb; s.Ks[0]=K;
        s.nseg=1; s.Ktot=K; return s;
    };
    auto seg3 = [](const float* A0, int la0, const float* B0, int lb0, int K0,
                   const float* A1, int la1, const float* B1, int lb1, int K1,
                   const float* A2, int la2, const float* B2, int lb2, int K2) {
        Segs s{}; s.A[0]=A0; s.lda[0]=la0; s.B[0]=B0; s.ldb[0]=lb0; s.Ks[0]=K0;
        s.A[1]=A1; s.lda[1]=la1; s.B[1]=B1; s.ldb[1]=lb1; s.Ks[1]=K1;
        s.A[2]=A2; s.lda[2]=la2; s.B[2]=B2; s.ldb[2]=lb2; s.Ks[2]=K2;
        s.nseg=3; s.Ktot=K0+K1+K2; return s;
    };
    auto seg4 = [](const float* A0, int la0, const float* B0, int lb0, int K0,
                   const float* A1, int la1, const float* B1, int lb1, int K1,
                   const float* A2, int la2, const float* B2, int lb2, int K2,
                   const float* A3, int la3, const float* B3, int lb3, int K3) {
        Segs s{}; s.A[0]=A0; s.lda[0]=la0; s.B[0]=B0; s.ldb[0]=lb0; s.Ks[0]=K0;
        s.A[1]=A1; s.lda[1]=la1; s.B[1]=B1; s.ldb[1]=lb1; s.Ks[1]=K1;
        s.A[2]=A2; s.lda[2]=la2; s.B[2]=B2; s.ldb[2]=lb2; s.Ks[2]=K2;
        s.A[3]=A3; s.lda[3]=la3; s.B[3]=B3; s.ldb[3]=lb3; s.Ks[3]=K3;
        s.nseg=4; s.Ktot=K0+K1+K2+K3; return s;
    };
    auto fgemm = [&](int ACT, int BM, int order, float* C, const Segs& sg,
                     const float* bias, int M, int N, int ldc) {
        int nbx = (N + 63) >> 6;
        int nby = (M + BM - 1) / BM;
        unsigned grid = (unsigned)((((nbx * nby) + 7) >> 3) << 3);
        if (BM == 128) {
            if (ACT == 0) sgemm_seg<0,128><<<grid, 256, 0, stream>>>(C, sg, bias, M, N, ldc, nbx, nby, order);
            else          sgemm_seg<1,128><<<grid, 256, 0, stream>>>(C, sg, bias, M, N, ldc, nbx, nby, order);
        } else {
            if (ACT == 0) sgemm_seg<0,64><<<grid, 256, 0, stream>>>(C, sg, bias, M, N, ldc, nbx, nby, order);
            else          sgemm_seg<1,64><<<grid, 256, 0, stream>>>(C, sg, bias, M, N, ldc, nbx, nby, order);
        }
    };

    const unsigned r4 = (NUM_E + 3) / 4;

    // ---- prelude: normalize rel, bias sums, weight conversions ----
    l2norm_rows4<<<100, 256, 0, stream>>>(reln, nullptr, rel, 400);
    bias_sum<<<3, 256, 0, stream>>>(bsum, b_ih, b_hh);
    cvt_bf16_k<<<nblk(600L*248), 256, 0, stream>>>(bW_ih, W_ih, 600L*248);
    cvt_bf16_k<<<nblk(600L*200), 256, 0, stream>>>(bW_hh, W_hh, 600L*200);
    tcvt_bf16_k<<<nblk(40000), 256, 0, stream>>>(bLp_t, loop_w, 200, 200);
    tcvt_bf16_k<<<nblk(40000), 256, 0, stream>>>(bWn_t,          Wn,          200, 200);
    tcvt_bf16_k<<<nblk(40000), 256, 0, stream>>>(bWn_t + 40000,  Wn + 40000,  200, 200);
    tcvt_bf16_k<<<nblk(40000), 256, 0, stream>>>(bWs_t,          Ws,          200, 200);
    tcvt_bf16_k<<<nblk(40000), 256, 0, stream>>>(bWs_t + 40000,  Ws + 40000,  200, 200);

    // prev = l2norm(ent @ loop_weight): bent in btmp region
    cvt_bf16_k<<<nblk(nE200), 256, 0, stream>>>(btmp, ent, nE200);
    mfma(0, 0, tmp, nullptr, bseg1(btmp, H_DIM, bLp_t, H_DIM, H_DIM), nullptr, NUM_E, H_DIM, H_DIM);
    l2norm_rows4<<<r4, 256, 0, stream>>>(prev, bprev, tmp, NUM_E);

    for (int i = 0; i < N_HIST; i++) {
        const int* si = src   + (long)i * E_EDGES;
        const int* di = dst   + (long)i * E_EDGES;
        const int* ei = etype + (long)i * E_EDGES;
        float tcnt = (float)(N_HIST - 1 - i);

        // CSR build
        fill_i32<<<nblk(NUM_E), 256, 0, stream>>>(cnt, NUM_E, 0);
        count_dst<<<nblk(E_EDGES), 256, 0, stream>>>(di, cnt, E_EDGES);
        scan_rows<<<1, 1024, 0, stream>>>(cnt, row_start, cursor, degf, invd);
        build_perm<<<nblk(E_EDGES), 256, 0, stream>>>(si, di, ei, cursor, ssrc, setype, E_EDGES);

        // h0 = l2norm(segsum(prev)*inv)
        seg_gather_norm<<<r4, 256, 0, stream>>>(h0, bh0, prev, ssrc, row_start, invd);
        tenc_ent<<<nblk((long)NUM_E * TD_DIM), 256, 0, stream>>>(bte, degf, af, ap, cf, cp, tcnt, NUM_E);

        // layer 0: h1 = relu([tmp|h0] @ [Wn0;Ws0])
        seg_gather_layer<<<r4, 256, 0, stream>>>(tmp, btmp, h0, reln, ssrc, setype, row_start, invd);
        mfma(1, 1, h1, bh1,
             bseg2(btmp, H_DIM, bWn_t,         H_DIM, H_DIM,
                   bh0,  H_DIM, bWs_t,         H_DIM, H_DIM),
             nullptr, NUM_E, H_DIM, H_DIM);
        // layer 1: h0 = relu([tmp|h1] @ [Wn1;Ws1])
        seg_gather_layer<<<r4, 256, 0, stream>>>(tmp, btmp, h1, reln, ssrc, setype, row_start, invd);
        mfma(1, 1, h0, bh0,
             bseg2(btmp, H_DIM, bWn_t + 40000, H_DIM, H_DIM,
                   bh1,  H_DIM, bWs_t + 40000, H_DIM, H_DIM),
             nullptr, NUM_E, H_DIM, H_DIM);
        // h = l2norm(h) in place, refresh bh0
        l2norm_rows4<<<r4, 256, 0, stream>>>(h0, bh0, h0, NUM_E);

        // GRU: rz (N=400, sigmoid fused, in d_out scratch), iN -> h1, hN -> tmp
        mfma(2, 0, rz, nullptr,
             bseg3(bh0,   H_DIM,  bW_ih,       248, H_DIM,
                   bte,   TD_DIM, bW_ih + 200, 248, TD_DIM,
                   bprev, H_DIM,  bW_hh,       200, H_DIM),
             bsum, NUM_E, 400, 400);
        mfma(0, 0, h1, nullptr,
             bseg2(bh0, H_DIM,  bW_ih + 400*248,       248, H_DIM,
                   bte, TD_DIM, bW_ih + 400*248 + 200, 248, TD_DIM),
             b_ih + 400, NUM_E, H_DIM, H_DIM);
        mfma(0, 0, tmp, nullptr,
             bseg1(bprev, H_DIM, bW_hh + 400*200, 200, H_DIM),
             b_hh + 400, NUM_E, H_DIM, H_DIM);

        gru_fused<<<r4, 256, 0, stream>>>(prev, bprev, rz, h1, tmp);
    }

    // ---- batch head (f32) ----
    gather_qs_qr3<<<nblk((long)BATCH * H_DIM), 256, 0, stream>>>(qs3, qr3, prev, reln, data);
    semb_kernel<<<dim3(BATCH, 3), 64, 0, stream>>>(semb, prev, his_idx, his_len);
    tenc_batch<<<nblk(3L * BATCH * TD_DIM), 256, 0, stream>>>(teb, his_len, af, ap, cf, cp);

    fgemm(1, 64, 0, abuf,
          seg4(qs3, H_DIM,  Wb_w,       648, H_DIM,
               qr3, H_DIM,  Wb_w + 200, 648, H_DIM,
               semb, H_DIM, Wb_w + 400, 648, H_DIM,
               teb, TD_DIM, Wb_w + 600, 648, TD_DIM),
          Wb_b, 3 * BATCH, H_DIM, H_DIM);
    att_logits_rows<<<(3 * BATCH + 3) / 4, 256, 0, stream>>>(atts, abuf, Wc_w, Wc_b);
    softmax_out2<<<nblk((long)BATCH * H_DIM), 256, 0, stream>>>(out2, atts, semb);

    fgemm(1, 64, 0, qbuf,
          seg3(qs3, H_DIM,  Wd_w,       600, H_DIM,
               qr3, H_DIM,  Wd_w + 200, 600, H_DIM,
               out2, H_DIM, Wd_w + 400, 600, H_DIM),
          Wd_b, BATCH, H_DIM, H_DIM);

    // result = q @ prev^T -> (512, 20000), f32, B-reuse swizzle
    fgemm(0, 128, 1, out_p, seg1(qbuf, H_DIM, prev, H_DIM, H_DIM), nullptr,
          BATCH, NUM_E, NUM_E);
}

// Round 7
// 1459.075 us; speedup vs baseline: 7.2592x; 1.0583x over previous
//
#include <hip/hip_runtime.h>
#include <hip/hip_bf16.h>

#define NUM_E   20000
#define H_DIM   200
#define TD_DIM  48
#define HD_DIM  24
#define L_HIST  32
#define N_HIST  3
#define E_EDGES 200000
#define BATCH   512

// ---------------------------------------------------------------- utilities

__device__ inline float wave_sum64(float x) {
    #pragma unroll
    for (int m = 1; m < 64; m <<= 1) x += __shfl_xor(x, m);
    return x;
}

__device__ inline ushort f2bf(float f) {
    unsigned u = __float_as_uint(f);
    u += 0x7fffu + ((u >> 16) & 1u);
    return (ushort)(u >> 16);
}
__device__ inline float bf2f(ushort u) {
    return __uint_as_float(((unsigned)u) << 16);
}
__device__ inline float4 bf4_to_f4(ushort4 v) {
    return (float4){bf2f(v.x), bf2f(v.y), bf2f(v.z), bf2f(v.w)};
}

__global__ void fill_i32(int* __restrict__ p, long n, int v) {
    long i = (long)blockIdx.x * blockDim.x + threadIdx.x;
    if (i < n) p[i] = v;
}

__global__ void bias_sum(float* __restrict__ bsum, const float* __restrict__ b_ih,
                         const float* __restrict__ b_hh) {
    int j = blockIdx.x * 256 + threadIdx.x;
    if (j < 600) bsum[j] = b_ih[j] + b_hh[j];
}

__global__ void cvt_bf16_k(ushort* __restrict__ o, const float* __restrict__ in, long n) {
    long i = (long)blockIdx.x * 256 + threadIdx.x;
    if (i < n) o[i] = f2bf(in[i]);
}

// in (R,C) row-major f32 -> o (C,R) row-major bf16
__global__ void tcvt_bf16_k(ushort* __restrict__ o, const float* __restrict__ in, int R, int C) {
    int i = blockIdx.x * 256 + threadIdx.x;
    if (i >= R * C) return;
    int r = i / C, c = i - r * C;
    o[(size_t)c * R + r] = f2bf(in[i]);
}

// ---------------------------------------------------------------- f32 multi-segment GEMM (B^T)
struct Segs {
    const float* A[4];
    const float* B[4];
    int lda[4], ldb[4], Ks[4];
    int nseg, Ktot;
};

__device__ inline void seg_find(const Segs& sg, int gk, int& s, int& loc) {
    s = 0; loc = gk;
    #pragma unroll
    for (int t = 0; t < 3; t++) {
        if (s + 1 < sg.nseg && loc >= sg.Ks[s]) { loc -= sg.Ks[s]; s++; }
    }
}

// ACT: 0 none, 1 relu. order: 0 = A-reuse, 1 = B-reuse. Register-prefetch double buffered.
template<int ACT, int BM>
__global__ __launch_bounds__(256) void sgemm_seg(
    float* __restrict__ C, const Segs sg, const float* __restrict__ bias,
    int M, int N, int ldc, int nbx, int nby, int order)
{
    constexpr int MR = BM / 16;
    constexpr int AR = BM / 32;
    __shared__ float As[32][BM + 4];
    __shared__ float Bs[32][68];

    int tot = nbx * nby;
    int chunk = (tot + 7) >> 3;
    int v = (int)(blockIdx.x & 7) * chunk + (int)(blockIdx.x >> 3);
    if (v >= tot) return;
    int bx, by;
    if (order == 0) { by = v / nbx; bx = v - by * nbx; }
    else            { bx = v / nby; by = v - bx * nby; }
    const int bn = bx * 64;
    const int bm = by * BM;
    const int tid = threadIdx.x;
    const int m0 = (tid >> 4) * MR;
    const int n0 = (tid & 15) * 4;

    float acc[MR][4];
    #pragma unroll
    for (int i = 0; i < MR; i++)
        #pragma unroll
        for (int j = 0; j < 4; j++) acc[i][j] = 0.f;

    const int Ktot = sg.Ktot;
    const int ntile = (Ktot + 31) / 32;

    const int a_m  = tid & 31;
    const int a_k4 = (tid >> 5) * 4;
    const int b1_n = tid & 63;
    const int b1_k = (tid >> 6) * 4;

    float4 ra[AR], rb[2];

    auto loadA = [&](int k0) {
        int gk = k0 + a_k4;
        bool kin = gk < Ktot;
        int s = 0, loc = 0;
        if (kin) seg_find(sg, gk, s, loc);
        const float* Ab = sg.A[s];
        const int lda = sg.lda[s];
        #pragma unroll
        for (int r = 0; r < AR; r++) {
            int row = bm + a_m + 32 * r;
            float4 vv = {0.f, 0.f, 0.f, 0.f};
            if (kin && row < M) vv = *(const float4*)(Ab + (size_t)row * lda + loc);
            ra[r] = vv;
        }
    };
    auto loadB = [&](int k0) {
        #pragma unroll
        for (int r = 0; r < 2; r++) {
            int k4 = b1_k + 16 * r;
            int gk = k0 + k4;
            bool kin = gk < Ktot;
            int s = 0, loc = 0;
            if (kin) seg_find(sg, gk, s, loc);
            const float* Bb = sg.B[s];
            const int ldb = sg.ldb[s];
            int gn = bn + b1_n;
            float4 vv = {0.f, 0.f, 0.f, 0.f};
            if (kin && gn < N) vv = *(const float4*)(Bb + (size_t)gn * ldb + loc);
            rb[r] = vv;
        }
    };

    loadA(0); loadB(0);

    for (int t = 0; t < ntile; t++) {
        // commit prefetched regs to LDS
        #pragma unroll
        for (int r = 0; r < AR; r++) {
            int m = a_m + 32 * r;
            As[a_k4 + 0][m] = ra[r].x;
            As[a_k4 + 1][m] = ra[r].y;
            As[a_k4 + 2][m] = ra[r].z;
            As[a_k4 + 3][m] = ra[r].w;
        }
        #pragma unroll
        for (int r = 0; r < 2; r++) {
            int k4 = b1_k + 16 * r;
            Bs[k4 + 0][b1_n] = rb[r].x;
            Bs[k4 + 1][b1_n] = rb[r].y;
            Bs[k4 + 2][b1_n] = rb[r].z;
            Bs[k4 + 3][b1_n] = rb[r].w;
        }
        __syncthreads();

        if (t + 1 < ntile) { loadA((t + 1) * 32); loadB((t + 1) * 32); }

        #pragma unroll 8
        for (int kk = 0; kk < 32; kk++) {
            float4 b = *(float4*)&Bs[kk][n0];
            float a[MR];
            #pragma unroll
            for (int q = 0; q < MR / 4; q++) {
                float4 av = *(float4*)&As[kk][m0 + q * 4];
                a[q*4 + 0] = av.x; a[q*4 + 1] = av.y;
                a[q*4 + 2] = av.z; a[q*4 + 3] = av.w;
            }
            #pragma unroll
            for (int i = 0; i < MR; i++) {
                acc[i][0] += a[i] * b.x;
                acc[i][1] += a[i] * b.y;
                acc[i][2] += a[i] * b.z;
                acc[i][3] += a[i] * b.w;
            }
        }
        __syncthreads();
    }

    int col = bn + n0;
    if (col < N) {
        float4 bv = {0.f, 0.f, 0.f, 0.f};
        if (bias) bv = *(const float4*)(bias + col);
        #pragma unroll
        for (int i = 0; i < MR; i++) {
            int row = bm + m0 + i;
            if (row < M) {
                float4 o;
                o.x = acc[i][0] + bv.x;
                o.y = acc[i][1] + bv.y;
                o.z = acc[i][2] + bv.z;
                o.w = acc[i][3] + bv.w;
                if (ACT == 1) {
                    o.x = fmaxf(o.x, 0.f); o.y = fmaxf(o.y, 0.f);
                    o.z = fmaxf(o.z, 0.f); o.w = fmaxf(o.w, 0.f);
                }
                *(float4*)(C + (size_t)row * ldc + col) = o;
            }
        }
    }
}

// ---------------------------------------------------------------- bf16 MFMA multi-segment GEMM
typedef __attribute__((ext_vector_type(8))) short bfrag;
typedef __attribute__((ext_vector_type(4))) float ffrag;

struct BfSegs {
    const ushort* A[3];
    const ushort* B[3];
    int lda[3], ldb[3], Ks[3];
    int nseg, Ktot;
};

__device__ inline void bseg_find(const BfSegs& sg, int gk, int& s, int& loc) {
    s = 0; loc = gk;
    #pragma unroll
    for (int t = 0; t < 2; t++) {
        if (s + 1 < sg.nseg && loc >= sg.Ks[s]) { loc -= sg.Ks[s]; s++; }
    }
}

// ACT: 0 none, 1 relu, 2 sigmoid. WF32: write f32 C. WBF: write bf16 Cb.
template<int ACT, int WF32, int WBF>
__global__ __launch_bounds__(256) void mfma_seg(
    float* __restrict__ C, ushort* __restrict__ Cb, const BfSegs sg,
    const float* __restrict__ bias, int M, int N, int ldc, int nbx)
{
    __shared__ __align__(16) ushort Als[8192];  // [mt(8)][kt(2)][lane(64)][8]
    __shared__ __align__(16) ushort Bls[4096];  // [nt(4)][kt(2)][lane(64)][8]

    int tot = nbx * ((M + 127) >> 7);
    int chunk = (tot + 7) >> 3;
    int v = (int)(blockIdx.x & 7) * chunk + (int)(blockIdx.x >> 3);
    if (v >= tot) return;
    int by = v / nbx, bx = v - by * nbx;
    const int bm = by * 128, bn = bx * 64;

    const int tid  = threadIdx.x;
    const int lane = tid & 63;
    const int w    = tid >> 6;
    const int wm   = (w & 1) * 4;
    const int wn   = (w >> 1) * 2;

    ffrag acc[4][2];
    #pragma unroll
    for (int i = 0; i < 4; i++)
        #pragma unroll
        for (int j = 0; j < 2; j++) acc[i][j] = (ffrag){0.f, 0.f, 0.f, 0.f};

    const int Ktot = sg.Ktot;
    const int nkt = (Ktot + 63) >> 6;

    // precompute staging coords
    int a_m[4], a_kq[4], a_wc[4];
    #pragma unroll
    for (int i = 0; i < 4; i++) {
        int c = i * 256 + tid;
        a_m[i] = c & 127; a_kq[i] = c >> 7;
        a_wc[i] = ((a_m[i] >> 4) * 2 + (a_kq[i] >> 2)) * 64 + (a_kq[i] & 3) * 16 + (a_m[i] & 15);
    }
    int b_n[2], b_kq[2], b_wc[2];
    #pragma unroll
    for (int i = 0; i < 2; i++) {
        int c = i * 256 + tid;
        b_n[i] = c & 63; b_kq[i] = c >> 6;
        b_wc[i] = ((b_n[i] >> 4) * 2 + (b_kq[i] >> 2)) * 64 + (b_kq[i] & 3) * 16 + (b_n[i] & 15);
    }

    uint4 ra[4], rb[2];
    auto loadA = [&](int k0) {
        #pragma unroll
        for (int i = 0; i < 4; i++) {
            int gk = k0 + a_kq[i] * 8;
            int row = bm + a_m[i];
            uint4 vv = {0u, 0u, 0u, 0u};
            if (gk < Ktot && row < M) {
                int s, loc; bseg_find(sg, gk, s, loc);
                vv = *(const uint4*)(sg.A[s] + (size_t)row * sg.lda[s] + loc);
            }
            ra[i] = vv;
        }
    };
    auto loadB = [&](int k0) {
        #pragma unroll
        for (int i = 0; i < 2; i++) {
            int gk = k0 + b_kq[i] * 8;
            int gn = bn + b_n[i];
            uint4 vv = {0u, 0u, 0u, 0u};
            if (gk < Ktot && gn < N) {
                int s, loc; bseg_find(sg, gk, s, loc);
                vv = *(const uint4*)(sg.B[s] + (size_t)gn * sg.ldb[s] + loc);
            }
            rb[i] = vv;
        }
    };

    loadA(0); loadB(0);

    for (int t = 0; t < nkt; t++) {
        #pragma unroll
        for (int i = 0; i < 4; i++) *(uint4*)(&Als[a_wc[i] * 8]) = ra[i];
        #pragma unroll
        for (int i = 0; i < 2; i++) *(uint4*)(&Bls[b_wc[i] * 8]) = rb[i];
        __syncthreads();

        if (t + 1 < nkt) { loadA((t + 1) << 6); loadB((t + 1) << 6); }

        #pragma unroll
        for (int kt = 0; kt < 2; kt++) {
            bfrag af[4], bf[2];
            #pragma unroll
            for (int i = 0; i < 4; i++)
                af[i] = *(const bfrag*)(&Als[(((wm + i) * 2 + kt) * 64 + lane) * 8]);
            #pragma unroll
            for (int j = 0; j < 2; j++)
                bf[j] = *(const bfrag*)(&Bls[(((wn + j) * 2 + kt) * 64 + lane) * 8]);
            #pragma unroll
            for (int i = 0; i < 4; i++)
                #pragma unroll
                for (int j = 0; j < 2; j++)
                    acc[i][j] = __builtin_amdgcn_mfma_f32_16x16x32_bf16(af[i], bf[j], acc[i][j], 0, 0, 0);
        }
        __syncthreads();
    }

    const int rbase = (lane >> 4) * 4;
    const int cl = lane & 15;
    #pragma unroll
    for (int j = 0; j < 2; j++) {
        int col = bn + (wn + j) * 16 + cl;
        if (col >= N) continue;
        float bv = bias ? bias[col] : 0.f;
        #pragma unroll
        for (int i = 0; i < 4; i++) {
            int mrow = bm + (wm + i) * 16 + rbase;
            #pragma unroll
            for (int r = 0; r < 4; r++) {
                int row = mrow + r;
                if (row < M) {
                    float o = acc[i][j][r] + bv;
                    if (ACT == 1) o = fmaxf(o, 0.f);
                    else if (ACT == 2) o = 1.f / (1.f + expf(-o));
                    if (WF32) C[(size_t)row * ldc + col] = o;
                    if (WBF)  Cb[(size_t)row * ldc + col] = f2bf(o);
                }
            }
        }
    }
}

// ---------------------------------------------------------------- CSR build

__global__ void count_dst(const int* __restrict__ di, int* __restrict__ cnt, int E) {
    int e = blockIdx.x * 256 + threadIdx.x;
    if (e < E) atomicAdd(&cnt[di[e]], 1);
}

__global__ __launch_bounds__(1024) void scan_rows(
    const int* __restrict__ cnt, int* __restrict__ row_start, int* __restrict__ cursor,
    float* __restrict__ degf, float* __restrict__ invd)
{
    __shared__ int part[1024];
    const int CH = (NUM_E + 1023) / 1024;
    int t = threadIdx.x;
    int base = t * CH;
    int local[32];
    int s = 0;
    for (int j = 0; j < CH; j++) {
        int idx = base + j;
        int c = (idx < NUM_E) ? cnt[idx] : 0;
        local[j] = s; s += c;
    }
    part[t] = s;
    __syncthreads();
    for (int off = 1; off < 1024; off <<= 1) {
        int vv = (t >= off) ? part[t - off] : 0;
        __syncthreads();
        part[t] += vv;
        __syncthreads();
    }
    int pre = (t == 0) ? 0 : part[t - 1];
    for (int j = 0; j < CH; j++) {
        int idx = base + j;
        if (idx < NUM_E) {
            int rs = pre + local[j];
            row_start[idx] = rs;
            cursor[idx] = rs;
            int c = cnt[idx];
            degf[idx] = (float)c;
            invd[idx] = 1.f / fmaxf((float)c, 1.f);
        }
    }
    if (t == 1023) row_start[NUM_E] = part[1023];
}

__global__ void build_perm(const int* __restrict__ si, const int* __restrict__ di,
                           const int* __restrict__ ei, int* __restrict__ cursor,
                           int* __restrict__ ssrc, int* __restrict__ setype, int E)
{
    int e = blockIdx.x * 256 + threadIdx.x;
    if (e >= E) return;
    int pos = atomicAdd(&cursor[di[e]], 1);
    ssrc[pos]   = si[e];
    setype[pos] = ei[e];
}

// ---------------------------------------------------------------- gathers (bf16 in/out)

// bh[v,:] = bf16( l2norm( (sum bprev[ssrc[e],:]) * inv_v ) )
__global__ __launch_bounds__(256) void seg_gather_norm_bf(
    ushort* __restrict__ bh, const ushort* __restrict__ bprev,
    const int* __restrict__ ssrc, const int* __restrict__ row_start,
    const float* __restrict__ invd)
{
    int v = blockIdx.x * 4 + (threadIdx.x >> 6);
    int lane = threadIdx.x & 63;
    if (v >= NUM_E) return;
    int s0 = row_start[v], s1 = row_start[v + 1];
    bool act = lane < 50;
    float4 acc = {0.f, 0.f, 0.f, 0.f};
    int j = s0;
    for (; j + 1 < s1; j += 2) {
        int sa = ssrc[j], sb = ssrc[j + 1];
        if (act) {
            float4 xa = bf4_to_f4(*(const ushort4*)(bprev + (long)sa * H_DIM + lane * 4));
            float4 xb = bf4_to_f4(*(const ushort4*)(bprev + (long)sb * H_DIM + lane * 4));
            acc.x += xa.x + xb.x; acc.y += xa.y + xb.y;
            acc.z += xa.z + xb.z; acc.w += xa.w + xb.w;
        }
    }
    if (j < s1) {
        int sa = ssrc[j];
        if (act) {
            float4 xa = bf4_to_f4(*(const ushort4*)(bprev + (long)sa * H_DIM + lane * 4));
            acc.x += xa.x; acc.y += xa.y; acc.z += xa.z; acc.w += xa.w;
        }
    }
    float iv = invd[v];
    acc.x *= iv; acc.y *= iv; acc.z *= iv; acc.w *= iv;
    float ss = act ? (acc.x*acc.x + acc.y*acc.y + acc.z*acc.z + acc.w*acc.w) : 0.f;
    ss = wave_sum64(ss);
    float r = 1.f / fmaxf(sqrtf(ss), 1e-12f);
    if (act) {
        ushort4 ob = {f2bf(acc.x * r), f2bf(acc.y * r), f2bf(acc.z * r), f2bf(acc.w * r)};
        *(ushort4*)(bh + (long)v * H_DIM + lane * 4) = ob;
    }
}

// btmp[v,:] = bf16( (sum bh[ssrc[e],:] + brel[setype[e],:]) * inv_v )
__global__ __launch_bounds__(256) void seg_gather_layer_bf(
    ushort* __restrict__ btmp, const ushort* __restrict__ bh, const ushort* __restrict__ brel,
    const int* __restrict__ ssrc, const int* __restrict__ setype,
    const int* __restrict__ row_start, const float* __restrict__ invd)
{
    int v = blockIdx.x * 4 + (threadIdx.x >> 6);
    int lane = threadIdx.x & 63;
    if (v >= NUM_E) return;
    int s0 = row_start[v], s1 = row_start[v + 1];
    bool act = lane < 50;
    float4 acc = {0.f, 0.f, 0.f, 0.f};
    for (int j = s0; j < s1; j++) {
        int s = ssrc[j];
        int t = setype[j];
        if (act) {
            float4 x = bf4_to_f4(*(const ushort4*)(bh   + (long)s * H_DIM + lane * 4));
            float4 y = bf4_to_f4(*(const ushort4*)(brel + (long)t * H_DIM + lane * 4));
            acc.x += x.x + y.x; acc.y += x.y + y.y;
            acc.z += x.z + y.z; acc.w += x.w + y.w;
        }
    }
    float iv = invd[v];
    if (act) {
        ushort4 ob = {f2bf(acc.x * iv), f2bf(acc.y * iv), f2bf(acc.z * iv), f2bf(acc.w * iv)};
        *(ushort4*)(btmp + (long)v * H_DIM + lane * 4) = ob;
    }
}

// ---------------------------------------------------------------- row kernels

__global__ __launch_bounds__(256) void l2norm_rows4(
    float* __restrict__ out, ushort* __restrict__ bout,
    const float* __restrict__ in, int nrows)
{
    int v = blockIdx.x * 4 + (threadIdx.x >> 6);
    int lane = threadIdx.x & 63;
    if (v >= nrows) return;
    bool act = lane < 50;
    float4 x = {0.f, 0.f, 0.f, 0.f};
    if (act) x = *(const float4*)(in + (long)v * H_DIM + lane * 4);
    float ss = x.x*x.x + x.y*x.y + x.z*x.z + x.w*x.w;
    ss = wave_sum64(ss);
    float r = 1.f / fmaxf(sqrtf(ss), 1e-12f);
    if (act) {
        long base = (long)v * H_DIM + lane * 4;
        float4 o = {x.x * r, x.y * r, x.z * r, x.w * r};
        *(float4*)(out + base) = o;
        if (bout) {
            ushort4 ob = {f2bf(o.x), f2bf(o.y), f2bf(o.z), f2bf(o.w)};
            *(ushort4*)(bout + base) = ob;
        }
    }
}

// in-place bf16 row l2norm
__global__ __launch_bounds__(256) void l2norm_bf4(ushort* __restrict__ b, int nrows)
{
    int v = blockIdx.x * 4 + (threadIdx.x >> 6);
    int lane = threadIdx.x & 63;
    if (v >= nrows) return;
    bool act = lane < 50;
    float4 x = {0.f, 0.f, 0.f, 0.f};
    long base = (long)v * H_DIM + lane * 4;
    if (act) x = bf4_to_f4(*(const ushort4*)(b + base));
    float ss = x.x*x.x + x.y*x.y + x.z*x.z + x.w*x.w;
    ss = wave_sum64(ss);
    float r = 1.f / fmaxf(sqrtf(ss), 1e-12f);
    if (act) {
        ushort4 ob = {f2bf(x.x * r), f2bf(x.y * r), f2bf(x.z * r), f2bf(x.w * r)};
        *(ushort4*)(b + base) = ob;
    }
}

__global__ void tenc_ent(ushort* __restrict__ bte, const float* __restrict__ deg,
                         const float* __restrict__ af, const float* __restrict__ ap,
                         const float* __restrict__ cf, const float* __restrict__ cp,
                         float tcnt, int M)
{
    int idx = blockIdx.x * 256 + threadIdx.x;
    if (idx >= M * TD_DIM) return;
    int v = idx / TD_DIM, j = idx % TD_DIM;
    float t = (deg[v] > 0.f) ? tcnt : 100.0f;
    float val;
    if (j < HD_DIM) val = tanhf((t + 1.f) * af[j] + ap[j]);
    else            val = cosf(t * cf[j - HD_DIM] + cp[j - HD_DIM]);
    bte[idx] = f2bf(val);
}

// prev = l2norm((1-z)*tanh(iN + r*hN) + z*prev); rz ld 400 (sigmoid applied)
__global__ __launch_bounds__(256) void gru_fused(
    float* __restrict__ prev, ushort* __restrict__ bprev, const float* __restrict__ rz,
    const float* __restrict__ iN, const float* __restrict__ hN)
{
    int v = blockIdx.x * 4 + (threadIdx.x >> 6);
    int lane = threadIdx.x & 63;
    if (v >= NUM_E) return;
    bool act = lane < 50;
    long b200 = (long)v * H_DIM + lane * 4;
    long b400 = (long)v * 400 + lane * 4;
    float4 o = {0.f, 0.f, 0.f, 0.f};
    if (act) {
        float4 r4 = *(const float4*)(rz + b400);
        float4 z4 = *(const float4*)(rz + b400 + 200);
        float4 n4 = *(const float4*)(iN + b200);
        float4 g4 = *(const float4*)(hN + b200);
        float4 p4 = *(const float4*)(prev + b200);
        float ngx = tanhf(n4.x + r4.x * g4.x);
        float ngy = tanhf(n4.y + r4.y * g4.y);
        float ngz = tanhf(n4.z + r4.z * g4.z);
        float ngw = tanhf(n4.w + r4.w * g4.w);
        o.x = (1.f - z4.x) * ngx + z4.x * p4.x;
        o.y = (1.f - z4.y) * ngy + z4.y * p4.y;
        o.z = (1.f - z4.z) * ngz + z4.z * p4.z;
        o.w = (1.f - z4.w) * ngw + z4.w * p4.w;
    }
    float ss = o.x*o.x + o.y*o.y + o.z*o.z + o.w*o.w;
    ss = wave_sum64(ss);
    float r = 1.f / fmaxf(sqrtf(ss), 1e-12f);
    if (act) {
        float4 wv = {o.x * r, o.y * r, o.z * r, o.w * r};
        *(float4*)(prev + b200) = wv;
        ushort4 ob = {f2bf(wv.x), f2bf(wv.y), f2bf(wv.z), f2bf(wv.w)};
        *(ushort4*)(bprev + b200) = ob;
    }
}

// ---------------------------------------------------------------- batch head

__global__ void gather_qs_qr3(float* __restrict__ qs3, float* __restrict__ qr3,
                              const float* __restrict__ out, const float* __restrict__ reln,
                              const int* __restrict__ data)
{
    long i = (long)blockIdx.x * 256 + threadIdx.x;
    if (i >= (long)BATCH * H_DIM) return;
    int b = (int)(i / H_DIM), j = (int)(i % H_DIM);
    float vs = out[(long)data[b * 4 + 0] * H_DIM + j];
    float vr = reln[(long)data[b * 4 + 1] * H_DIM + j];
    const long S = (long)BATCH * H_DIM;
    qs3[i] = vs; qs3[i + S] = vs; qs3[i + 2*S] = vs;
    qr3[i] = vr; qr3[i + S] = vr; qr3[i + 2*S] = vr;
}

__global__ __launch_bounds__(64) void semb_kernel(
    float* __restrict__ semb, const float* __restrict__ out,
    const int* __restrict__ his_idx, const int* __restrict__ his_len)
{
    int b = blockIdx.x, k = blockIdx.y;
    int lane = threadIdx.x;
    int ln = his_len[b * 3 + k];
    if (ln > L_HIST) ln = L_HIST;
    float vals[4] = {0.f, 0.f, 0.f, 0.f};
    for (int l = 0; l < ln; l++) {
        int idx = his_idx[((long)b * 3 + k) * L_HIST + l];
        #pragma unroll
        for (int t = 0; t < 4; t++) {
            int j = lane + t * 64;
            if (j < H_DIM) vals[t] += out[(long)idx * H_DIM + j];
        }
    }
    float scale = 1.f / fmaxf((float)ln, 1.f);
    float ss = 0.f;
    #pragma unroll
    for (int t = 0; t < 4; t++) { vals[t] *= scale; ss += vals[t] * vals[t]; }
    ss = wave_sum64(ss);
    float r = 1.f / fmaxf(sqrtf(ss), 1e-12f);
    #pragma unroll
    for (int t = 0; t < 4; t++) {
        int j = lane + t * 64;
        if (j < H_DIM) semb[((long)k * BATCH + b) * H_DIM + j] = vals[t] * r;
    }
}

__global__ void tenc_batch(float* __restrict__ teb, const int* __restrict__ his_len,
                           const float* __restrict__ af, const float* __restrict__ ap,
                           const float* __restrict__ cf, const float* __restrict__ cp)
{
    int idx = blockIdx.x * 256 + threadIdx.x;
    if (idx >= 3 * BATCH * TD_DIM) return;
    int k = idx / (BATCH * TD_DIM);
    int rem = idx - k * (BATCH * TD_DIM);
    int b = rem / TD_DIM, j = rem % TD_DIM;
    int ln = his_len[b * 3 + k];
    float t = (ln > 0) ? (float)(2 - k) : 100.0f;
    float val;
    if (j < HD_DIM) val = tanhf((t + 1.f) * af[j] + ap[j]);
    else            val = cosf(t * cf[j - HD_DIM] + cp[j - HD_DIM]);
    teb[idx] = val;
}

__global__ __launch_bounds__(256) void att_logits_rows(
    float* __restrict__ atts, const float* __restrict__ a,
    const float* __restrict__ Wc_w, const float* __restrict__ Wc_b)
{
    int row = blockIdx.x * 4 + (threadIdx.x >> 6);
    int lane = threadIdx.x & 63;
    if (row >= 3 * BATCH) return;
    int k = row >> 9;
    int b = row & 511;
    float s = 0.f;
    for (int j = lane; j < H_DIM; j += 64) s += a[(long)row * H_DIM + j] * Wc_w[j];
    s = wave_sum64(s);
    if (lane == 0) atts[b * 3 + k] = s + Wc_b[0];
}

__global__ void softmax_out2(float* __restrict__ out2, const float* __restrict__ atts,
                             const float* __restrict__ semb)
{
    long i = (long)blockIdx.x * 256 + threadIdx.x;
    if (i >= (long)BATCH * H_DIM) return;
    int b = (int)(i / H_DIM), j = (int)(i % H_DIM);
    float l0 = atts[b * 3 + 0], l1 = atts[b * 3 + 1], l2 = atts[b * 3 + 2];
    float m = fmaxf(l0, fmaxf(l1, l2));
    float e0 = expf(l0 - m), e1 = expf(l1 - m), e2 = expf(l2 - m);
    float s = e0 + e1 + e2;
    float v = (e0 * semb[((long)0 * BATCH + b) * H_DIM + j] +
               e1 * semb[((long)1 * BATCH + b) * H_DIM + j] +
               e2 * semb[((long)2 * BATCH + b) * H_DIM + j]) / s;
    out2[i] = v;
}

// ---------------------------------------------------------------- launch

extern "C" void kernel_launch(void* const* d_in, const int* in_sizes, int n_in,
                              void* d_out, int out_size, void* d_ws, size_t ws_size,
                              hipStream_t stream)
{
    (void)in_sizes; (void)n_in; (void)out_size; (void)ws_size;

    const int*   src     = (const int*)d_in[0];
    const int*   dst     = (const int*)d_in[1];
    const int*   etype   = (const int*)d_in[2];
    const int*   data    = (const int*)d_in[3];
    const int*   his_idx = (const int*)d_in[4];
    const int*   his_len = (const int*)d_in[5];
    const float* ent     = (const float*)d_in[6];
    const float* loop_w  = (const float*)d_in[7];
    const float* rel     = (const float*)d_in[8];
    const float* af      = (const float*)d_in[9];
    const float* ap      = (const float*)d_in[10];
    const float* cf      = (const float*)d_in[11];
    const float* cp      = (const float*)d_in[12];
    const float* Wn      = (const float*)d_in[13];
    const float* Ws      = (const float*)d_in[14];
    const float* W_ih    = (const float*)d_in[15];
    const float* W_hh    = (const float*)d_in[16];
    const float* b_ih    = (const float*)d_in[17];
    const float* b_hh    = (const float*)d_in[18];
    const float* Wb_w    = (const float*)d_in[19];
    const float* Wb_b    = (const float*)d_in[20];
    const float* Wc_w    = (const float*)d_in[21];
    const float* Wc_b    = (const float*)d_in[22];
    const float* Wd_w    = (const float*)d_in[23];
    const float* Wd_b    = (const float*)d_in[24];
    float* out_p = (float*)d_out;

    float* wp = (float*)d_ws;
    size_t off = 0;
    auto alloc = [&](size_t n) {
        size_t n4 = (n + 3) & ~(size_t)3;
        float* p = wp + off; off += n4; return p;
    };
    const long nE200 = (long)NUM_E * H_DIM;
    float* prev   = alloc(nE200);
    float* h1     = alloc(nE200);                       // GRU iN (f32)
    float* tmp    = alloc(nE200);                       // init gemm out; GRU hN (f32)
    float* rz     = out_p;                              // (NUM_E x 400) scratch in d_out
    ushort* bh0   = (ushort*)alloc(nE200 / 2);
    ushort* bh1   = (ushort*)alloc(nE200 / 2);
    ushort* btmp  = (ushort*)alloc(nE200 / 2);          // gather target / bent for init
    ushort* bprev = (ushort*)alloc(nE200 / 2);
    ushort* bte   = (ushort*)alloc((size_t)NUM_E * TD_DIM / 2);
    ushort* brel  = (ushort*)alloc(400 * H_DIM / 2);
    ushort* bW_ih = (ushort*)alloc(600 * 248 / 2);
    ushort* bW_hh = (ushort*)alloc(600 * 200 / 2);
    ushort* bWn_t = (ushort*)alloc(2 * 200 * 200 / 2);
    ushort* bWs_t = (ushort*)alloc(2 * 200 * 200 / 2);
    ushort* bLp_t = (ushort*)alloc(200 * 200 / 2);
    float* degf   = alloc(NUM_E);
    float* invd   = alloc(NUM_E);
    float* reln   = alloc(400 * H_DIM);
    float* bsum   = alloc(1024);
    float* qs3    = alloc(3 * BATCH * H_DIM);
    float* qr3    = alloc(3 * BATCH * H_DIM);
    float* semb   = alloc(3 * BATCH * H_DIM);
    float* teb    = alloc(3 * BATCH * TD_DIM);
    float* abuf   = alloc(3 * BATCH * H_DIM);
    float* atts   = alloc(2048);
    float* out2   = alloc(BATCH * H_DIM);
    float* qbuf   = alloc(BATCH * H_DIM);
    int* cnt       = (int*)alloc(NUM_E);
    int* row_start = (int*)alloc(NUM_E + 4);
    int* cursor    = (int*)alloc(NUM_E);
    int* ssrc      = (int*)alloc(E_EDGES);
    int* setype    = (int*)alloc(E_EDGES);

    auto nblk = [](long n) { return (unsigned)((n + 255) / 256); };

    auto bseg1 = [](const ushort* A, int la, const ushort* B, int lb, int K) {
        BfSegs s{}; s.A[0]=A; s.lda[0]=la; s.B[0]=B; s.ldb[0]=lb; s.Ks[0]=K;
        s.nseg=1; s.Ktot=K; return s;
    };
    auto bseg2 = [](const ushort* A0, int la0, const ushort* B0, int lb0, int K0,
                    const ushort* A1, int la1, const ushort* B1, int lb1, int K1) {
        BfSegs s{}; s.A[0]=A0; s.lda[0]=la0; s.B[0]=B0; s.ldb[0]=lb0; s.Ks[0]=K0;
        s.A[1]=A1; s.lda[1]=la1; s.B[1]=B1; s.ldb[1]=lb1; s.Ks[1]=K1;
        s.nseg=2; s.Ktot=K0+K1; return s;
    };
    auto bseg3 = [](const ushort* A0, int la0, const ushort* B0, int lb0, int K0,
                    const ushort* A1, int la1, const ushort* B1, int lb1, int K1,
                    const ushort* A2, int la2, const ushort* B2, int lb2, int K2) {
        BfSegs s{}; s.A[0]=A0; s.lda[0]=la0; s.B[0]=B0; s.ldb[0]=lb0; s.Ks[0]=K0;
        s.A[1]=A1; s.lda[1]=la1; s.B[1]=B1; s.ldb[1]=lb1; s.Ks[1]=K1;
        s.A[2]=A2; s.lda[2]=la2; s.B[2]=B2; s.ldb[2]=lb2; s.Ks[2]=K2;
        s.nseg=3; s.Ktot=K0+K1+K2; return s;
    };

    // MODE: 0 = f32-out no act; 1 = relu bf16-only; 2 = sigmoid f32-only
    auto mfma = [&](int MODE, float* C, ushort* Cb, const BfSegs& sg,
                    const float* bias, int M, int N, int ldc) {
        int nbx = (N + 63) >> 6;
        int tot = nbx * ((M + 127) >> 7);
        unsigned grid = (unsigned)(((tot + 7) >> 3) << 3);
        if (MODE == 0)      mfma_seg<0,1,0><<<grid, 256, 0, stream>>>(C, Cb, sg, bias, M, N, ldc, nbx);
        else if (MODE == 1) mfma_seg<1,0,1><<<grid, 256, 0, stream>>>(C, Cb, sg, bias, M, N, ldc, nbx);
        else                mfma_seg<2,1,0><<<grid, 256, 0, stream>>>(C, Cb, sg, bias, M, N, ldc, nbx);
    };

    auto seg1 = [](const float* A, int la, const float* B, int lb, int K) {
        Segs s{}; s.A[0]=A; s.lda[0]=la; s.B[0]=B; s.ldb[0]=lb; s.Ks[0]=K;
        s.nseg=1; s.Ktot=K; return s;
    };
    auto seg3 = [](const float* A0, int la0, const float* B0, int lb0, int K0,
                   const float* A1, int la1, const float* B1, int lb1, int K1,
                   const float* A2, int la2, const float* B2, int lb2, int K2) {
        Segs s{}; s.A[0]=A0; s.lda[0]=la0; s.B[0]=B0; s.ldb[0]=lb0; s.Ks[0]=K0;
        s.A[1]=A1; s.lda[1]=la1; s.B[1]=B1; s.ldb[1]=lb1; s.Ks[1]=K1;
        s.A[2]=A2; s.lda[2]=la2; s.B[2]=B2; s.ldb[2]=lb2; s.Ks[2]=K2;
        s.nseg=3; s.Ktot=K0+K1+K2; return s;
    };
    auto seg4 = [](const float* A0, int la0, const float* B0, int lb0, int K0,
                   const float* A1, int la1, const float* B1, int lb1, int K1,
                   const float* A2, int la2, const float* B2, int lb2, int K2,
                   const float* A3, int la3, const float* B3, int lb3, int K3) {
        Segs s{}; s.A[0]=A0; s.lda[0]=la0; s.B[0]=B0; s.ldb[0]=lb0; s.Ks[0]=K0;
        s.A[1]=A1; s.lda[1]=la1; s.B[1]=B1; s.ldb[1]=lb1; s.Ks[1]=K1;
        s.A[2]=A2; s.lda[2]=la2; s.B[2]=B2; s.ldb[2]=lb2; s.Ks[2]=K2;
        s.A[3]=A3; s.lda[3]=la3; s.B[3]=B3; s.ldb[3]=lb3; s.Ks[3]=K3;
        s.nseg=4; s.Ktot=K0+K1+K2+K3; return s;
    };
    auto fgemm = [&](int ACT, int BM, int order, float* C, const Segs& sg,
                     const float* bias, int M, int N, int ldc) {
        int nbx = (N + 63) >> 6;
        int nby = (M + BM - 1) / BM;
        unsigned grid = (unsigned)((((nbx * nby) + 7) >> 3) << 3);
        if (BM == 128) {
            if (ACT == 0) sgemm_seg<0,128><<<grid, 256, 0, stream>>>(C, sg, bias, M, N, ldc, nbx, nby, order);
            else          sgemm_seg<1,128><<<grid, 256, 0, stream>>>(C, sg, bias, M, N, ldc, nbx, nby, order);
        } else {
            if (ACT == 0) sgemm_seg<0,64><<<grid, 256, 0, stream>>>(C, sg, bias, M, N, ldc, nbx, nby, order);
            else          sgemm_seg<1,64><<<grid, 256, 0, stream>>>(C, sg, bias, M, N, ldc, nbx, nby, order);
        }
    };

    const unsigned r4 = (NUM_E + 3) / 4;

    // ---- prelude ----
    l2norm_rows4<<<100, 256, 0, stream>>>(reln, brel, rel, 400);
    bias_sum<<<3, 256, 0, stream>>>(bsum, b_ih, b_hh);
    cvt_bf16_k<<<nblk(600L*248), 256, 0, stream>>>(bW_ih, W_ih, 600L*248);
    cvt_bf16_k<<<nblk(600L*200), 256, 0, stream>>>(bW_hh, W_hh, 600L*200);
    tcvt_bf16_k<<<nblk(40000), 256, 0, stream>>>(bLp_t, loop_w, 200, 200);
    tcvt_bf16_k<<<nblk(40000), 256, 0, stream>>>(bWn_t,          Wn,          200, 200);
    tcvt_bf16_k<<<nblk(40000), 256, 0, stream>>>(bWn_t + 40000,  Wn + 40000,  200, 200);
    tcvt_bf16_k<<<nblk(40000), 256, 0, stream>>>(bWs_t,          Ws,          200, 200);
    tcvt_bf16_k<<<nblk(40000), 256, 0, stream>>>(bWs_t + 40000,  Ws + 40000,  200, 200);

    // prev = l2norm(ent @ loop_weight)
    cvt_bf16_k<<<nblk(nE200), 256, 0, stream>>>(btmp, ent, nE200);
    mfma(0, tmp, nullptr, bseg1(btmp, H_DIM, bLp_t, H_DIM, H_DIM), nullptr, NUM_E, H_DIM, H_DIM);
    l2norm_rows4<<<r4, 256, 0, stream>>>(prev, bprev, tmp, NUM_E);

    for (int i = 0; i < N_HIST; i++) {
        const int* si = src   + (long)i * E_EDGES;
        const int* di = dst   + (long)i * E_EDGES;
        const int* ei = etype + (long)i * E_EDGES;
        float tcnt = (float)(N_HIST - 1 - i);

        // CSR build
        fill_i32<<<nblk(NUM_E), 256, 0, stream>>>(cnt, NUM_E, 0);
        count_dst<<<nblk(E_EDGES), 256, 0, stream>>>(di, cnt, E_EDGES);
        scan_rows<<<1, 1024, 0, stream>>>(cnt, row_start, cursor, degf, invd);
        build_perm<<<nblk(E_EDGES), 256, 0, stream>>>(si, di, ei, cursor, ssrc, setype, E_EDGES);

        // bh0 = bf16(l2norm(segsum(bprev)*inv))
        seg_gather_norm_bf<<<r4, 256, 0, stream>>>(bh0, bprev, ssrc, row_start, invd);
        tenc_ent<<<nblk((long)NUM_E * TD_DIM), 256, 0, stream>>>(bte, degf, af, ap, cf, cp, tcnt, NUM_E);

        // layer 0: bh1 = relu([btmp|bh0] @ [Wn0;Ws0])   (bf16-only output)
        seg_gather_layer_bf<<<r4, 256, 0, stream>>>(btmp, bh0, brel, ssrc, setype, row_start, invd);
        mfma(1, nullptr, bh1,
             bseg2(btmp, H_DIM, bWn_t,         H_DIM, H_DIM,
                   bh0,  H_DIM, bWs_t,         H_DIM, H_DIM),
             nullptr, NUM_E, H_DIM, H_DIM);
        // layer 1: bh0 = relu([btmp|bh1] @ [Wn1;Ws1])
        seg_gather_layer_bf<<<r4, 256, 0, stream>>>(btmp, bh1, brel, ssrc, setype, row_start, invd);
        mfma(1, nullptr, bh0,
             bseg2(btmp, H_DIM, bWn_t + 40000, H_DIM, H_DIM,
                   bh1,  H_DIM, bWs_t + 40000, H_DIM, H_DIM),
             nullptr, NUM_E, H_DIM, H_DIM);
        // h = l2norm(h) in place on bf16
        l2norm_bf4<<<r4, 256, 0, stream>>>(bh0, NUM_E);

        // GRU: rz (N=400, sigmoid, f32 in d_out scratch), iN -> h1, hN -> tmp
        mfma(2, rz, nullptr,
             bseg3(bh0,   H_DIM,  bW_ih,       248, H_DIM,
                   bte,   TD_DIM, bW_ih + 200, 248, TD_DIM,
                   bprev, H_DIM,  bW_hh,       200, H_DIM),
             bsum, NUM_E, 400, 400);
        mfma(0, h1, nullptr,
             bseg2(bh0, H_DIM,  bW_ih + 400*248,       248, H_DIM,
                   bte, TD_DIM, bW_ih + 400*248 + 200, 248, TD_DIM),
             b_ih + 400, NUM_E, H_DIM, H_DIM);
        mfma(0, tmp, nullptr,
             bseg1(bprev, H_DIM, bW_hh + 400*200, 200, H_DIM),
             b_hh + 400, NUM_E, H_DIM, H_DIM);

        gru_fused<<<r4, 256, 0, stream>>>(prev, bprev, rz, h1, tmp);
    }

    // ---- batch head (f32) ----
    gather_qs_qr3<<<nblk((long)BATCH * H_DIM), 256, 0, stream>>>(qs3, qr3, prev, reln, data);
    semb_kernel<<<dim3(BATCH, 3), 64, 0, stream>>>(semb, prev, his_idx, his_len);
    tenc_batch<<<nblk(3L * BATCH * TD_DIM), 256, 0, stream>>>(teb, his_len, af, ap, cf, cp);

    fgemm(1, 64, 0, abuf,
          seg4(qs3, H_DIM,  Wb_w,       648, H_DIM,
               qr3, H_DIM,  Wb_w + 200, 648, H_DIM,
               semb, H_DIM, Wb_w + 400, 648, H_DIM,
               teb, TD_DIM, Wb_w + 600, 648, TD_DIM),
          Wb_b, 3 * BATCH, H_DIM, H_DIM);
    att_logits_rows<<<(3 * BATCH + 3) / 4, 256, 0, stream>>>(atts, abuf, Wc_w, Wc_b);
    softmax_out2<<<nblk((long)BATCH * H_DIM), 256, 0, stream>>>(out2, atts, semb);

    fgemm(1, 64, 0, qbuf,
          seg3(qs3, H_DIM,  Wd_w,       600, H_DIM,
               qr3, H_DIM,  Wd_w + 200, 600, H_DIM,
               out2, H_DIM, Wd_w + 400, 600, H_DIM),
          Wd_b, BATCH, H_DIM, H_DIM);

    // result = q @ prev^T -> (512, 20000), f32, B-reuse swizzle
    fgemm(0, 128, 1, out_p, seg1(qbuf, H_DIM, prev, H_DIM, H_DIM), nullptr,
          BATCH, NUM_E, NUM_E);
}

// Round 8
// 1364.565 us; speedup vs baseline: 7.7619x; 1.0693x over previous
//
#include <hip/hip_runtime.h>
#include <hip/hip_bf16.h>

#define NUM_E   20000
#define H_DIM   200
#define TD_DIM  48
#define HD_DIM  24
#define L_HIST  32
#define N_HIST  3
#define E_EDGES 200000
#define BATCH   512

// ---------------------------------------------------------------- utilities

__device__ inline float wave_sum64(float x) {
    #pragma unroll
    for (int m = 1; m < 64; m <<= 1) x += __shfl_xor(x, m);
    return x;
}

__device__ inline ushort f2bf(float f) {
    unsigned u = __float_as_uint(f);
    u += 0x7fffu + ((u >> 16) & 1u);
    return (ushort)(u >> 16);
}
__device__ inline float bf2f(ushort u) {
    return __uint_as_float(((unsigned)u) << 16);
}
__device__ inline float4 bf4_to_f4(ushort4 v) {
    return (float4){bf2f(v.x), bf2f(v.y), bf2f(v.z), bf2f(v.w)};
}

__global__ void fill_i32(int* __restrict__ p, long n, int v) {
    long i = (long)blockIdx.x * blockDim.x + threadIdx.x;
    if (i < n) p[i] = v;
}

__global__ void bias_sum(float* __restrict__ bsum, const float* __restrict__ b_ih,
                         const float* __restrict__ b_hh) {
    int j = blockIdx.x * 256 + threadIdx.x;
    if (j < 600) bsum[j] = b_ih[j] + b_hh[j];
}

__global__ void cvt_bf16_k(ushort* __restrict__ o, const float* __restrict__ in, long n) {
    long i = (long)blockIdx.x * 256 + threadIdx.x;
    if (i < n) o[i] = f2bf(in[i]);
}

// lo[i] = bf16(x[i] - f32(hi[i]))
__global__ void make_lo(ushort* __restrict__ lo, const float* __restrict__ x,
                        const ushort* __restrict__ hi, long n) {
    long i = (long)blockIdx.x * 256 + threadIdx.x;
    if (i < n) lo[i] = f2bf(x[i] - bf2f(hi[i]));
}

// in (R,C) row-major f32 -> o (C,R) row-major bf16
__global__ void tcvt_bf16_k(ushort* __restrict__ o, const float* __restrict__ in, int R, int C) {
    int i = blockIdx.x * 256 + threadIdx.x;
    if (i >= R * C) return;
    int r = i / C, c = i - r * C;
    o[(size_t)c * R + r] = f2bf(in[i]);
}

// ---------------------------------------------------------------- f32 split-K GEMM (B^T)
struct Segs {
    const float* A[4];
    const float* B[4];
    int lda[4], ldb[4], Ks[4];
    int nseg, Ktot;
};

__device__ inline void seg_find(const Segs& sg, int gk, int& s, int& loc) {
    s = 0; loc = gk;
    #pragma unroll
    for (int t = 0; t < 3; t++) {
        if (s + 1 < sg.nseg && loc >= sg.Ks[s]) { loc -= sg.Ks[s]; s++; }
    }
}

// Partial GEMM: P[kc][M][N] = A@B^T over k-chunk kc. BM=64, BN=64, BK=32.
__global__ __launch_bounds__(256) void sgemm_splitk(
    float* __restrict__ P, const Segs sg, int M, int N, int nbx, int nby,
    int KS, int tpc)
{
    __shared__ float As[32][68];
    __shared__ float Bs[32][68];

    int tot = nbx * nby;
    int tot_all = tot * KS;
    int chunk = (tot_all + 7) >> 3;
    int v = (int)(blockIdx.x & 7) * chunk + (int)(blockIdx.x >> 3);
    if (v >= tot_all) return;
    int kc = v / tot;
    int tile = v - kc * tot;
    int by = tile / nbx, bx = tile - by * nbx;
    const int bn = bx * 64;
    const int bm = by * 64;
    const int tid = threadIdx.x;
    const int m0 = (tid >> 4) * 4;
    const int n0 = (tid & 15) * 4;

    float acc[4][4];
    #pragma unroll
    for (int i = 0; i < 4; i++)
        #pragma unroll
        for (int j = 0; j < 4; j++) acc[i][j] = 0.f;

    const int Ktot = sg.Ktot;
    const int ntile = (Ktot + 31) / 32;
    const int kt0 = kc * tpc;
    const int kt1 = min(ntile, kt0 + tpc);

    const int a_m  = tid & 31;
    const int a_k4 = (tid >> 5) * 4;
    const int b1_n = tid & 63;
    const int b1_k = (tid >> 6) * 4;

    float4 ra[2], rb[2];
    auto loadA = [&](int k0) {
        int gk = k0 + a_k4;
        bool kin = gk < Ktot;
        int s = 0, loc = 0;
        if (kin) seg_find(sg, gk, s, loc);
        const float* Ab = sg.A[s];
        const int lda = sg.lda[s];
        #pragma unroll
        for (int r = 0; r < 2; r++) {
            int row = bm + a_m + 32 * r;
            float4 vv = {0.f, 0.f, 0.f, 0.f};
            if (kin && row < M) vv = *(const float4*)(Ab + (size_t)row * lda + loc);
            ra[r] = vv;
        }
    };
    auto loadB = [&](int k0) {
        #pragma unroll
        for (int r = 0; r < 2; r++) {
            int k4 = b1_k + 16 * r;
            int gk = k0 + k4;
            bool kin = gk < Ktot;
            int s = 0, loc = 0;
            if (kin) seg_find(sg, gk, s, loc);
            const float* Bb = sg.B[s];
            const int ldb = sg.ldb[s];
            int gn = bn + b1_n;
            float4 vv = {0.f, 0.f, 0.f, 0.f};
            if (kin && gn < N) vv = *(const float4*)(Bb + (size_t)gn * ldb + loc);
            rb[r] = vv;
        }
    };

    if (kt0 < kt1) {
        loadA(kt0 * 32); loadB(kt0 * 32);
        for (int t = kt0; t < kt1; t++) {
            #pragma unroll
            for (int r = 0; r < 2; r++) {
                int m = a_m + 32 * r;
                As[a_k4 + 0][m] = ra[r].x;
                As[a_k4 + 1][m] = ra[r].y;
                As[a_k4 + 2][m] = ra[r].z;
                As[a_k4 + 3][m] = ra[r].w;
            }
            #pragma unroll
            for (int r = 0; r < 2; r++) {
                int k4 = b1_k + 16 * r;
                Bs[k4 + 0][b1_n] = rb[r].x;
                Bs[k4 + 1][b1_n] = rb[r].y;
                Bs[k4 + 2][b1_n] = rb[r].z;
                Bs[k4 + 3][b1_n] = rb[r].w;
            }
            __syncthreads();
            if (t + 1 < kt1) { loadA((t + 1) * 32); loadB((t + 1) * 32); }
            #pragma unroll 8
            for (int kk = 0; kk < 32; kk++) {
                float4 b = *(float4*)&Bs[kk][n0];
                float4 av = *(float4*)&As[kk][m0];
                float a[4] = {av.x, av.y, av.z, av.w};
                #pragma unroll
                for (int i = 0; i < 4; i++) {
                    acc[i][0] += a[i] * b.x;
                    acc[i][1] += a[i] * b.y;
                    acc[i][2] += a[i] * b.z;
                    acc[i][3] += a[i] * b.w;
                }
            }
            __syncthreads();
        }
    }

    int col = bn + n0;
    if (col < N) {
        #pragma unroll
        for (int i = 0; i < 4; i++) {
            int row = bm + m0 + i;
            if (row < M) {
                float4 o = {acc[i][0], acc[i][1], acc[i][2], acc[i][3]};
                *(float4*)(P + ((size_t)kc * M + row) * N + col) = o;
            }
        }
    }
}

// out = relu(sum_kc P + bias)
__global__ void reduce_relu(float* __restrict__ out, const float* __restrict__ P,
                            const float* __restrict__ bias, int MN, int N, int KS)
{
    int i = blockIdx.x * 256 + threadIdx.x;
    if (i >= MN) return;
    float s = bias[i % N];
    for (int k = 0; k < KS; k++) s += P[(size_t)k * MN + i];
    out[i] = fmaxf(s, 0.f);
}

// qhi/qlo = hi/lo bf16 split of relu(sum_kc P + bias)
__global__ void reduce_relu_split(ushort* __restrict__ qhi, ushort* __restrict__ qlo,
                                  const float* __restrict__ P, const float* __restrict__ bias,
                                  int MN, int N, int KS)
{
    int i = blockIdx.x * 256 + threadIdx.x;
    if (i >= MN) return;
    float s = bias[i % N];
    for (int k = 0; k < KS; k++) s += P[(size_t)k * MN + i];
    s = fmaxf(s, 0.f);
    ushort h = f2bf(s);
    qhi[i] = h;
    qlo[i] = f2bf(s - bf2f(h));
}

// ---------------------------------------------------------------- bf16 MFMA multi-segment GEMM
typedef __attribute__((ext_vector_type(8))) short bfrag;
typedef __attribute__((ext_vector_type(4))) float ffrag;

struct BfSegs {
    const ushort* A[3];
    const ushort* B[3];
    int lda[3], ldb[3], Ks[3];
    int nseg, Ktot;
};

__device__ inline void bseg_find(const BfSegs& sg, int gk, int& s, int& loc) {
    s = 0; loc = gk;
    #pragma unroll
    for (int t = 0; t < 2; t++) {
        if (s + 1 < sg.nseg && loc >= sg.Ks[s]) { loc -= sg.Ks[s]; s++; }
    }
}

// ACT: 0 none, 1 relu, 2 sigmoid. WF32: write f32 C. WBF: write bf16 Cb.
// order: 0 = A-reuse, 1 = B-reuse (XCD-contiguous).
template<int ACT, int WF32, int WBF>
__global__ __launch_bounds__(256) void mfma_seg(
    float* __restrict__ C, ushort* __restrict__ Cb, const BfSegs sg,
    const float* __restrict__ bias, int M, int N, int ldc, int nbx, int order)
{
    __shared__ __align__(16) ushort Als[8192];
    __shared__ __align__(16) ushort Bls[4096];

    int nby = (M + 127) >> 7;
    int tot = nbx * nby;
    int chunk = (tot + 7) >> 3;
    int v = (int)(blockIdx.x & 7) * chunk + (int)(blockIdx.x >> 3);
    if (v >= tot) return;
    int by, bx;
    if (order == 0) { by = v / nbx; bx = v - by * nbx; }
    else            { bx = v / nby; by = v - bx * nby; }
    const int bm = by * 128, bn = bx * 64;

    const int tid  = threadIdx.x;
    const int lane = tid & 63;
    const int w    = tid >> 6;
    const int wm   = (w & 1) * 4;
    const int wn   = (w >> 1) * 2;

    ffrag acc[4][2];
    #pragma unroll
    for (int i = 0; i < 4; i++)
        #pragma unroll
        for (int j = 0; j < 2; j++) acc[i][j] = (ffrag){0.f, 0.f, 0.f, 0.f};

    const int Ktot = sg.Ktot;
    const int nkt = (Ktot + 63) >> 6;

    int a_m[4], a_kq[4], a_wc[4];
    #pragma unroll
    for (int i = 0; i < 4; i++) {
        int c = i * 256 + tid;
        a_m[i] = c & 127; a_kq[i] = c >> 7;
        a_wc[i] = ((a_m[i] >> 4) * 2 + (a_kq[i] >> 2)) * 64 + (a_kq[i] & 3) * 16 + (a_m[i] & 15);
    }
    int b_n[2], b_kq[2], b_wc[2];
    #pragma unroll
    for (int i = 0; i < 2; i++) {
        int c = i * 256 + tid;
        b_n[i] = c & 63; b_kq[i] = c >> 6;
        b_wc[i] = ((b_n[i] >> 4) * 2 + (b_kq[i] >> 2)) * 64 + (b_kq[i] & 3) * 16 + (b_n[i] & 15);
    }

    uint4 ra[4], rb[2];
    auto loadA = [&](int k0) {
        #pragma unroll
        for (int i = 0; i < 4; i++) {
            int gk = k0 + a_kq[i] * 8;
            int row = bm + a_m[i];
            uint4 vv = {0u, 0u, 0u, 0u};
            if (gk < Ktot && row < M) {
                int s, loc; bseg_find(sg, gk, s, loc);
                vv = *(const uint4*)(sg.A[s] + (size_t)row * sg.lda[s] + loc);
            }
            ra[i] = vv;
        }
    };
    auto loadB = [&](int k0) {
        #pragma unroll
        for (int i = 0; i < 2; i++) {
            int gk = k0 + b_kq[i] * 8;
            int gn = bn + b_n[i];
            uint4 vv = {0u, 0u, 0u, 0u};
            if (gk < Ktot && gn < N) {
                int s, loc; bseg_find(sg, gk, s, loc);
                vv = *(const uint4*)(sg.B[s] + (size_t)gn * sg.ldb[s] + loc);
            }
            rb[i] = vv;
        }
    };

    loadA(0); loadB(0);

    for (int t = 0; t < nkt; t++) {
        #pragma unroll
        for (int i = 0; i < 4; i++) *(uint4*)(&Als[a_wc[i] * 8]) = ra[i];
        #pragma unroll
        for (int i = 0; i < 2; i++) *(uint4*)(&Bls[b_wc[i] * 8]) = rb[i];
        __syncthreads();

        if (t + 1 < nkt) { loadA((t + 1) << 6); loadB((t + 1) << 6); }

        #pragma unroll
        for (int kt = 0; kt < 2; kt++) {
            bfrag af[4], bf[2];
            #pragma unroll
            for (int i = 0; i < 4; i++)
                af[i] = *(const bfrag*)(&Als[(((wm + i) * 2 + kt) * 64 + lane) * 8]);
            #pragma unroll
            for (int j = 0; j < 2; j++)
                bf[j] = *(const bfrag*)(&Bls[(((wn + j) * 2 + kt) * 64 + lane) * 8]);
            #pragma unroll
            for (int i = 0; i < 4; i++)
                #pragma unroll
                for (int j = 0; j < 2; j++)
                    acc[i][j] = __builtin_amdgcn_mfma_f32_16x16x32_bf16(af[i], bf[j], acc[i][j], 0, 0, 0);
        }
        __syncthreads();
    }

    const int rbase = (lane >> 4) * 4;
    const int cl = lane & 15;
    #pragma unroll
    for (int j = 0; j < 2; j++) {
        int col = bn + (wn + j) * 16 + cl;
        if (col >= N) continue;
        float bv = bias ? bias[col] : 0.f;
        #pragma unroll
        for (int i = 0; i < 4; i++) {
            int mrow = bm + (wm + i) * 16 + rbase;
            #pragma unroll
            for (int r = 0; r < 4; r++) {
                int row = mrow + r;
                if (row < M) {
                    float o = acc[i][j][r] + bv;
                    if (ACT == 1) o = fmaxf(o, 0.f);
                    else if (ACT == 2) o = 1.f / (1.f + expf(-o));
                    if (WF32) C[(size_t)row * ldc + col] = o;
                    if (WBF)  Cb[(size_t)row * ldc + col] = f2bf(o);
                }
            }
        }
    }
}

// ---------------------------------------------------------------- CSR build

__global__ void count_dst(const int* __restrict__ di, int* __restrict__ cnt, int E) {
    int e = blockIdx.x * 256 + threadIdx.x;
    if (e < E) atomicAdd(&cnt[di[e]], 1);
}

__global__ __launch_bounds__(1024) void scan_rows(
    const int* __restrict__ cnt, int* __restrict__ row_start, int* __restrict__ cursor,
    float* __restrict__ degf, float* __restrict__ invd)
{
    __shared__ int part[1024];
    const int CH = (NUM_E + 1023) / 1024;
    int t = threadIdx.x;
    int base = t * CH;
    int local[32];
    int s = 0;
    for (int j = 0; j < CH; j++) {
        int idx = base + j;
        int c = (idx < NUM_E) ? cnt[idx] : 0;
        local[j] = s; s += c;
    }
    part[t] = s;
    __syncthreads();
    for (int off = 1; off < 1024; off <<= 1) {
        int vv = (t >= off) ? part[t - off] : 0;
        __syncthreads();
        part[t] += vv;
        __syncthreads();
    }
    int pre = (t == 0) ? 0 : part[t - 1];
    for (int j = 0; j < CH; j++) {
        int idx = base + j;
        if (idx < NUM_E) {
            int rs = pre + local[j];
            row_start[idx] = rs;
            cursor[idx] = rs;
            int c = cnt[idx];
            degf[idx] = (float)c;
            invd[idx] = 1.f / fmaxf((float)c, 1.f);
        }
    }
    if (t == 1023) row_start[NUM_E] = part[1023];
}

__global__ void build_perm(const int* __restrict__ si, const int* __restrict__ di,
                           const int* __restrict__ ei, int* __restrict__ cursor,
                           int* __restrict__ ssrc, int* __restrict__ setype, int E)
{
    int e = blockIdx.x * 256 + threadIdx.x;
    if (e >= E) return;
    int pos = atomicAdd(&cursor[di[e]], 1);
    ssrc[pos]   = si[e];
    setype[pos] = ei[e];
}

// ---------------------------------------------------------------- gathers (bf16 in/out)

__global__ __launch_bounds__(256) void seg_gather_norm_bf(
    ushort* __restrict__ bh, const ushort* __restrict__ bprev,
    const int* __restrict__ ssrc, const int* __restrict__ row_start,
    const float* __restrict__ invd)
{
    int v = blockIdx.x * 4 + (threadIdx.x >> 6);
    int lane = threadIdx.x & 63;
    if (v >= NUM_E) return;
    int s0 = row_start[v], s1 = row_start[v + 1];
    bool act = lane < 50;
    float4 acc = {0.f, 0.f, 0.f, 0.f};
    int j = s0;
    for (; j + 1 < s1; j += 2) {
        int sa = ssrc[j], sb = ssrc[j + 1];
        if (act) {
            float4 xa = bf4_to_f4(*(const ushort4*)(bprev + (long)sa * H_DIM + lane * 4));
            float4 xb = bf4_to_f4(*(const ushort4*)(bprev + (long)sb * H_DIM + lane * 4));
            acc.x += xa.x + xb.x; acc.y += xa.y + xb.y;
            acc.z += xa.z + xb.z; acc.w += xa.w + xb.w;
        }
    }
    if (j < s1) {
        int sa = ssrc[j];
        if (act) {
            float4 xa = bf4_to_f4(*(const ushort4*)(bprev + (long)sa * H_DIM + lane * 4));
            acc.x += xa.x; acc.y += xa.y; acc.z += xa.z; acc.w += xa.w;
        }
    }
    float iv = invd[v];
    acc.x *= iv; acc.y *= iv; acc.z *= iv; acc.w *= iv;
    float ss = act ? (acc.x*acc.x + acc.y*acc.y + acc.z*acc.z + acc.w*acc.w) : 0.f;
    ss = wave_sum64(ss);
    float r = 1.f / fmaxf(sqrtf(ss), 1e-12f);
    if (act) {
        ushort4 ob = {f2bf(acc.x * r), f2bf(acc.y * r), f2bf(acc.z * r), f2bf(acc.w * r)};
        *(ushort4*)(bh + (long)v * H_DIM + lane * 4) = ob;
    }
}

__global__ __launch_bounds__(256) void seg_gather_layer_bf(
    ushort* __restrict__ btmp, const ushort* __restrict__ bh, const ushort* __restrict__ brel,
    const int* __restrict__ ssrc, const int* __restrict__ setype,
    const int* __restrict__ row_start, const float* __restrict__ invd)
{
    int v = blockIdx.x * 4 + (threadIdx.x >> 6);
    int lane = threadIdx.x & 63;
    if (v >= NUM_E) return;
    int s0 = row_start[v], s1 = row_start[v + 1];
    bool act = lane < 50;
    float4 acc = {0.f, 0.f, 0.f, 0.f};
    for (int j = s0; j < s1; j++) {
        int s = ssrc[j];
        int t = setype[j];
        if (act) {
            float4 x = bf4_to_f4(*(const ushort4*)(bh   + (long)s * H_DIM + lane * 4));
            float4 y = bf4_to_f4(*(const ushort4*)(brel + (long)t * H_DIM + lane * 4));
            acc.x += x.x + y.x; acc.y += x.y + y.y;
            acc.z += x.z + y.z; acc.w += x.w + y.w;
        }
    }
    float iv = invd[v];
    if (act) {
        ushort4 ob = {f2bf(acc.x * iv), f2bf(acc.y * iv), f2bf(acc.z * iv), f2bf(acc.w * iv)};
        *(ushort4*)(btmp + (long)v * H_DIM + lane * 4) = ob;
    }
}

// ---------------------------------------------------------------- row kernels

__global__ __launch_bounds__(256) void l2norm_rows4(
    float* __restrict__ out, ushort* __restrict__ bout,
    const float* __restrict__ in, int nrows)
{
    int v = blockIdx.x * 4 + (threadIdx.x >> 6);
    int lane = threadIdx.x & 63;
    if (v >= nrows) return;
    bool act = lane < 50;
    float4 x = {0.f, 0.f, 0.f, 0.f};
    if (act) x = *(const float4*)(in + (long)v * H_DIM + lane * 4);
    float ss = x.x*x.x + x.y*x.y + x.z*x.z + x.w*x.w;
    ss = wave_sum64(ss);
    float r = 1.f / fmaxf(sqrtf(ss), 1e-12f);
    if (act) {
        long base = (long)v * H_DIM + lane * 4;
        float4 o = {x.x * r, x.y * r, x.z * r, x.w * r};
        *(float4*)(out + base) = o;
        if (bout) {
            ushort4 ob = {f2bf(o.x), f2bf(o.y), f2bf(o.z), f2bf(o.w)};
            *(ushort4*)(bout + base) = ob;
        }
    }
}

__global__ __launch_bounds__(256) void l2norm_bf4(ushort* __restrict__ b, int nrows)
{
    int v = blockIdx.x * 4 + (threadIdx.x >> 6);
    int lane = threadIdx.x & 63;
    if (v >= nrows) return;
    bool act = lane < 50;
    float4 x = {0.f, 0.f, 0.f, 0.f};
    long base = (long)v * H_DIM + lane * 4;
    if (act) x = bf4_to_f4(*(const ushort4*)(b + base));
    float ss = x.x*x.x + x.y*x.y + x.z*x.z + x.w*x.w;
    ss = wave_sum64(ss);
    float r = 1.f / fmaxf(sqrtf(ss), 1e-12f);
    if (act) {
        ushort4 ob = {f2bf(x.x * r), f2bf(x.y * r), f2bf(x.z * r), f2bf(x.w * r)};
        *(ushort4*)(b + base) = ob;
    }
}

__global__ void tenc_ent(ushort* __restrict__ bte, const float* __restrict__ deg,
                         const float* __restrict__ af, const float* __restrict__ ap,
                         const float* __restrict__ cf, const float* __restrict__ cp,
                         float tcnt, int M)
{
    int idx = blockIdx.x * 256 + threadIdx.x;
    if (idx >= M * TD_DIM) return;
    int v = idx / TD_DIM, j = idx % TD_DIM;
    float t = (deg[v] > 0.f) ? tcnt : 100.0f;
    float val;
    if (j < HD_DIM) val = tanhf((t + 1.f) * af[j] + ap[j]);
    else            val = cosf(t * cf[j - HD_DIM] + cp[j - HD_DIM]);
    bte[idx] = f2bf(val);
}

__global__ __launch_bounds__(256) void gru_fused(
    float* __restrict__ prev, ushort* __restrict__ bprev, const float* __restrict__ rz,
    const float* __restrict__ iN, const float* __restrict__ hN)
{
    int v = blockIdx.x * 4 + (threadIdx.x >> 6);
    int lane = threadIdx.x & 63;
    if (v >= NUM_E) return;
    bool act = lane < 50;
    long b200 = (long)v * H_DIM + lane * 4;
    long b400 = (long)v * 400 + lane * 4;
    float4 o = {0.f, 0.f, 0.f, 0.f};
    if (act) {
        float4 r4 = *(const float4*)(rz + b400);
        float4 z4 = *(const float4*)(rz + b400 + 200);
        float4 n4 = *(const float4*)(iN + b200);
        float4 g4 = *(const float4*)(hN + b200);
        float4 p4 = *(const float4*)(prev + b200);
        float ngx = tanhf(n4.x + r4.x * g4.x);
        float ngy = tanhf(n4.y + r4.y * g4.y);
        float ngz = tanhf(n4.z + r4.z * g4.z);
        float ngw = tanhf(n4.w + r4.w * g4.w);
        o.x = (1.f - z4.x) * ngx + z4.x * p4.x;
        o.y = (1.f - z4.y) * ngy + z4.y * p4.y;
        o.z = (1.f - z4.z) * ngz + z4.z * p4.z;
        o.w = (1.f - z4.w) * ngw + z4.w * p4.w;
    }
    float ss = o.x*o.x + o.y*o.y + o.z*o.z + o.w*o.w;
    ss = wave_sum64(ss);
    float r = 1.f / fmaxf(sqrtf(ss), 1e-12f);
    if (act) {
        float4 wv = {o.x * r, o.y * r, o.z * r, o.w * r};
        *(float4*)(prev + b200) = wv;
        ushort4 ob = {f2bf(wv.x), f2bf(wv.y), f2bf(wv.z), f2bf(wv.w)};
        *(ushort4*)(bprev + b200) = ob;
    }
}

// ---------------------------------------------------------------- batch head

__global__ void gather_qs_qr3(float* __restrict__ qs3, float* __restrict__ qr3,
                              const float* __restrict__ out, const float* __restrict__ reln,
                              const int* __restrict__ data)
{
    long i = (long)blockIdx.x * 256 + threadIdx.x;
    if (i >= (long)BATCH * H_DIM) return;
    int b = (int)(i / H_DIM), j = (int)(i % H_DIM);
    float vs = out[(long)data[b * 4 + 0] * H_DIM + j];
    float vr = reln[(long)data[b * 4 + 1] * H_DIM + j];
    const long S = (long)BATCH * H_DIM;
    qs3[i] = vs; qs3[i + S] = vs; qs3[i + 2*S] = vs;
    qr3[i] = vr; qr3[i + S] = vr; qr3[i + 2*S] = vr;
}

__global__ __launch_bounds__(64) void semb_kernel(
    float* __restrict__ semb, const float* __restrict__ out,
    const int* __restrict__ his_idx, const int* __restrict__ his_len)
{
    int b = blockIdx.x, k = blockIdx.y;
    int lane = threadIdx.x;
    int ln = his_len[b * 3 + k];
    if (ln > L_HIST) ln = L_HIST;
    float vals[4] = {0.f, 0.f, 0.f, 0.f};
    for (int l = 0; l < ln; l++) {
        int idx = his_idx[((long)b * 3 + k) * L_HIST + l];
        #pragma unroll
        for (int t = 0; t < 4; t++) {
            int j = lane + t * 64;
            if (j < H_DIM) vals[t] += out[(long)idx * H_DIM + j];
        }
    }
    float scale = 1.f / fmaxf((float)ln, 1.f);
    float ss = 0.f;
    #pragma unroll
    for (int t = 0; t < 4; t++) { vals[t] *= scale; ss += vals[t] * vals[t]; }
    ss = wave_sum64(ss);
    float r = 1.f / fmaxf(sqrtf(ss), 1e-12f);
    #pragma unroll
    for (int t = 0; t < 4; t++) {
        int j = lane + t * 64;
        if (j < H_DIM) semb[((long)k * BATCH + b) * H_DIM + j] = vals[t] * r;
    }
}

__global__ void tenc_batch(float* __restrict__ teb, const int* __restrict__ his_len,
                           const float* __restrict__ af, const float* __restrict__ ap,
                           const float* __restrict__ cf, const float* __restrict__ cp)
{
    int idx = blockIdx.x * 256 + threadIdx.x;
    if (idx >= 3 * BATCH * TD_DIM) return;
    int k = idx / (BATCH * TD_DIM);
    int rem = idx - k * (BATCH * TD_DIM);
    int b = rem / TD_DIM, j = rem % TD_DIM;
    int ln = his_len[b * 3 + k];
    float t = (ln > 0) ? (float)(2 - k) : 100.0f;
    float val;
    if (j < HD_DIM) val = tanhf((t + 1.f) * af[j] + ap[j]);
    else            val = cosf(t * cf[j - HD_DIM] + cp[j - HD_DIM]);
    teb[idx] = val;
}

__global__ __launch_bounds__(256) void att_logits_rows(
    float* __restrict__ atts, const float* __restrict__ a,
    const float* __restrict__ Wc_w, const float* __restrict__ Wc_b)
{
    int row = blockIdx.x * 4 + (threadIdx.x >> 6);
    int lane = threadIdx.x & 63;
    if (row >= 3 * BATCH) return;
    int k = row >> 9;
    int b = row & 511;
    float s = 0.f;
    for (int j = lane; j < H_DIM; j += 64) s += a[(long)row * H_DIM + j] * Wc_w[j];
    s = wave_sum64(s);
    if (lane == 0) atts[b * 3 + k] = s + Wc_b[0];
}

__global__ void softmax_out2(float* __restrict__ out2, const float* __restrict__ atts,
                             const float* __restrict__ semb)
{
    long i = (long)blockIdx.x * 256 + threadIdx.x;
    if (i >= (long)BATCH * H_DIM) return;
    int b = (int)(i / H_DIM), j = (int)(i % H_DIM);
    float l0 = atts[b * 3 + 0], l1 = atts[b * 3 + 1], l2 = atts[b * 3 + 2];
    float m = fmaxf(l0, fmaxf(l1, l2));
    float e0 = expf(l0 - m), e1 = expf(l1 - m), e2 = expf(l2 - m);
    float s = e0 + e1 + e2;
    float v = (e0 * semb[((long)0 * BATCH + b) * H_DIM + j] +
               e1 * semb[((long)1 * BATCH + b) * H_DIM + j] +
               e2 * semb[((long)2 * BATCH + b) * H_DIM + j]) / s;
    out2[i] = v;
}

// ---------------------------------------------------------------- launch

extern "C" void kernel_launch(void* const* d_in, const int* in_sizes, int n_in,
                              void* d_out, int out_size, void* d_ws, size_t ws_size,
                              hipStream_t stream)
{
    (void)in_sizes; (void)n_in; (void)out_size; (void)ws_size;

    const int*   src     = (const int*)d_in[0];
    const int*   dst     = (const int*)d_in[1];
    const int*   etype   = (const int*)d_in[2];
    const int*   data    = (const int*)d_in[3];
    const int*   his_idx = (const int*)d_in[4];
    const int*   his_len = (const int*)d_in[5];
    const float* ent     = (const float*)d_in[6];
    const float* loop_w  = (const float*)d_in[7];
    const float* rel     = (const float*)d_in[8];
    const float* af      = (const float*)d_in[9];
    const float* ap      = (const float*)d_in[10];
    const float* cf      = (const float*)d_in[11];
    const float* cp      = (const float*)d_in[12];
    const float* Wn      = (const float*)d_in[13];
    const float* Ws      = (const float*)d_in[14];
    const float* W_ih    = (const float*)d_in[15];
    const float* W_hh    = (const float*)d_in[16];
    const float* b_ih    = (const float*)d_in[17];
    const float* b_hh    = (const float*)d_in[18];
    const float* Wb_w    = (const float*)d_in[19];
    const float* Wb_b    = (const float*)d_in[20];
    const float* Wc_w    = (const float*)d_in[21];
    const float* Wc_b    = (const float*)d_in[22];
    const float* Wd_w    = (const float*)d_in[23];
    const float* Wd_b    = (const float*)d_in[24];
    float* out_p = (float*)d_out;

    float* wp = (float*)d_ws;
    size_t off = 0;
    auto alloc = [&](size_t n) {
        size_t n4 = (n + 3) & ~(size_t)3;
        float* p = wp + off; off += n4; return p;
    };
    const long nE200 = (long)NUM_E * H_DIM;
    float* prev   = alloc(nE200);
    float* h1     = alloc(nE200);                       // GRU iN (f32); batch head: split-K partials
    float* tmp    = alloc(nE200);                       // init gemm out; GRU hN; qbuf partials
    float* rz     = out_p;                              // (NUM_E x 400) scratch in d_out
    ushort* bh0   = (ushort*)alloc(nE200 / 2);
    ushort* bh1   = (ushort*)alloc(nE200 / 2);
    ushort* btmp  = (ushort*)alloc(nE200 / 2);
    ushort* bprev = (ushort*)alloc(nE200 / 2);
    ushort* plo   = (ushort*)alloc(nE200 / 2);
    ushort* bte   = (ushort*)alloc((size_t)NUM_E * TD_DIM / 2);
    ushort* brel  = (ushort*)alloc(400 * H_DIM / 2);
    ushort* bW_ih = (ushort*)alloc(600 * 248 / 2);
    ushort* bW_hh = (ushort*)alloc(600 * 200 / 2);
    ushort* bWn_t = (ushort*)alloc(2 * 200 * 200 / 2);
    ushort* bWs_t = (ushort*)alloc(2 * 200 * 200 / 2);
    ushort* bLp_t = (ushort*)alloc(200 * 200 / 2);
    ushort* qhi   = (ushort*)alloc(BATCH * H_DIM / 2);
    ushort* qlo   = (ushort*)alloc(BATCH * H_DIM / 2);
    float* degf   = alloc(NUM_E);
    float* invd   = alloc(NUM_E);
    float* reln   = alloc(400 * H_DIM);
    float* bsum   = alloc(1024);
    float* qs3    = alloc(3 * BATCH * H_DIM);
    float* qr3    = alloc(3 * BATCH * H_DIM);
    float* semb   = alloc(3 * BATCH * H_DIM);
    float* teb    = alloc(3 * BATCH * TD_DIM);
    float* abuf   = alloc(3 * BATCH * H_DIM);
    float* atts   = alloc(2048);
    float* out2   = alloc(BATCH * H_DIM);
    int* cnt       = (int*)alloc(NUM_E);
    int* row_start = (int*)alloc(NUM_E + 4);
    int* cursor    = (int*)alloc(NUM_E);
    int* ssrc      = (int*)alloc(E_EDGES);
    int* setype    = (int*)alloc(E_EDGES);

    auto nblk = [](long n) { return (unsigned)((n + 255) / 256); };

    auto bseg1 = [](const ushort* A, int la, const ushort* B, int lb, int K) {
        BfSegs s{}; s.A[0]=A; s.lda[0]=la; s.B[0]=B; s.ldb[0]=lb; s.Ks[0]=K;
        s.nseg=1; s.Ktot=K; return s;
    };
    auto bseg2 = [](const ushort* A0, int la0, const ushort* B0, int lb0, int K0,
                    const ushort* A1, int la1, const ushort* B1, int lb1, int K1) {
        BfSegs s{}; s.A[0]=A0; s.lda[0]=la0; s.B[0]=B0; s.ldb[0]=lb0; s.Ks[0]=K0;
        s.A[1]=A1; s.lda[1]=la1; s.B[1]=B1; s.ldb[1]=lb1; s.Ks[1]=K1;
        s.nseg=2; s.Ktot=K0+K1; return s;
    };
    auto bseg3 = [](const ushort* A0, int la0, const ushort* B0, int lb0, int K0,
                    const ushort* A1, int la1, const ushort* B1, int lb1, int K1,
                    const ushort* A2, int la2, const ushort* B2, int lb2, int K2) {
        BfSegs s{}; s.A[0]=A0; s.lda[0]=la0; s.B[0]=B0; s.ldb[0]=lb0; s.Ks[0]=K0;
        s.A[1]=A1; s.lda[1]=la1; s.B[1]=B1; s.ldb[1]=lb1; s.Ks[1]=K1;
        s.A[2]=A2; s.lda[2]=la2; s.B[2]=B2; s.ldb[2]=lb2; s.Ks[2]=K2;
        s.nseg=3; s.Ktot=K0+K1+K2; return s;
    };

    // MODE: 0 = f32-out no act; 1 = relu bf16-only; 2 = sigmoid f32-only
    auto mfma = [&](int MODE, float* C, ushort* Cb, const BfSegs& sg,
                    const float* bias, int M, int N, int ldc, int order) {
        int nbx = (N + 63) >> 6;
        int tot = nbx * ((M + 127) >> 7);
        unsigned grid = (unsigned)(((tot + 7) >> 3) << 3);
        if (MODE == 0)      mfma_seg<0,1,0><<<grid, 256, 0, stream>>>(C, Cb, sg, bias, M, N, ldc, nbx, order);
        else if (MODE == 1) mfma_seg<1,0,1><<<grid, 256, 0, stream>>>(C, Cb, sg, bias, M, N, ldc, nbx, order);
        else                mfma_seg<2,1,0><<<grid, 256, 0, stream>>>(C, Cb, sg, bias, M, N, ldc, nbx, order);
    };

    auto seg3 = [](const float* A0, int la0, const float* B0, int lb0, int K0,
                   const float* A1, int la1, const float* B1, int lb1, int K1,
                   const float* A2, int la2, const float* B2, int lb2, int K2) {
        Segs s{}; s.A[0]=A0; s.lda[0]=la0; s.B[0]=B0; s.ldb[0]=lb0; s.Ks[0]=K0;
        s.A[1]=A1; s.lda[1]=la1; s.B[1]=B1; s.ldb[1]=lb1; s.Ks[1]=K1;
        s.A[2]=A2; s.lda[2]=la2; s.B[2]=B2; s.ldb[2]=lb2; s.Ks[2]=K2;
        s.nseg=3; s.Ktot=K0+K1+K2; return s;
    };
    auto seg4 = [](const float* A0, int la0, const float* B0, int lb0, int K0,
                   const float* A1, int la1, const float* B1, int lb1, int K1,
                   const float* A2, int la2, const float* B2, int lb2, int K2,
                   const float* A3, int la3, const float* B3, int lb3, int K3) {
        Segs s{}; s.A[0]=A0; s.lda[0]=la0; s.B[0]=B0; s.ldb[0]=lb0; s.Ks[0]=K0;
        s.A[1]=A1; s.lda[1]=la1; s.B[1]=B1; s.ldb[1]=lb1; s.Ks[1]=K1;
        s.A[2]=A2; s.lda[2]=la2; s.B[2]=B2; s.ldb[2]=lb2; s.Ks[2]=K2;
        s.A[3]=A3; s.lda[3]=la3; s.B[3]=B3; s.ldb[3]=lb3; s.Ks[3]=K3;
        s.nseg=4; s.Ktot=K0+K1+K2+K3; return s;
    };
    // split-K partial gemm launcher
    auto splitk = [&](float* P, const Segs& sg, int M, int N, int KS) {
        int nbx = (N + 63) >> 6;
        int nby = (M + 63) >> 6;
        int ntile = (sg.Ktot + 31) / 32;
        int tpc = (ntile + KS - 1) / KS;
        int tot_all = nbx * nby * KS;
        unsigned grid = (unsigned)(((tot_all + 7) >> 3) << 3);
        sgemm_splitk<<<grid, 256, 0, stream>>>(P, sg, M, N, nbx, nby, KS, tpc);
    };

    const unsigned r4 = (NUM_E + 3) / 4;

    // ---- prelude ----
    l2norm_rows4<<<100, 256, 0, stream>>>(reln, brel, rel, 400);
    bias_sum<<<3, 256, 0, stream>>>(bsum, b_ih, b_hh);
    cvt_bf16_k<<<nblk(600L*248), 256, 0, stream>>>(bW_ih, W_ih, 600L*248);
    cvt_bf16_k<<<nblk(600L*200), 256, 0, stream>>>(bW_hh, W_hh, 600L*200);
    tcvt_bf16_k<<<nblk(40000), 256, 0, stream>>>(bLp_t, loop_w, 200, 200);
    tcvt_bf16_k<<<nblk(40000), 256, 0, stream>>>(bWn_t,          Wn,          200, 200);
    tcvt_bf16_k<<<nblk(40000), 256, 0, stream>>>(bWn_t + 40000,  Wn + 40000,  200, 200);
    tcvt_bf16_k<<<nblk(40000), 256, 0, stream>>>(bWs_t,          Ws,          200, 200);
    tcvt_bf16_k<<<nblk(40000), 256, 0, stream>>>(bWs_t + 40000,  Ws + 40000,  200, 200);

    // prev = l2norm(ent @ loop_weight)
    cvt_bf16_k<<<nblk(nE200), 256, 0, stream>>>(btmp, ent, nE200);
    mfma(0, tmp, nullptr, bseg1(btmp, H_DIM, bLp_t, H_DIM, H_DIM), nullptr, NUM_E, H_DIM, H_DIM, 0);
    l2norm_rows4<<<r4, 256, 0, stream>>>(prev, bprev, tmp, NUM_E);

    for (int i = 0; i < N_HIST; i++) {
        const int* si = src   + (long)i * E_EDGES;
        const int* di = dst   + (long)i * E_EDGES;
        const int* ei = etype + (long)i * E_EDGES;
        float tcnt = (float)(N_HIST - 1 - i);

        // CSR build
        fill_i32<<<nblk(NUM_E), 256, 0, stream>>>(cnt, NUM_E, 0);
        count_dst<<<nblk(E_EDGES), 256, 0, stream>>>(di, cnt, E_EDGES);
        scan_rows<<<1, 1024, 0, stream>>>(cnt, row_start, cursor, degf, invd);
        build_perm<<<nblk(E_EDGES), 256, 0, stream>>>(si, di, ei, cursor, ssrc, setype, E_EDGES);

        seg_gather_norm_bf<<<r4, 256, 0, stream>>>(bh0, bprev, ssrc, row_start, invd);
        tenc_ent<<<nblk((long)NUM_E * TD_DIM), 256, 0, stream>>>(bte, degf, af, ap, cf, cp, tcnt, NUM_E);

        seg_gather_layer_bf<<<r4, 256, 0, stream>>>(btmp, bh0, brel, ssrc, setype, row_start, invd);
        mfma(1, nullptr, bh1,
             bseg2(btmp, H_DIM, bWn_t,         H_DIM, H_DIM,
                   bh0,  H_DIM, bWs_t,         H_DIM, H_DIM),
             nullptr, NUM_E, H_DIM, H_DIM, 0);
        seg_gather_layer_bf<<<r4, 256, 0, stream>>>(btmp, bh1, brel, ssrc, setype, row_start, invd);
        mfma(1, nullptr, bh0,
             bseg2(btmp, H_DIM, bWn_t + 40000, H_DIM, H_DIM,
                   bh1,  H_DIM, bWs_t + 40000, H_DIM, H_DIM),
             nullptr, NUM_E, H_DIM, H_DIM, 0);
        l2norm_bf4<<<r4, 256, 0, stream>>>(bh0, NUM_E);

        mfma(2, rz, nullptr,
             bseg3(bh0,   H_DIM,  bW_ih,       248, H_DIM,
                   bte,   TD_DIM, bW_ih + 200, 248, TD_DIM,
                   bprev, H_DIM,  bW_hh,       200, H_DIM),
             bsum, NUM_E, 400, 400, 0);
        mfma(0, h1, nullptr,
             bseg2(bh0, H_DIM,  bW_ih + 400*248,       248, H_DIM,
                   bte, TD_DIM, bW_ih + 400*248 + 200, 248, TD_DIM),
             b_ih + 400, NUM_E, H_DIM, H_DIM, 0);
        mfma(0, tmp, nullptr,
             bseg1(bprev, H_DIM, bW_hh + 400*200, 200, H_DIM),
             b_hh + 400, NUM_E, H_DIM, H_DIM, 0);

        gru_fused<<<r4, 256, 0, stream>>>(prev, bprev, rz, h1, tmp);
    }

    // ---- batch head ----
    gather_qs_qr3<<<nblk((long)BATCH * H_DIM), 256, 0, stream>>>(qs3, qr3, prev, reln, data);
    semb_kernel<<<dim3(BATCH, 3), 64, 0, stream>>>(semb, prev, his_idx, his_len);
    tenc_batch<<<nblk(3L * BATCH * TD_DIM), 256, 0, stream>>>(teb, his_len, af, ap, cf, cp);

    // abuf = relu([qs|qr|semb|teb] @ Wb_w^T + Wb_b)   -- split-K, partials in h1
    {
        const int KS = 8;
        const int MN = 3 * BATCH * H_DIM;
        splitk(h1, seg4(qs3, H_DIM,  Wb_w,       648, H_DIM,
                        qr3, H_DIM,  Wb_w + 200, 648, H_DIM,
                        semb, H_DIM, Wb_w + 400, 648, H_DIM,
                        teb, TD_DIM, Wb_w + 600, 648, TD_DIM),
               3 * BATCH, H_DIM, KS);
        reduce_relu<<<nblk(MN), 256, 0, stream>>>(abuf, h1, Wb_b, MN, H_DIM, KS);
    }
    att_logits_rows<<<(3 * BATCH + 3) / 4, 256, 0, stream>>>(atts, abuf, Wc_w, Wc_b);
    softmax_out2<<<nblk((long)BATCH * H_DIM), 256, 0, stream>>>(out2, atts, semb);

    // qbuf = relu([qs|qr|out2] @ Wd_w^T + Wd_b) -> hi/lo bf16 split (partials in tmp)
    {
        const int KS = 8;
        const int MN = BATCH * H_DIM;
        splitk(tmp, seg3(qs3, H_DIM,  Wd_w,       600, H_DIM,
                         qr3, H_DIM,  Wd_w + 200, 600, H_DIM,
                         out2, H_DIM, Wd_w + 400, 600, H_DIM),
               BATCH, H_DIM, KS);
        reduce_relu_split<<<nblk(MN), 256, 0, stream>>>(qhi, qlo, tmp, Wd_b, MN, H_DIM, KS);
    }

    // plo = bf16(prev - f32(bprev))  (bprev is the hi part)
    make_lo<<<nblk(nE200), 256, 0, stream>>>(plo, prev, bprev, nE200);

    // result = q @ prev^T via hi/lo-compensated bf16 MFMA:
    //   qhi@phi + qhi@plo + qlo@phi   (3 K-segments, Ktot=600), B-reuse swizzle
    mfma(0, out_p, nullptr,
         bseg3(qhi, H_DIM, bprev, H_DIM, H_DIM,
               qhi, H_DIM, plo,   H_DIM, H_DIM,
               qlo, H_DIM, bprev, H_DIM, H_DIM),
         nullptr, BATCH, NUM_E, NUM_E, 1);
}